// Round 1
// baseline (1077.308 us; speedup 1.0000x reference)
//
#include <hip/hip_runtime.h>
#include <math.h>

#define D_MODEL 768
#define D_STATE 16
#define D_INNER 1536
#define DT_RANK 48
#define B_SZ    2
#define L_SEQ   2048

// ---------------------------------------------------------------------------
// GEMM: C[M,N] = A[M,K] * B[N,K]^T  (+ optional bias over N, optional softplus)
// A row stride lda, B row stride ldb, C row stride ldc. Kd % 16 == 0.
// 64x64 tile, 256 threads, 4x4 micro-tile per thread.
// ---------------------------------------------------------------------------
template <int ACT>
__global__ __launch_bounds__(256) void gemm_bt(
    const float* __restrict__ A, int lda,
    const float* __restrict__ Bm, int ldb,
    const float* __restrict__ bias,
    float* __restrict__ C, int ldc,
    int M, int N, int Kd) {
  __shared__ float As[16][64];
  __shared__ float Bs[16][64];
  const int tid = threadIdx.x;
  const int tx = tid & 15, ty = tid >> 4;
  const int bm = blockIdx.y * 64, bn = blockIdx.x * 64;
  const int r = tid >> 2;          // 0..63
  const int p = (tid & 3) << 2;    // 0,4,8,12

  float acc[4][4] = {};

  for (int k0 = 0; k0 < Kd; k0 += 16) {
    float4 va = make_float4(0.f, 0.f, 0.f, 0.f);
    if (bm + r < M) va = *(const float4*)(A + (size_t)(bm + r) * lda + k0 + p);
    float4 vb = make_float4(0.f, 0.f, 0.f, 0.f);
    if (bn + r < N) vb = *(const float4*)(Bm + (size_t)(bn + r) * ldb + k0 + p);
    As[p + 0][r] = va.x; As[p + 1][r] = va.y; As[p + 2][r] = va.z; As[p + 3][r] = va.w;
    Bs[p + 0][r] = vb.x; Bs[p + 1][r] = vb.y; Bs[p + 2][r] = vb.z; Bs[p + 3][r] = vb.w;
    __syncthreads();
#pragma unroll
    for (int kk = 0; kk < 16; ++kk) {
      const float4 av = *(const float4*)&As[kk][ty << 2];
      const float4 bv = *(const float4*)&Bs[kk][tx << 2];
      acc[0][0] += av.x * bv.x; acc[0][1] += av.x * bv.y; acc[0][2] += av.x * bv.z; acc[0][3] += av.x * bv.w;
      acc[1][0] += av.y * bv.x; acc[1][1] += av.y * bv.y; acc[1][2] += av.y * bv.z; acc[1][3] += av.y * bv.w;
      acc[2][0] += av.z * bv.x; acc[2][1] += av.z * bv.y; acc[2][2] += av.z * bv.z; acc[2][3] += av.z * bv.w;
      acc[3][0] += av.w * bv.x; acc[3][1] += av.w * bv.y; acc[3][2] += av.w * bv.z; acc[3][3] += av.w * bv.w;
    }
    __syncthreads();
  }

#pragma unroll
  for (int i = 0; i < 4; ++i) {
    const int gm = bm + (ty << 2) + i;
    if (gm >= M) continue;
#pragma unroll
    for (int j = 0; j < 4; ++j) {
      const int gn = bn + (tx << 2) + j;
      if (gn >= N) continue;
      float v = acc[i][j];
      if (bias) v += bias[gn];
      if (ACT == 1) v = (v > 20.f) ? v : log1pf(__expf(v));
      C[(size_t)gm * ldc + gn] = v;
    }
  }
}

// ---------------------------------------------------------------------------
// Depthwise conv (k=3, pad=1) over L + bias + SiLU.
// xz: [B, L, 3072] (x_conv = cols [0,1536)), u out: [B, L, 1536]
// ---------------------------------------------------------------------------
__global__ __launch_bounds__(256) void conv_silu_kernel(
    const float* __restrict__ xz, const float* __restrict__ cw,
    const float* __restrict__ cb, float* __restrict__ u) {
  const int nd4 = D_INNER / 4;
  int idx = blockIdx.x * 256 + threadIdx.x;
  if (idx >= B_SZ * L_SEQ * nd4) return;
  const int d = (idx % nd4) * 4;
  const int l = (idx / nd4) % L_SEQ;
  const int b = idx / (nd4 * L_SEQ);
  float a0 = cb[d + 0], a1 = cb[d + 1], a2 = cb[d + 2], a3 = cb[d + 3];
#pragma unroll
  for (int j = 0; j < 3; ++j) {
    const int ll = l + j - 1;
    if (ll < 0 || ll >= L_SEQ) continue;
    const float4 xv = *(const float4*)(xz + ((size_t)b * L_SEQ + ll) * 3072 + d);
    a0 += xv.x * cw[(d + 0) * 3 + j];
    a1 += xv.y * cw[(d + 1) * 3 + j];
    a2 += xv.z * cw[(d + 2) * 3 + j];
    a3 += xv.w * cw[(d + 3) * 3 + j];
  }
  float4 o;
  o.x = a0 / (1.f + __expf(-a0));
  o.y = a1 / (1.f + __expf(-a1));
  o.z = a2 / (1.f + __expf(-a2));
  o.w = a3 / (1.f + __expf(-a3));
  *(float4*)(u + ((size_t)b * L_SEQ + l) * D_INNER + d) = o;
}

// ---------------------------------------------------------------------------
// Selective scan. One block = (k, b, 16 channels d). 16 lanes (n) per channel.
// k=0 scans forward over l, k=1 backward (equivalent to flip/scan/flip).
// y_k[b,l,d] = sum_n h*C + u*D
// ---------------------------------------------------------------------------
__global__ __launch_bounds__(256) void scan_kernel(
    const float* __restrict__ u,      // [B,L,D]
    const float* __restrict__ xdbl,   // [B,L,160]
    const float* __restrict__ delta,  // [K,B,L,D]
    const float* __restrict__ A_logs, // [K*D,16]
    const float* __restrict__ Ds,     // [K*D]
    float* __restrict__ y) {          // [K,B,L,D]
  __shared__ float sd[64][16], su[64][16], sB[64][16], sC[64][16];
  const int tid = threadIdx.x;
  const int c = tid >> 4;   // local channel
  const int n = tid & 15;   // state index
  const int bid = blockIdx.x;
  const int dg = bid % 96;
  const int b = (bid / 96) & 1;
  const int k = bid / 192;
  const int d0 = dg * 16;
  const int d = d0 + c;
  const int row = k * D_INNER + d;
  const float An = -__expf(A_logs[row * D_STATE + n]);
  const float Dk = Ds[row];
  const float* dptr = delta + ((size_t)(k * B_SZ + b) * L_SEQ) * D_INNER;
  const float* uptr = u + ((size_t)b * L_SEQ) * D_INNER;
  const float* xptr = xdbl + ((size_t)b * L_SEQ) * 160 + k * 80;
  float* yptr = y + ((size_t)(k * B_SZ + b) * L_SEQ) * D_INNER;

  const int lr = tid >> 2;        // load row 0..63
  const int lp = (tid & 3) << 2;  // 0,4,8,12

  float h = 0.f;
  for (int ch = 0; ch < L_SEQ / 64; ++ch) {
    const int l0 = (k == 0) ? ch * 64 : (L_SEQ - 64 - ch * 64);
    const size_t rowL = (size_t)(l0 + lr);
    *(float4*)&sd[lr][lp] = *(const float4*)(dptr + rowL * D_INNER + d0 + lp);
    *(float4*)&su[lr][lp] = *(const float4*)(uptr + rowL * D_INNER + d0 + lp);
    *(float4*)&sB[lr][lp] = *(const float4*)(xptr + rowL * 160 + DT_RANK + lp);
    *(float4*)&sC[lr][lp] = *(const float4*)(xptr + rowL * 160 + DT_RANK + D_STATE + lp);
    __syncthreads();
    for (int s = 0; s < 64; ++s) {
      const int kk = (k == 0) ? s : (63 - s);
      const float dlt = sd[kk][c];
      const float uu = su[kk][c];
      const float dA = __expf(dlt * An);
      const float dBu = dlt * uu * sB[kk][n];
      h = h * dA + dBu;
      float yt = h * sC[kk][n];
      yt += __shfl_xor(yt, 1);
      yt += __shfl_xor(yt, 2);
      yt += __shfl_xor(yt, 4);
      yt += __shfl_xor(yt, 8);
      if (n == 0) {
        yptr[(size_t)(l0 + kk) * D_INNER + d] = yt + uu * Dk;
      }
    }
    __syncthreads();
  }
}

// ---------------------------------------------------------------------------
// y_gated = (y0 + y1) * z   (z = xz cols [1536,3072))
// ---------------------------------------------------------------------------
__global__ __launch_bounds__(256) void gate_kernel(
    const float* __restrict__ y, const float* __restrict__ xz,
    float* __restrict__ yg) {
  const size_t total = (size_t)B_SZ * L_SEQ * D_INNER;
  size_t idx = ((size_t)blockIdx.x * 256 + threadIdx.x) * 4;
  if (idx >= total) return;
  const size_t m = idx / D_INNER;
  const size_t dd = idx % D_INNER;
  const float4 y0 = *(const float4*)(y + idx);
  const float4 y1 = *(const float4*)(y + total + idx);
  const float4 zv = *(const float4*)(xz + m * 3072 + 1536 + dd);
  float4 o;
  o.x = (y0.x + y1.x) * zv.x;
  o.y = (y0.y + y1.y) * zv.y;
  o.z = (y0.z + y1.z) * zv.z;
  o.w = (y0.w + y1.w) * zv.w;
  *(float4*)(yg + idx) = o;
}

// ---------------------------------------------------------------------------
extern "C" void kernel_launch(void* const* d_in, const int* in_sizes, int n_in,
                              void* d_out, int out_size, void* d_ws,
                              size_t ws_size, hipStream_t stream) {
  const float* x          = (const float*)d_in[0];
  const float* in_proj_w  = (const float*)d_in[1];
  const float* conv_w     = (const float*)d_in[2];
  const float* conv_b     = (const float*)d_in[3];
  const float* x_proj_w   = (const float*)d_in[4];
  const float* dt_proj_w  = (const float*)d_in[5];
  const float* dt_proj_b  = (const float*)d_in[6];
  const float* A_logs     = (const float*)d_in[7];
  const float* Ds         = (const float*)d_in[8];
  const float* out_proj_w = (const float*)d_in[9];
  float* out = (float*)d_out;

  const int M = B_SZ * L_SEQ;  // 4096

  float* ws   = (float*)d_ws;
  float* xz   = ws;                                  // [M,3072]
  float* u    = xz + (size_t)M * 3072;               // [M,1536]
  float* xdbl = u + (size_t)M * 1536;                // [M,160]
  float* delta = xdbl + (size_t)M * 160;             // [2,M,1536]
  float* y    = delta + (size_t)2 * M * 1536;        // [2,M,1536]
  float* yg   = u;  // reuse (u dead after scan)

  dim3 blk(256);

  // 1. xz = x @ in_proj_w^T
  gemm_bt<0><<<dim3(3072 / 64, M / 64), blk, 0, stream>>>(
      x, D_MODEL, in_proj_w, D_MODEL, nullptr, xz, 3072, M, 3072, D_MODEL);

  // 2. u = silu(depthwise_conv(x_conv) + bias)
  conv_silu_kernel<<<dim3((M * (D_INNER / 4) + 255) / 256), blk, 0, stream>>>(
      xz, conv_w, conv_b, u);

  // 3. xdbl = u @ x_proj_w^T  (both directions stacked: N=160)
  gemm_bt<0><<<dim3((160 + 63) / 64, M / 64), blk, 0, stream>>>(
      u, D_INNER, x_proj_w, D_INNER, nullptr, xdbl, 160, M, 160, D_INNER);

  // 4. delta_k = softplus(dt_in_k @ dt_proj_w_k^T + dt_proj_b_k)
  for (int k = 0; k < 2; ++k) {
    gemm_bt<1><<<dim3(D_INNER / 64, M / 64), blk, 0, stream>>>(
        xdbl + k * 80, 160, dt_proj_w + (size_t)k * D_INNER * DT_RANK, DT_RANK,
        dt_proj_b + k * D_INNER, delta + (size_t)k * M * D_INNER, D_INNER, M,
        D_INNER, DT_RANK);
  }

  // 5. selective scan (both directions)
  scan_kernel<<<dim3(2 * B_SZ * (D_INNER / 16)), blk, 0, stream>>>(
      u, xdbl, delta, A_logs, Ds, y);

  // 6. yg = (y0 + y1) * z
  gate_kernel<<<dim3((M * D_INNER / 4 + 255) / 256), blk, 0, stream>>>(y, xz, yg);

  // 7. out = yg @ out_proj_w^T
  gemm_bt<0><<<dim3(D_MODEL / 64, M / 64), blk, 0, stream>>>(
      yg, D_INNER, out_proj_w, D_INNER, nullptr, out, D_MODEL, M, D_MODEL,
      D_INNER);
}

// Round 2
// 1027.436 us; speedup vs baseline: 1.0485x; 1.0485x over previous
//
#include <hip/hip_runtime.h>
#include <math.h>

#define D_MODEL 768
#define D_STATE 16
#define D_INNER 1536
#define DT_RANK 48
#define B_SZ    2
#define L_SEQ   2048
#define CH      128            // scan chunk length
#define NCH     (L_SEQ / CH)   // 16 chunks

// ---------------------------------------------------------------------------
// GEMM: C[M,N] = A[M,K] * B[N,K]^T  (+ optional bias over N, optional softplus)
// ---------------------------------------------------------------------------
template <int ACT>
__global__ __launch_bounds__(256) void gemm_bt(
    const float* __restrict__ A, int lda,
    const float* __restrict__ Bm, int ldb,
    const float* __restrict__ bias,
    float* __restrict__ C, int ldc,
    int M, int N, int Kd) {
  __shared__ float As[16][64];
  __shared__ float Bs[16][64];
  const int tid = threadIdx.x;
  const int tx = tid & 15, ty = tid >> 4;
  const int bm = blockIdx.y * 64, bn = blockIdx.x * 64;
  const int r = tid >> 2;
  const int p = (tid & 3) << 2;

  float acc[4][4] = {};

  for (int k0 = 0; k0 < Kd; k0 += 16) {
    float4 va = make_float4(0.f, 0.f, 0.f, 0.f);
    if (bm + r < M) va = *(const float4*)(A + (size_t)(bm + r) * lda + k0 + p);
    float4 vb = make_float4(0.f, 0.f, 0.f, 0.f);
    if (bn + r < N) vb = *(const float4*)(Bm + (size_t)(bn + r) * ldb + k0 + p);
    As[p + 0][r] = va.x; As[p + 1][r] = va.y; As[p + 2][r] = va.z; As[p + 3][r] = va.w;
    Bs[p + 0][r] = vb.x; Bs[p + 1][r] = vb.y; Bs[p + 2][r] = vb.z; Bs[p + 3][r] = vb.w;
    __syncthreads();
#pragma unroll
    for (int kk = 0; kk < 16; ++kk) {
      const float4 av = *(const float4*)&As[kk][ty << 2];
      const float4 bv = *(const float4*)&Bs[kk][tx << 2];
      acc[0][0] += av.x * bv.x; acc[0][1] += av.x * bv.y; acc[0][2] += av.x * bv.z; acc[0][3] += av.x * bv.w;
      acc[1][0] += av.y * bv.x; acc[1][1] += av.y * bv.y; acc[1][2] += av.y * bv.z; acc[1][3] += av.y * bv.w;
      acc[2][0] += av.z * bv.x; acc[2][1] += av.z * bv.y; acc[2][2] += av.z * bv.z; acc[2][3] += av.z * bv.w;
      acc[3][0] += av.w * bv.x; acc[3][1] += av.w * bv.y; acc[3][2] += av.w * bv.z; acc[3][3] += av.w * bv.w;
    }
    __syncthreads();
  }

#pragma unroll
  for (int i = 0; i < 4; ++i) {
    const int gm = bm + (ty << 2) + i;
    if (gm >= M) continue;
#pragma unroll
    for (int j = 0; j < 4; ++j) {
      const int gn = bn + (tx << 2) + j;
      if (gn >= N) continue;
      float v = acc[i][j];
      if (bias) v += bias[gn];
      if (ACT == 1) v = (v > 20.f) ? v : log1pf(__expf(v));
      C[(size_t)gm * ldc + gn] = v;
    }
  }
}

// ---------------------------------------------------------------------------
// Depthwise conv (k=3, pad=1) over L + bias + SiLU.
// ---------------------------------------------------------------------------
__global__ __launch_bounds__(256) void conv_silu_kernel(
    const float* __restrict__ xz, const float* __restrict__ cw,
    const float* __restrict__ cb, float* __restrict__ u) {
  const int nd4 = D_INNER / 4;
  int idx = blockIdx.x * 256 + threadIdx.x;
  if (idx >= B_SZ * L_SEQ * nd4) return;
  const int d = (idx % nd4) * 4;
  const int l = (idx / nd4) % L_SEQ;
  const int b = idx / (nd4 * L_SEQ);
  float a0 = cb[d + 0], a1 = cb[d + 1], a2 = cb[d + 2], a3 = cb[d + 3];
#pragma unroll
  for (int j = 0; j < 3; ++j) {
    const int ll = l + j - 1;
    if (ll < 0 || ll >= L_SEQ) continue;
    const float4 xv = *(const float4*)(xz + ((size_t)b * L_SEQ + ll) * 3072 + d);
    a0 += xv.x * cw[(d + 0) * 3 + j];
    a1 += xv.y * cw[(d + 1) * 3 + j];
    a2 += xv.z * cw[(d + 2) * 3 + j];
    a3 += xv.w * cw[(d + 3) * 3 + j];
  }
  float4 o;
  o.x = a0 / (1.f + __expf(-a0));
  o.y = a1 / (1.f + __expf(-a1));
  o.z = a2 / (1.f + __expf(-a2));
  o.w = a3 / (1.f + __expf(-a3));
  *(float4*)(u + ((size_t)b * L_SEQ + l) * D_INNER + d) = o;
}

// ---------------------------------------------------------------------------
// K1: local scan per chunk (h0 = 0). One block = (k, b, dgroup of 16, chunk).
// Writes y_local (incl. u*D), final state hfin, and chunk delta-sum Tsum.
// Scan position t = 0..L-1; l = t (k=0) or L-1-t (k=1).
// ---------------------------------------------------------------------------
__global__ __launch_bounds__(256) void scan_local_kernel(
    const float* __restrict__ u,      // [B,L,D]
    const float* __restrict__ xdbl,   // [B,L,160]
    const float* __restrict__ delta,  // [K,B,L,D]
    const float* __restrict__ A_logs, // [K*D,16]
    const float* __restrict__ Ds,     // [K*D]
    float* __restrict__ y,            // [K,B,L,D]
    float* __restrict__ hfin,         // [(k,b,ch), dg, tid]
    float* __restrict__ Tsum) {       // [(k,b,ch), dg, c]
  __shared__ float sd[64][16], su[64][16], sB[64][16], sC[64][16];
  const int tid = threadIdx.x;
  const int c = tid >> 4;
  const int n = tid & 15;
  int bid = blockIdx.x;
  const int ch = bid % NCH;
  const int dg = (bid / NCH) % 96;
  const int b = (bid / (NCH * 96)) & 1;
  const int k = bid / (NCH * 96 * 2);
  const int d0 = dg * 16;
  const int d = d0 + c;
  const int row = k * D_INNER + d;
  const float An = -__expf(A_logs[row * D_STATE + n]);
  const float Dk = Ds[row];
  const float* uptr = u + ((size_t)b * L_SEQ) * D_INNER;
  const float* dptr = delta + ((size_t)(k * B_SZ + b) * L_SEQ) * D_INNER;
  const float* xptr = xdbl + ((size_t)b * L_SEQ) * 160 + k * 80;
  float* yptr = y + ((size_t)(k * B_SZ + b) * L_SEQ) * D_INNER;

  const int lr = tid >> 2;
  const int lp = (tid & 3) << 2;
  const int ridx = k ? (63 - lr) : lr;   // scan-order slot for loaded row

  float h = 0.f, S = 0.f;
  for (int sub = 0; sub < CH / 64; ++sub) {
    const int t0 = ch * CH + sub * 64;
    // global rows ascending in l for coalescing; reverse into LDS for k=1
    const int lbase = k ? (L_SEQ - 64 - t0) : t0;
    const size_t rowL = (size_t)(lbase + lr);
    *(float4*)&sd[ridx][lp] = *(const float4*)(dptr + rowL * D_INNER + d0 + lp);
    *(float4*)&su[ridx][lp] = *(const float4*)(uptr + rowL * D_INNER + d0 + lp);
    *(float4*)&sB[ridx][lp] = *(const float4*)(xptr + rowL * 160 + DT_RANK + lp);
    *(float4*)&sC[ridx][lp] = *(const float4*)(xptr + rowL * 160 + DT_RANK + D_STATE + lp);
    __syncthreads();
    for (int s = 0; s < 64; ++s) {
      const float dlt = sd[s][c];
      const float uu = su[s][c];
      S += dlt;
      h = h * __expf(dlt * An) + dlt * uu * sB[s][n];
      float yt = h * sC[s][n];
      yt += __shfl_xor(yt, 1);
      yt += __shfl_xor(yt, 2);
      yt += __shfl_xor(yt, 4);
      yt += __shfl_xor(yt, 8);
      if (n == 0) {
        const int t = t0 + s;
        const int l = k ? (L_SEQ - 1 - t) : t;
        yptr[(size_t)l * D_INNER + d] = yt + uu * Dk;
      }
    }
    __syncthreads();
  }
  const size_t cidx = ((size_t)(k * B_SZ + b) * NCH + ch) * 96 + dg;
  hfin[cidx * 256 + tid] = h;
  if (n == 0) Tsum[cidx * 16 + c] = S;
}

// ---------------------------------------------------------------------------
// K2: stitch chunk states sequentially (16 chunks). One block = (k,b,dg).
// hin[ch] = carry-in state for chunk ch.
// ---------------------------------------------------------------------------
__global__ __launch_bounds__(256) void scan_stitch_kernel(
    const float* __restrict__ hfin, const float* __restrict__ Tsum,
    const float* __restrict__ A_logs, float* __restrict__ hin) {
  const int tid = threadIdx.x;
  const int c = tid >> 4;
  const int n = tid & 15;
  const int bid = blockIdx.x;
  const int dg = bid % 96;
  const int b = (bid / 96) & 1;
  const int k = bid / 192;
  const int row = k * D_INNER + dg * 16 + c;
  const float An = -__expf(A_logs[row * D_STATE + n]);
  float carry = 0.f;
  for (int ch = 0; ch < NCH; ++ch) {
    const size_t cidx = ((size_t)(k * B_SZ + b) * NCH + ch) * 96 + dg;
    hin[cidx * 256 + tid] = carry;
    const float T = Tsum[cidx * 16 + c];
    carry = carry * __expf(An * T) + hfin[cidx * 256 + tid];
  }
}

// ---------------------------------------------------------------------------
// K3: fixup — y_t += sum_n C_tn * exp(An*S_t) * hin_n. All steps independent
// (S_t cumsum is a 1-add/step chain).
// ---------------------------------------------------------------------------
__global__ __launch_bounds__(256) void scan_fixup_kernel(
    const float* __restrict__ xdbl, const float* __restrict__ delta,
    const float* __restrict__ A_logs, const float* __restrict__ hin,
    float* __restrict__ y) {
  __shared__ float sd[64][16], sC[64][16];
  const int tid = threadIdx.x;
  const int c = tid >> 4;
  const int n = tid & 15;
  int bid = blockIdx.x;
  const int ch = bid % NCH;
  const int dg = (bid / NCH) % 96;
  const int b = (bid / (NCH * 96)) & 1;
  const int k = bid / (NCH * 96 * 2);
  const int d0 = dg * 16;
  const int d = d0 + c;
  const int row = k * D_INNER + d;
  const float An = -__expf(A_logs[row * D_STATE + n]);
  const size_t cidx = ((size_t)(k * B_SZ + b) * NCH + ch) * 96 + dg;
  const float hl = hin[cidx * 256 + tid];
  const float* dptr = delta + ((size_t)(k * B_SZ + b) * L_SEQ) * D_INNER;
  const float* xptr = xdbl + ((size_t)b * L_SEQ) * 160 + k * 80;
  float* yptr = y + ((size_t)(k * B_SZ + b) * L_SEQ) * D_INNER;

  const int lr = tid >> 2;
  const int lp = (tid & 3) << 2;
  const int ridx = k ? (63 - lr) : lr;

  float S = 0.f;
  for (int sub = 0; sub < CH / 64; ++sub) {
    const int t0 = ch * CH + sub * 64;
    const int lbase = k ? (L_SEQ - 64 - t0) : t0;
    const size_t rowL = (size_t)(lbase + lr);
    *(float4*)&sd[ridx][lp] = *(const float4*)(dptr + rowL * D_INNER + d0 + lp);
    *(float4*)&sC[ridx][lp] = *(const float4*)(xptr + rowL * 160 + DT_RANK + D_STATE + lp);
    __syncthreads();
    for (int s = 0; s < 64; ++s) {
      S += sd[s][c];
      float yt = __expf(An * S) * hl * sC[s][n];
      yt += __shfl_xor(yt, 1);
      yt += __shfl_xor(yt, 2);
      yt += __shfl_xor(yt, 4);
      yt += __shfl_xor(yt, 8);
      if (n == 0) {
        const int t = t0 + s;
        const int l = k ? (L_SEQ - 1 - t) : t;
        yptr[(size_t)l * D_INNER + d] += yt;
      }
    }
    __syncthreads();
  }
}

// ---------------------------------------------------------------------------
// y_gated = (y0 + y1) * z
// ---------------------------------------------------------------------------
__global__ __launch_bounds__(256) void gate_kernel(
    const float* __restrict__ y, const float* __restrict__ xz,
    float* __restrict__ yg) {
  const size_t total = (size_t)B_SZ * L_SEQ * D_INNER;
  size_t idx = ((size_t)blockIdx.x * 256 + threadIdx.x) * 4;
  if (idx >= total) return;
  const size_t m = idx / D_INNER;
  const size_t dd = idx % D_INNER;
  const float4 y0 = *(const float4*)(y + idx);
  const float4 y1 = *(const float4*)(y + total + idx);
  const float4 zv = *(const float4*)(xz + m * 3072 + 1536 + dd);
  float4 o;
  o.x = (y0.x + y1.x) * zv.x;
  o.y = (y0.y + y1.y) * zv.y;
  o.z = (y0.z + y1.z) * zv.z;
  o.w = (y0.w + y1.w) * zv.w;
  *(float4*)(yg + idx) = o;
}

// ---------------------------------------------------------------------------
extern "C" void kernel_launch(void* const* d_in, const int* in_sizes, int n_in,
                              void* d_out, int out_size, void* d_ws,
                              size_t ws_size, hipStream_t stream) {
  const float* x          = (const float*)d_in[0];
  const float* in_proj_w  = (const float*)d_in[1];
  const float* conv_w     = (const float*)d_in[2];
  const float* conv_b     = (const float*)d_in[3];
  const float* x_proj_w   = (const float*)d_in[4];
  const float* dt_proj_w  = (const float*)d_in[5];
  const float* dt_proj_b  = (const float*)d_in[6];
  const float* A_logs     = (const float*)d_in[7];
  const float* Ds         = (const float*)d_in[8];
  const float* out_proj_w = (const float*)d_in[9];
  float* out = (float*)d_out;

  const int M = B_SZ * L_SEQ;  // 4096

  float* ws    = (float*)d_ws;
  float* xz    = ws;                                  // [M,3072]
  float* u     = xz + (size_t)M * 3072;               // [M,1536]
  float* xdbl  = u + (size_t)M * 1536;                // [M,160]
  float* delta = xdbl + (size_t)M * 160;              // [2,M,1536]
  float* y     = delta + (size_t)2 * M * 1536;        // [2,M,1536]
  float* hfin  = y + (size_t)2 * M * 1536;            // [2*2*NCH*96*256]
  float* hin   = hfin + (size_t)2 * B_SZ * NCH * 96 * 256;
  float* Tsum  = hin + (size_t)2 * B_SZ * NCH * 96 * 256;  // [2*2*NCH*96*16]
  float* yg    = u;  // reuse (u dead after scan_local)

  dim3 blk(256);

  // 1. xz = x @ in_proj_w^T
  gemm_bt<0><<<dim3(3072 / 64, M / 64), blk, 0, stream>>>(
      x, D_MODEL, in_proj_w, D_MODEL, nullptr, xz, 3072, M, 3072, D_MODEL);

  // 2. u = silu(depthwise_conv(x_conv) + bias)
  conv_silu_kernel<<<dim3((M * (D_INNER / 4) + 255) / 256), blk, 0, stream>>>(
      xz, conv_w, conv_b, u);

  // 3. xdbl = u @ x_proj_w^T
  gemm_bt<0><<<dim3((160 + 63) / 64, M / 64), blk, 0, stream>>>(
      u, D_INNER, x_proj_w, D_INNER, nullptr, xdbl, 160, M, 160, D_INNER);

  // 4. delta_k = softplus(dt_in_k @ dt_proj_w_k^T + dt_proj_b_k)
  for (int k = 0; k < 2; ++k) {
    gemm_bt<1><<<dim3(D_INNER / 64, M / 64), blk, 0, stream>>>(
        xdbl + k * 80, 160, dt_proj_w + (size_t)k * D_INNER * DT_RANK, DT_RANK,
        dt_proj_b + k * D_INNER, delta + (size_t)k * M * D_INNER, D_INNER, M,
        D_INNER, DT_RANK);
  }

  // 5a. local chunk scans
  scan_local_kernel<<<dim3(2 * B_SZ * 96 * NCH), blk, 0, stream>>>(
      u, xdbl, delta, A_logs, Ds, y, hfin, Tsum);
  // 5b. stitch chunk states
  scan_stitch_kernel<<<dim3(2 * B_SZ * 96), blk, 0, stream>>>(
      hfin, Tsum, A_logs, hin);
  // 5c. fixup
  scan_fixup_kernel<<<dim3(2 * B_SZ * 96 * NCH), blk, 0, stream>>>(
      xdbl, delta, A_logs, hin, y);

  // 6. yg = (y0 + y1) * z
  gate_kernel<<<dim3((M * D_INNER / 4 + 255) / 256), blk, 0, stream>>>(y, xz, yg);

  // 7. out = yg @ out_proj_w^T
  gemm_bt<0><<<dim3(D_MODEL / 64, M / 64), blk, 0, stream>>>(
      yg, D_INNER, out_proj_w, D_INNER, nullptr, out, D_MODEL, M, D_MODEL,
      D_INNER);
}

// Round 3
// 614.030 us; speedup vs baseline: 1.7545x; 1.6733x over previous
//
#include <hip/hip_runtime.h>
#include <math.h>

#define D_MODEL 768
#define D_STATE 16
#define D_INNER 1536
#define DT_RANK 48
#define B_SZ    2
#define L_SEQ   2048
#define CH      128            // scan chunk length
#define NCH     (L_SEQ / CH)   // 16 chunks

typedef __bf16 bf16x8 __attribute__((ext_vector_type(8)));
typedef float f32x4 __attribute__((ext_vector_type(4)));

__device__ __forceinline__ ushort f2bf(float f) {
  unsigned int u = __float_as_uint(f);
  unsigned int r = (u + 0x7fff + ((u >> 16) & 1)) >> 16;
  return (ushort)r;
}

__device__ __forceinline__ void gload_lds16(const ushort* g, ushort* l) {
  __builtin_amdgcn_global_load_lds(
      (__attribute__((address_space(1))) void*)(void*)(g),
      (__attribute__((address_space(3))) void*)(void*)(l), 16, 0, 0);
}

// ---------------------------------------------------------------------------
// bf16 MFMA GEMM: C[M,N] = A[M,K](bf16) * B[N,K](bf16)^T  (+bias, +softplus)
// Grid covers M,N exactly (N padded); Nreal guards C writes. K % 32 == 0.
// 4 waves as 2x2; per-wave tile (BM/2)x(BN/2); BK=32; m97 2-barrier structure.
// ---------------------------------------------------------------------------
template <int BM, int BN, int ACT>
__global__ __launch_bounds__(256) void gemm_bf16(
    const ushort* __restrict__ A, int lda,
    const ushort* __restrict__ B, int ldb,
    const float* __restrict__ bias,
    float* __restrict__ C, int ldc, int Nreal, int K) {
  __shared__ ushort As[BM][32];
  __shared__ ushort Bs[BN][32];
  constexpr int WM = BM / 2, WN = BN / 2;
  constexpr int FM = WM / 16, FN = WN / 16;
  const int tid = threadIdx.x;
  const int lane = tid & 63;
  const int w = tid >> 6;
  const int wr = w >> 1, wc = w & 1;
  const int bm = blockIdx.y * BM, bn = blockIdx.x * BN;

  const int lrow = lane >> 2;    // 0..15 within a 16-row staging group
  const int lchunk = lane & 3;   // which 16B chunk of the 64B row

  f32x4 acc[FM][FN] = {};

  const int fr = lane & 15;
  const int k8 = (lane >> 4) * 8;

  for (int k0 = 0; k0 < K; k0 += 32) {
#pragma unroll
    for (int g = 0; g < BM / 64; ++g) {
      const int rb = w * (BM / 4) + g * 16;
      const ushort* gp = A + (size_t)(bm + rb + lrow) * lda + k0 + lchunk * 8;
      gload_lds16(gp, &As[rb][0]);
    }
#pragma unroll
    for (int g = 0; g < BN / 64; ++g) {
      const int rb = w * (BN / 4) + g * 16;
      const ushort* gp = B + (size_t)(bn + rb + lrow) * ldb + k0 + lchunk * 8;
      gload_lds16(gp, &Bs[rb][0]);
    }
    __syncthreads();
    bf16x8 af[FM], bfr[FN];
#pragma unroll
    for (int m = 0; m < FM; ++m)
      af[m] = *reinterpret_cast<const bf16x8*>(&As[wr * WM + m * 16 + fr][k8]);
#pragma unroll
    for (int n = 0; n < FN; ++n)
      bfr[n] = *reinterpret_cast<const bf16x8*>(&Bs[wc * WN + n * 16 + fr][k8]);
#pragma unroll
    for (int m = 0; m < FM; ++m)
#pragma unroll
      for (int n = 0; n < FN; ++n)
        acc[m][n] = __builtin_amdgcn_mfma_f32_16x16x32_bf16(af[m], bfr[n],
                                                            acc[m][n], 0, 0, 0);
    __syncthreads();
  }

  const int row4 = (lane >> 4) * 4;
#pragma unroll
  for (int m = 0; m < FM; ++m) {
#pragma unroll
    for (int n = 0; n < FN; ++n) {
      const int gn = bn + wc * WN + n * 16 + fr;
      if (gn >= Nreal) continue;
      const int gm0 = bm + wr * WM + m * 16 + row4;
      const float bv = bias ? bias[gn] : 0.f;
#pragma unroll
      for (int j = 0; j < 4; ++j) {
        float v = acc[m][n][j] + bv;
        if (ACT == 1) v = (v > 20.f) ? v : log1pf(__expf(v));
        C[(size_t)(gm0 + j) * ldc + gn] = v;
      }
    }
  }
}

// ---------------------------------------------------------------------------
// fp32 -> bf16 converters
// ---------------------------------------------------------------------------
__global__ __launch_bounds__(256) void cvt_bf16_kernel(
    const float* __restrict__ s, ushort* __restrict__ d, int n) {
  int i = (blockIdx.x * 256 + threadIdx.x) * 4;
  if (i >= n) return;
  const float4 v = *(const float4*)(s + i);
  ushort4 o;
  o.x = f2bf(v.x); o.y = f2bf(v.y); o.z = f2bf(v.z); o.w = f2bf(v.w);
  *(ushort4*)(d + i) = o;
}

// x_proj_w [160,1536] -> [256,1536] bf16 (zero rows >= 160)
__global__ __launch_bounds__(256) void cvt_xprojw_kernel(
    const float* __restrict__ s, ushort* __restrict__ d) {
  int i = (blockIdx.x * 256 + threadIdx.x) * 4;
  if (i >= 256 * 1536) return;
  const int row = i / 1536;
  ushort4 o = {0, 0, 0, 0};
  if (row < 160) {
    const float4 v = *(const float4*)(s + i);
    o.x = f2bf(v.x); o.y = f2bf(v.y); o.z = f2bf(v.z); o.w = f2bf(v.w);
  }
  *(ushort4*)(d + i) = o;
}

// dt_proj_w [2*1536,48] -> [2*1536,64] bf16 (zero cols >= 48)
__global__ __launch_bounds__(256) void cvt_dtw_kernel(
    const float* __restrict__ s, ushort* __restrict__ d) {
  int i = (blockIdx.x * 256 + threadIdx.x) * 4;
  if (i >= 2 * 1536 * 64) return;
  const int col = i & 63;
  const int row = i >> 6;
  ushort4 o = {0, 0, 0, 0};
  if (col < 48) {
    const float4 v = *(const float4*)(s + row * 48 + col);
    o.x = f2bf(v.x); o.y = f2bf(v.y); o.z = f2bf(v.z); o.w = f2bf(v.w);
  }
  *(ushort4*)(d + i) = o;
}

// xdbl [M,160] -> dtin [2,M,64] bf16 (cols 0..47 from k*80.., rest zero)
__global__ __launch_bounds__(256) void cvt_dtin_kernel(
    const float* __restrict__ xdbl, ushort* __restrict__ d) {
  const int M = B_SZ * L_SEQ;
  int i = (blockIdx.x * 256 + threadIdx.x) * 4;
  if (i >= 2 * M * 64) return;
  const int col = i & 63;
  const int m = (i >> 6) % M;
  const int k = i / (M * 64);
  ushort4 o = {0, 0, 0, 0};
  if (col < 48) {
    const float4 v = *(const float4*)(xdbl + (size_t)m * 160 + k * 80 + col);
    o.x = f2bf(v.x); o.y = f2bf(v.y); o.z = f2bf(v.z); o.w = f2bf(v.w);
  }
  *(ushort4*)(d + i) = o;
}

// ---------------------------------------------------------------------------
// Depthwise conv (k=3, pad=1) + bias + SiLU. Emits u (fp32) and u_bf (bf16).
// ---------------------------------------------------------------------------
__global__ __launch_bounds__(256) void conv_silu_kernel(
    const float* __restrict__ xz, const float* __restrict__ cw,
    const float* __restrict__ cb, float* __restrict__ u,
    ushort* __restrict__ u_bf) {
  const int nd4 = D_INNER / 4;
  int idx = blockIdx.x * 256 + threadIdx.x;
  if (idx >= B_SZ * L_SEQ * nd4) return;
  const int d = (idx % nd4) * 4;
  const int l = (idx / nd4) % L_SEQ;
  const int b = idx / (nd4 * L_SEQ);
  float a0 = cb[d + 0], a1 = cb[d + 1], a2 = cb[d + 2], a3 = cb[d + 3];
#pragma unroll
  for (int j = 0; j < 3; ++j) {
    const int ll = l + j - 1;
    if (ll < 0 || ll >= L_SEQ) continue;
    const float4 xv = *(const float4*)(xz + ((size_t)b * L_SEQ + ll) * 3072 + d);
    a0 += xv.x * cw[(d + 0) * 3 + j];
    a1 += xv.y * cw[(d + 1) * 3 + j];
    a2 += xv.z * cw[(d + 2) * 3 + j];
    a3 += xv.w * cw[(d + 3) * 3 + j];
  }
  float4 o;
  o.x = a0 / (1.f + __expf(-a0));
  o.y = a1 / (1.f + __expf(-a1));
  o.z = a2 / (1.f + __expf(-a2));
  o.w = a3 / (1.f + __expf(-a3));
  const size_t off = ((size_t)b * L_SEQ + l) * D_INNER + d;
  *(float4*)(u + off) = o;
  ushort4 ob;
  ob.x = f2bf(o.x); ob.y = f2bf(o.y); ob.z = f2bf(o.z); ob.w = f2bf(o.w);
  *(ushort4*)(u_bf + off) = ob;
}

// ---------------------------------------------------------------------------
// K1: local scan per chunk (h0 = 0).
// ---------------------------------------------------------------------------
__global__ __launch_bounds__(256) void scan_local_kernel(
    const float* __restrict__ u, const float* __restrict__ xdbl,
    const float* __restrict__ delta, const float* __restrict__ A_logs,
    const float* __restrict__ Ds, float* __restrict__ y,
    float* __restrict__ hfin, float* __restrict__ Tsum) {
  __shared__ float sd[64][16], su[64][16], sB[64][16], sC[64][16];
  const int tid = threadIdx.x;
  const int c = tid >> 4;
  const int n = tid & 15;
  int bid = blockIdx.x;
  const int ch = bid % NCH;
  const int dg = (bid / NCH) % 96;
  const int b = (bid / (NCH * 96)) & 1;
  const int k = bid / (NCH * 96 * 2);
  const int d0 = dg * 16;
  const int d = d0 + c;
  const int row = k * D_INNER + d;
  const float An = -__expf(A_logs[row * D_STATE + n]);
  const float Dk = Ds[row];
  const float* uptr = u + ((size_t)b * L_SEQ) * D_INNER;
  const float* dptr = delta + ((size_t)(k * B_SZ + b) * L_SEQ) * D_INNER;
  const float* xptr = xdbl + ((size_t)b * L_SEQ) * 160 + k * 80;
  float* yptr = y + ((size_t)(k * B_SZ + b) * L_SEQ) * D_INNER;

  const int lr = tid >> 2;
  const int lp = (tid & 3) << 2;
  const int ridx = k ? (63 - lr) : lr;

  float h = 0.f, S = 0.f;
  for (int sub = 0; sub < CH / 64; ++sub) {
    const int t0 = ch * CH + sub * 64;
    const int lbase = k ? (L_SEQ - 64 - t0) : t0;
    const size_t rowL = (size_t)(lbase + lr);
    *(float4*)&sd[ridx][lp] = *(const float4*)(dptr + rowL * D_INNER + d0 + lp);
    *(float4*)&su[ridx][lp] = *(const float4*)(uptr + rowL * D_INNER + d0 + lp);
    *(float4*)&sB[ridx][lp] = *(const float4*)(xptr + rowL * 160 + DT_RANK + lp);
    *(float4*)&sC[ridx][lp] = *(const float4*)(xptr + rowL * 160 + DT_RANK + D_STATE + lp);
    __syncthreads();
    for (int s = 0; s < 64; ++s) {
      const float dlt = sd[s][c];
      const float uu = su[s][c];
      S += dlt;
      h = h * __expf(dlt * An) + dlt * uu * sB[s][n];
      float yt = h * sC[s][n];
      yt += __shfl_xor(yt, 1);
      yt += __shfl_xor(yt, 2);
      yt += __shfl_xor(yt, 4);
      yt += __shfl_xor(yt, 8);
      if (n == 0) {
        const int t = t0 + s;
        const int l = k ? (L_SEQ - 1 - t) : t;
        yptr[(size_t)l * D_INNER + d] = yt + uu * Dk;
      }
    }
    __syncthreads();
  }
  const size_t cidx = ((size_t)(k * B_SZ + b) * NCH + ch) * 96 + dg;
  hfin[cidx * 256 + tid] = h;
  if (n == 0) Tsum[cidx * 16 + c] = S;
}

// ---------------------------------------------------------------------------
// K2: stitch chunk states sequentially.
// ---------------------------------------------------------------------------
__global__ __launch_bounds__(256) void scan_stitch_kernel(
    const float* __restrict__ hfin, const float* __restrict__ Tsum,
    const float* __restrict__ A_logs, float* __restrict__ hin) {
  const int tid = threadIdx.x;
  const int c = tid >> 4;
  const int n = tid & 15;
  const int bid = blockIdx.x;
  const int dg = bid % 96;
  const int b = (bid / 96) & 1;
  const int k = bid / 192;
  const int row = k * D_INNER + dg * 16 + c;
  const float An = -__expf(A_logs[row * D_STATE + n]);
  float carry = 0.f;
  for (int ch = 0; ch < NCH; ++ch) {
    const size_t cidx = ((size_t)(k * B_SZ + b) * NCH + ch) * 96 + dg;
    hin[cidx * 256 + tid] = carry;
    const float T = Tsum[cidx * 16 + c];
    carry = carry * __expf(An * T) + hfin[cidx * 256 + tid];
  }
}

// ---------------------------------------------------------------------------
// K3: fixup — y_t += sum_n C_tn * exp(An*S_t) * hin_n.
// ---------------------------------------------------------------------------
__global__ __launch_bounds__(256) void scan_fixup_kernel(
    const float* __restrict__ xdbl, const float* __restrict__ delta,
    const float* __restrict__ A_logs, const float* __restrict__ hin,
    float* __restrict__ y) {
  __shared__ float sd[64][16], sC[64][16];
  const int tid = threadIdx.x;
  const int c = tid >> 4;
  const int n = tid & 15;
  int bid = blockIdx.x;
  const int ch = bid % NCH;
  const int dg = (bid / NCH) % 96;
  const int b = (bid / (NCH * 96)) & 1;
  const int k = bid / (NCH * 96 * 2);
  const int d0 = dg * 16;
  const int d = d0 + c;
  const int row = k * D_INNER + d;
  const float An = -__expf(A_logs[row * D_STATE + n]);
  const size_t cidx = ((size_t)(k * B_SZ + b) * NCH + ch) * 96 + dg;
  const float hl = hin[cidx * 256 + tid];
  const float* dptr = delta + ((size_t)(k * B_SZ + b) * L_SEQ) * D_INNER;
  const float* xptr = xdbl + ((size_t)b * L_SEQ) * 160 + k * 80;
  float* yptr = y + ((size_t)(k * B_SZ + b) * L_SEQ) * D_INNER;

  const int lr = tid >> 2;
  const int lp = (tid & 3) << 2;
  const int ridx = k ? (63 - lr) : lr;

  float S = 0.f;
  for (int sub = 0; sub < CH / 64; ++sub) {
    const int t0 = ch * CH + sub * 64;
    const int lbase = k ? (L_SEQ - 64 - t0) : t0;
    const size_t rowL = (size_t)(lbase + lr);
    *(float4*)&sd[ridx][lp] = *(const float4*)(dptr + rowL * D_INNER + d0 + lp);
    *(float4*)&sC[ridx][lp] = *(const float4*)(xptr + rowL * 160 + DT_RANK + D_STATE + lp);
    __syncthreads();
    for (int s = 0; s < 64; ++s) {
      S += sd[s][c];
      float yt = __expf(An * S) * hl * sC[s][n];
      yt += __shfl_xor(yt, 1);
      yt += __shfl_xor(yt, 2);
      yt += __shfl_xor(yt, 4);
      yt += __shfl_xor(yt, 8);
      if (n == 0) {
        const int t = t0 + s;
        const int l = k ? (L_SEQ - 1 - t) : t;
        yptr[(size_t)l * D_INNER + d] += yt;
      }
    }
    __syncthreads();
  }
}

// ---------------------------------------------------------------------------
// y_gated = (y0 + y1) * z  -> bf16
// ---------------------------------------------------------------------------
__global__ __launch_bounds__(256) void gate_kernel(
    const float* __restrict__ y, const float* __restrict__ xz,
    ushort* __restrict__ yg) {
  const size_t total = (size_t)B_SZ * L_SEQ * D_INNER;
  size_t idx = ((size_t)blockIdx.x * 256 + threadIdx.x) * 4;
  if (idx >= total) return;
  const size_t m = idx / D_INNER;
  const size_t dd = idx % D_INNER;
  const float4 y0 = *(const float4*)(y + idx);
  const float4 y1 = *(const float4*)(y + total + idx);
  const float4 zv = *(const float4*)(xz + m * 3072 + 1536 + dd);
  ushort4 o;
  o.x = f2bf((y0.x + y1.x) * zv.x);
  o.y = f2bf((y0.y + y1.y) * zv.y);
  o.z = f2bf((y0.z + y1.z) * zv.z);
  o.w = f2bf((y0.w + y1.w) * zv.w);
  *(ushort4*)(yg + idx) = o;
}

// ---------------------------------------------------------------------------
extern "C" void kernel_launch(void* const* d_in, const int* in_sizes, int n_in,
                              void* d_out, int out_size, void* d_ws,
                              size_t ws_size, hipStream_t stream) {
  const float* x          = (const float*)d_in[0];
  const float* in_proj_w  = (const float*)d_in[1];
  const float* conv_w     = (const float*)d_in[2];
  const float* conv_b     = (const float*)d_in[3];
  const float* x_proj_w   = (const float*)d_in[4];
  const float* dt_proj_w  = (const float*)d_in[5];
  const float* dt_proj_b  = (const float*)d_in[6];
  const float* A_logs     = (const float*)d_in[7];
  const float* Ds         = (const float*)d_in[8];
  const float* out_proj_w = (const float*)d_in[9];
  float* out = (float*)d_out;

  const int M = B_SZ * L_SEQ;  // 4096

  float* ws    = (float*)d_ws;
  float* xz    = ws;                                  // [M,3072]
  float* u     = xz + (size_t)M * 3072;               // [M,1536]
  float* xdbl  = u + (size_t)M * 1536;                // [M,160]
  float* delta = xdbl + (size_t)M * 160;              // [2,M,1536]
  float* y     = delta + (size_t)2 * M * 1536;        // [2,M,1536]
  float* hfin  = y + (size_t)2 * M * 1536;
  float* hin   = hfin + (size_t)2 * B_SZ * NCH * 96 * 256;
  float* Tsum  = hin + (size_t)2 * B_SZ * NCH * 96 * 256;
  ushort* w_out_bf = (ushort*)(Tsum + (size_t)2 * B_SZ * NCH * 96 * 16);

  // bf16 scratch overlaid on y (all dead before scan_local writes y)
  ushort* x_bf    = (ushort*)y;                  // 3,145,728
  ushort* w_in_bf = x_bf + (size_t)M * 768;      // 2,359,296
  ushort* w_xp_bf = w_in_bf + (size_t)3072 * 768;  // 393,216
  ushort* w_dt_bf = w_xp_bf + (size_t)256 * 1536;  // 196,608
  ushort* u_bf    = w_dt_bf + (size_t)2 * 1536 * 64;  // 6,291,456
  ushort* dtin    = u_bf + (size_t)M * 1536;     // 524,288
  // gate output overlaid on delta (dead after fixup)
  ushort* yg_bf   = (ushort*)delta;

  dim3 blk(256);

  // 0. conversions
  cvt_bf16_kernel<<<dim3(M * 768 / 4 / 256), blk, 0, stream>>>(x, x_bf, M * 768);
  cvt_bf16_kernel<<<dim3(3072 * 768 / 4 / 256), blk, 0, stream>>>(
      in_proj_w, w_in_bf, 3072 * 768);
  cvt_bf16_kernel<<<dim3(768 * 1536 / 4 / 256), blk, 0, stream>>>(
      out_proj_w, w_out_bf, 768 * 1536);
  cvt_xprojw_kernel<<<dim3(256 * 1536 / 4 / 256), blk, 0, stream>>>(x_proj_w,
                                                                    w_xp_bf);
  cvt_dtw_kernel<<<dim3(2 * 1536 * 64 / 4 / 256), blk, 0, stream>>>(dt_proj_w,
                                                                    w_dt_bf);

  // 1. xz = x @ in_proj_w^T   (M=4096, N=3072, K=768)
  gemm_bf16<128, 128, 0><<<dim3(3072 / 128, M / 128), blk, 0, stream>>>(
      x_bf, 768, w_in_bf, 768, nullptr, xz, 3072, 3072, 768);

  // 2. u = silu(conv(x_conv)+bias)  (fp32 + bf16)
  conv_silu_kernel<<<dim3((M * (D_INNER / 4) + 255) / 256), blk, 0, stream>>>(
      xz, conv_w, conv_b, u, u_bf);

  // 3. xdbl = u @ x_proj_w^T  (M=4096, N=256 padded / 160 real, K=1536)
  gemm_bf16<64, 64, 0><<<dim3(256 / 64, M / 64), blk, 0, stream>>>(
      u_bf, 1536, w_xp_bf, 1536, nullptr, xdbl, 160, 160, 1536);

  // 4. dtin = pad(xdbl dt cols) bf16
  cvt_dtin_kernel<<<dim3(2 * M * 64 / 4 / 256), blk, 0, stream>>>(xdbl, dtin);

  // 5. delta_k = softplus(dtin_k @ dtw_k^T + dtb_k)  (N=1536, K=64)
  for (int k = 0; k < 2; ++k) {
    gemm_bf16<128, 128, 1><<<dim3(1536 / 128, M / 128), blk, 0, stream>>>(
        dtin + (size_t)k * M * 64, 64, w_dt_bf + (size_t)k * 1536 * 64, 64,
        dt_proj_b + k * 1536, delta + (size_t)k * M * 1536, 1536, 1536, 64);
  }

  // 6. scan
  scan_local_kernel<<<dim3(2 * B_SZ * 96 * NCH), blk, 0, stream>>>(
      u, xdbl, delta, A_logs, Ds, y, hfin, Tsum);
  scan_stitch_kernel<<<dim3(2 * B_SZ * 96), blk, 0, stream>>>(hfin, Tsum,
                                                              A_logs, hin);
  scan_fixup_kernel<<<dim3(2 * B_SZ * 96 * NCH), blk, 0, stream>>>(
      xdbl, delta, A_logs, hin, y);

  // 7. yg = (y0 + y1) * z -> bf16
  gate_kernel<<<dim3((M * D_INNER / 4 + 255) / 256), blk, 0, stream>>>(y, xz,
                                                                       yg_bf);

  // 8. out = yg @ out_proj_w^T  (M=4096, N=768, K=1536)
  gemm_bf16<128, 128, 0><<<dim3(768 / 128, M / 128), blk, 0, stream>>>(
      yg_bf, 1536, w_out_bf, 1536, nullptr, out, 768, 768, 1536);
}

// Round 4
// 323.937 us; speedup vs baseline: 3.3257x; 1.8955x over previous
//
#include <hip/hip_runtime.h>
#include <math.h>

#define D_MODEL 768
#define D_STATE 16
#define D_INNER 1536
#define DT_RANK 48
#define B_SZ    2
#define L_SEQ   2048
#define CH      128            // scan chunk length
#define NCH     (L_SEQ / CH)   // 16 chunks
#define NDG     24             // d-groups of 64 channels

typedef __bf16 bf16x8 __attribute__((ext_vector_type(8)));
typedef float f32x4 __attribute__((ext_vector_type(4)));

__device__ __forceinline__ ushort f2bf(float f) {
  unsigned int u = __float_as_uint(f);
  unsigned int r = (u + 0x7fff + ((u >> 16) & 1)) >> 16;
  return (ushort)r;
}

__device__ __forceinline__ void gload_lds16(const ushort* g, ushort* l) {
  __builtin_amdgcn_global_load_lds(
      (__attribute__((address_space(1))) void*)(void*)(g),
      (__attribute__((address_space(3))) void*)(void*)(l), 16, 0, 0);
}

// ---------------------------------------------------------------------------
// bf16 MFMA GEMM: C[M,N] = A[M,K](bf16) * B[N,K](bf16)^T  (+bias, +softplus)
// ---------------------------------------------------------------------------
template <int BM, int BN, int ACT>
__global__ __launch_bounds__(256) void gemm_bf16(
    const ushort* __restrict__ A, int lda,
    const ushort* __restrict__ B, int ldb,
    const float* __restrict__ bias,
    float* __restrict__ C, int ldc, int Nreal, int K) {
  __shared__ ushort As[BM][32];
  __shared__ ushort Bs[BN][32];
  constexpr int WM = BM / 2, WN = BN / 2;
  constexpr int FM = WM / 16, FN = WN / 16;
  const int tid = threadIdx.x;
  const int lane = tid & 63;
  const int w = tid >> 6;
  const int wr = w >> 1, wc = w & 1;
  const int bm = blockIdx.y * BM, bn = blockIdx.x * BN;

  const int lrow = lane >> 2;
  const int lchunk = lane & 3;

  f32x4 acc[FM][FN] = {};

  const int fr = lane & 15;
  const int k8 = (lane >> 4) * 8;

  for (int k0 = 0; k0 < K; k0 += 32) {
#pragma unroll
    for (int g = 0; g < BM / 64; ++g) {
      const int rb = w * (BM / 4) + g * 16;
      const ushort* gp = A + (size_t)(bm + rb + lrow) * lda + k0 + lchunk * 8;
      gload_lds16(gp, &As[rb][0]);
    }
#pragma unroll
    for (int g = 0; g < BN / 64; ++g) {
      const int rb = w * (BN / 4) + g * 16;
      const ushort* gp = B + (size_t)(bn + rb + lrow) * ldb + k0 + lchunk * 8;
      gload_lds16(gp, &Bs[rb][0]);
    }
    __syncthreads();
    bf16x8 af[FM], bfr[FN];
#pragma unroll
    for (int m = 0; m < FM; ++m)
      af[m] = *reinterpret_cast<const bf16x8*>(&As[wr * WM + m * 16 + fr][k8]);
#pragma unroll
    for (int n = 0; n < FN; ++n)
      bfr[n] = *reinterpret_cast<const bf16x8*>(&Bs[wc * WN + n * 16 + fr][k8]);
#pragma unroll
    for (int m = 0; m < FM; ++m)
#pragma unroll
      for (int n = 0; n < FN; ++n)
        acc[m][n] = __builtin_amdgcn_mfma_f32_16x16x32_bf16(af[m], bfr[n],
                                                            acc[m][n], 0, 0, 0);
    __syncthreads();
  }

  const int row4 = (lane >> 4) * 4;
#pragma unroll
  for (int m = 0; m < FM; ++m) {
#pragma unroll
    for (int n = 0; n < FN; ++n) {
      const int gn = bn + wc * WN + n * 16 + fr;
      if (gn >= Nreal) continue;
      const int gm0 = bm + wr * WM + m * 16 + row4;
      const float bv = bias ? bias[gn] : 0.f;
#pragma unroll
      for (int j = 0; j < 4; ++j) {
        float v = acc[m][n][j] + bv;
        if (ACT == 1) v = (v > 20.f) ? v : log1pf(__expf(v));
        C[(size_t)(gm0 + j) * ldc + gn] = v;
      }
    }
  }
}

// ---------------------------------------------------------------------------
// fp32 -> bf16 converters
// ---------------------------------------------------------------------------
__global__ __launch_bounds__(256) void cvt_bf16_kernel(
    const float* __restrict__ s, ushort* __restrict__ d, int n) {
  int i = (blockIdx.x * 256 + threadIdx.x) * 4;
  if (i >= n) return;
  const float4 v = *(const float4*)(s + i);
  ushort4 o;
  o.x = f2bf(v.x); o.y = f2bf(v.y); o.z = f2bf(v.z); o.w = f2bf(v.w);
  *(ushort4*)(d + i) = o;
}

__global__ __launch_bounds__(256) void cvt_xprojw_kernel(
    const float* __restrict__ s, ushort* __restrict__ d) {
  int i = (blockIdx.x * 256 + threadIdx.x) * 4;
  if (i >= 256 * 1536) return;
  const int row = i / 1536;
  ushort4 o = {0, 0, 0, 0};
  if (row < 160) {
    const float4 v = *(const float4*)(s + i);
    o.x = f2bf(v.x); o.y = f2bf(v.y); o.z = f2bf(v.z); o.w = f2bf(v.w);
  }
  *(ushort4*)(d + i) = o;
}

__global__ __launch_bounds__(256) void cvt_dtw_kernel(
    const float* __restrict__ s, ushort* __restrict__ d) {
  int i = (blockIdx.x * 256 + threadIdx.x) * 4;
  if (i >= 2 * 1536 * 64) return;
  const int col = i & 63;
  const int row = i >> 6;
  ushort4 o = {0, 0, 0, 0};
  if (col < 48) {
    const float4 v = *(const float4*)(s + row * 48 + col);
    o.x = f2bf(v.x); o.y = f2bf(v.y); o.z = f2bf(v.z); o.w = f2bf(v.w);
  }
  *(ushort4*)(d + i) = o;
}

__global__ __launch_bounds__(256) void cvt_dtin_kernel(
    const float* __restrict__ xdbl, ushort* __restrict__ d) {
  const int M = B_SZ * L_SEQ;
  int i = (blockIdx.x * 256 + threadIdx.x) * 4;
  if (i >= 2 * M * 64) return;
  const int col = i & 63;
  const int m = (i >> 6) % M;
  const int k = i / (M * 64);
  ushort4 o = {0, 0, 0, 0};
  if (col < 48) {
    const float4 v = *(const float4*)(xdbl + (size_t)m * 160 + k * 80 + col);
    o.x = f2bf(v.x); o.y = f2bf(v.y); o.z = f2bf(v.z); o.w = f2bf(v.w);
  }
  *(ushort4*)(d + i) = o;
}

// ---------------------------------------------------------------------------
// Depthwise conv (k=3, pad=1) + bias + SiLU. Emits u (fp32) and u_bf (bf16).
// ---------------------------------------------------------------------------
__global__ __launch_bounds__(256) void conv_silu_kernel(
    const float* __restrict__ xz, const float* __restrict__ cw,
    const float* __restrict__ cb, float* __restrict__ u,
    ushort* __restrict__ u_bf) {
  const int nd4 = D_INNER / 4;
  int idx = blockIdx.x * 256 + threadIdx.x;
  if (idx >= B_SZ * L_SEQ * nd4) return;
  const int d = (idx % nd4) * 4;
  const int l = (idx / nd4) % L_SEQ;
  const int b = idx / (nd4 * L_SEQ);
  float a0 = cb[d + 0], a1 = cb[d + 1], a2 = cb[d + 2], a3 = cb[d + 3];
#pragma unroll
  for (int j = 0; j < 3; ++j) {
    const int ll = l + j - 1;
    if (ll < 0 || ll >= L_SEQ) continue;
    const float4 xv = *(const float4*)(xz + ((size_t)b * L_SEQ + ll) * 3072 + d);
    a0 += xv.x * cw[(d + 0) * 3 + j];
    a1 += xv.y * cw[(d + 1) * 3 + j];
    a2 += xv.z * cw[(d + 2) * 3 + j];
    a3 += xv.w * cw[(d + 3) * 3 + j];
  }
  float4 o;
  o.x = a0 / (1.f + __expf(-a0));
  o.y = a1 / (1.f + __expf(-a1));
  o.z = a2 / (1.f + __expf(-a2));
  o.w = a3 / (1.f + __expf(-a3));
  const size_t off = ((size_t)b * L_SEQ + l) * D_INNER + d;
  *(float4*)(u + off) = o;
  ushort4 ob;
  ob.x = f2bf(o.x); ob.y = f2bf(o.y); ob.z = f2bf(o.z); ob.w = f2bf(o.w);
  *(ushort4*)(u_bf + off) = ob;
}

// ---------------------------------------------------------------------------
// K1: local scan. Block = (k,b,dgB of 64 ch, chunk). Wave = 16 d x 4 nq.
// Each lane holds h[4] (4 states). 2 shuffles/step (xor16, xor32).
// State layout: hfin[cidxB*1024 + dl*16 + n], Tsum[cidxB*64 + dl].
// ---------------------------------------------------------------------------
__global__ __launch_bounds__(256) void scan_local_kernel(
    const float* __restrict__ u, const float* __restrict__ xdbl,
    const float* __restrict__ delta, const float* __restrict__ A_logs,
    const float* __restrict__ Ds, float* __restrict__ y,
    float* __restrict__ hfin, float* __restrict__ Tsum) {
  __shared__ float sd[32][64], su[32][64], sB[32][16], sC[32][16];
  const int tid = threadIdx.x;
  const int lane = tid & 63;
  const int w = tid >> 6;
  const int c = lane & 15;
  const int nq = lane >> 4;            // 0..3
  const int bid = blockIdx.x;
  const int ch = bid & 15;
  const int rest = bid >> 4;
  const int dgB = rest % NDG;
  const int kb = rest / NDG;
  const int b = kb & 1;
  const int k = kb >> 1;
  const int d0 = dgB * 64;
  const int dl = w * 16 + c;
  const int d = d0 + dl;
  const int row = k * D_INNER + d;

  const float4 alv = *(const float4*)(A_logs + (size_t)row * D_STATE + nq * 4);
  const float An0 = -__expf(alv.x), An1 = -__expf(alv.y);
  const float An2 = -__expf(alv.z), An3 = -__expf(alv.w);
  const float Dk = Ds[row];

  const float* uptr = u + ((size_t)b * L_SEQ) * D_INNER;
  const float* dptr = delta + ((size_t)(k * B_SZ + b) * L_SEQ) * D_INNER;
  const float* xptr = xdbl + ((size_t)b * L_SEQ) * 160 + k * 80;
  float* yptr = y + ((size_t)(k * B_SZ + b) * L_SEQ) * D_INNER;

  float h0 = 0.f, h1 = 0.f, h2 = 0.f, h3 = 0.f, S = 0.f;

  for (int sub = 0; sub < CH / 32; ++sub) {
    const int t0 = ch * CH + sub * 32;
    const int lbase = k ? (L_SEQ - 32 - t0) : t0;
    // stage delta/u: [32][64]
#pragma unroll
    for (int i = 0; i < 2; ++i) {
      const int r = (tid >> 4) + i * 16;
      const int ridx = k ? (31 - r) : r;
      const int colq = (tid & 15) * 4;
      const size_t rowL = (size_t)(lbase + r);
      *(float4*)&sd[ridx][colq] = *(const float4*)(dptr + rowL * D_INNER + d0 + colq);
      *(float4*)&su[ridx][colq] = *(const float4*)(uptr + rowL * D_INNER + d0 + colq);
    }
    // stage B/C: [32][16]
    {
      const int t2 = tid & 127;
      const int r = t2 >> 2;
      const int ridx = k ? (31 - r) : r;
      const int c4 = (t2 & 3) * 4;
      const size_t rowL = (size_t)(lbase + r);
      if (tid < 128)
        *(float4*)&sB[ridx][c4] = *(const float4*)(xptr + rowL * 160 + DT_RANK + c4);
      else
        *(float4*)&sC[ridx][c4] = *(const float4*)(xptr + rowL * 160 + DT_RANK + D_STATE + c4);
    }
    __syncthreads();
    for (int s = 0; s < 32; ++s) {
      const float dlt = sd[s][dl];
      const float uu = su[s][dl];
      S += dlt;
      const float4 Bv = *(const float4*)&sB[s][nq * 4];
      const float4 Cv = *(const float4*)&sC[s][nq * 4];
      const float du = dlt * uu;
      h0 = h0 * __expf(dlt * An0) + du * Bv.x;
      h1 = h1 * __expf(dlt * An1) + du * Bv.y;
      h2 = h2 * __expf(dlt * An2) + du * Bv.z;
      h3 = h3 * __expf(dlt * An3) + du * Bv.w;
      float yt = h0 * Cv.x + h1 * Cv.y + h2 * Cv.z + h3 * Cv.w;
      yt += __shfl_xor(yt, 16);
      yt += __shfl_xor(yt, 32);
      if (nq == 0) {
        const int t = t0 + s;
        const int l = k ? (L_SEQ - 1 - t) : t;
        yptr[(size_t)l * D_INNER + d] = yt + uu * Dk;
      }
    }
    __syncthreads();
  }

  const size_t cidxB = ((size_t)(k * B_SZ + b) * NCH + ch) * NDG + dgB;
  float4 hv = make_float4(h0, h1, h2, h3);
  *(float4*)(hfin + cidxB * 1024 + dl * 16 + nq * 4) = hv;
  if (nq == 0) Tsum[cidxB * 64 + dl] = S;
}

// ---------------------------------------------------------------------------
// K2: stitch. Block = (k,b,dgB). Thread = (dl = tid>>2, nq = tid&3), float4.
// ---------------------------------------------------------------------------
__global__ __launch_bounds__(256) void scan_stitch_kernel(
    const float* __restrict__ hfin, const float* __restrict__ Tsum,
    const float* __restrict__ A_logs, float* __restrict__ hin) {
  const int tid = threadIdx.x;
  const int dl = tid >> 2;
  const int nq = tid & 3;
  const int bid = blockIdx.x;
  const int dgB = bid % NDG;
  const int b = (bid / NDG) & 1;
  const int k = bid / (NDG * 2);
  const int row = k * D_INNER + dgB * 64 + dl;
  const float4 alv = *(const float4*)(A_logs + (size_t)row * D_STATE + nq * 4);
  const float An0 = -__expf(alv.x), An1 = -__expf(alv.y);
  const float An2 = -__expf(alv.z), An3 = -__expf(alv.w);
  float c0 = 0.f, c1 = 0.f, c2 = 0.f, c3 = 0.f;
  for (int ch = 0; ch < NCH; ++ch) {
    const size_t cidxB = ((size_t)(k * B_SZ + b) * NCH + ch) * NDG + dgB;
    const size_t off = cidxB * 1024 + dl * 16 + nq * 4;
    *(float4*)(hin + off) = make_float4(c0, c1, c2, c3);
    const float T = Tsum[cidxB * 64 + dl];
    const float4 hf = *(const float4*)(hfin + off);
    c0 = c0 * __expf(An0 * T) + hf.x;
    c1 = c1 * __expf(An1 * T) + hf.y;
    c2 = c2 * __expf(An2 * T) + hf.z;
    c3 = c3 * __expf(An3 * T) + hf.w;
  }
}

// ---------------------------------------------------------------------------
// K3: fixup, shuffle-free. Block = (k,b,dgB of 64 ch, chunk).
// Thread = (wave tq = tid>>6 owning 16 t's per sub, dl = tid&63).
// h[16], An[16] in registers; S via per-sub LDS prefix.
// ---------------------------------------------------------------------------
__global__ __launch_bounds__(256) void scan_fixup_kernel(
    const float* __restrict__ xdbl, const float* __restrict__ delta,
    const float* __restrict__ A_logs, const float* __restrict__ hin,
    float* __restrict__ y) {
  __shared__ float sd[64][64], sC[64][16], sOct[64][4];
  const int tid = threadIdx.x;
  const int tq = tid >> 6;   // wave id = t-quarter
  const int dl = tid & 63;
  const int bid = blockIdx.x;
  const int ch = bid & 15;
  const int rest = bid >> 4;
  const int dgB = rest % NDG;
  const int kb = rest / NDG;
  const int b = kb & 1;
  const int k = kb >> 1;
  const int d0 = dgB * 64;
  const int d = d0 + dl;
  const int row = k * D_INNER + d;

  float An[16], h[16];
#pragma unroll
  for (int q = 0; q < 4; ++q) {
    const float4 alv = *(const float4*)(A_logs + (size_t)row * D_STATE + q * 4);
    An[q * 4 + 0] = -__expf(alv.x);
    An[q * 4 + 1] = -__expf(alv.y);
    An[q * 4 + 2] = -__expf(alv.z);
    An[q * 4 + 3] = -__expf(alv.w);
  }
  const size_t cidxB = ((size_t)(k * B_SZ + b) * NCH + ch) * NDG + dgB;
#pragma unroll
  for (int q = 0; q < 4; ++q) {
    const float4 hv = *(const float4*)(hin + cidxB * 1024 + dl * 16 + q * 4);
    h[q * 4 + 0] = hv.x; h[q * 4 + 1] = hv.y;
    h[q * 4 + 2] = hv.z; h[q * 4 + 3] = hv.w;
  }

  const float* dptr = delta + ((size_t)(k * B_SZ + b) * L_SEQ) * D_INNER;
  const float* xptr = xdbl + ((size_t)b * L_SEQ) * 160 + k * 80;
  float* yptr = y + ((size_t)(k * B_SZ + b) * L_SEQ) * D_INNER;

  float Scarry = 0.f;
  for (int sub = 0; sub < CH / 64; ++sub) {
    const int t0 = ch * CH + sub * 64;
    const int lbase = k ? (L_SEQ - 64 - t0) : t0;
    // stage delta [64][64] and C [64][16]
#pragma unroll
    for (int i = 0; i < 4; ++i) {
      const int r = (tid >> 4) + i * 16;
      const int ridx = k ? (63 - r) : r;
      const int colq = (tid & 15) * 4;
      *(float4*)&sd[ridx][colq] =
          *(const float4*)(dptr + (size_t)(lbase + r) * D_INNER + d0 + colq);
    }
    {
      const int r = tid >> 2;
      const int ridx = k ? (63 - r) : r;
      const int c4 = (tid & 3) * 4;
      *(float4*)&sC[ridx][c4] =
          *(const float4*)(xptr + (size_t)(lbase + r) * 160 + DT_RANK + D_STATE + c4);
    }
    __syncthreads();
    // per-thread quarter sum -> LDS prefix
    float qsum = 0.f;
#pragma unroll
    for (int i = 0; i < 16; ++i) qsum += sd[tq * 16 + i][dl];
    sOct[dl][tq] = qsum;
    __syncthreads();
    float S0 = Scarry;
#pragma unroll
    for (int j = 0; j < 4; ++j) {
      const float v = sOct[dl][j];
      if (j < tq) S0 += v;
      Scarry += v;
    }
    // main: 16 t's, 16 n's in registers
    for (int i = 0; i < 16; ++i) {
      const int t = tq * 16 + i;
      S0 += sd[t][dl];
      const float4 C0 = *(const float4*)&sC[t][0];
      const float4 C1 = *(const float4*)&sC[t][4];
      const float4 C2 = *(const float4*)&sC[t][8];
      const float4 C3 = *(const float4*)&sC[t][12];
      float yt;
      yt  = C0.x * (__expf(An[0] * S0) * h[0]);
      yt += C0.y * (__expf(An[1] * S0) * h[1]);
      yt += C0.z * (__expf(An[2] * S0) * h[2]);
      yt += C0.w * (__expf(An[3] * S0) * h[3]);
      yt += C1.x * (__expf(An[4] * S0) * h[4]);
      yt += C1.y * (__expf(An[5] * S0) * h[5]);
      yt += C1.z * (__expf(An[6] * S0) * h[6]);
      yt += C1.w * (__expf(An[7] * S0) * h[7]);
      yt += C2.x * (__expf(An[8] * S0) * h[8]);
      yt += C2.y * (__expf(An[9] * S0) * h[9]);
      yt += C2.z * (__expf(An[10] * S0) * h[10]);
      yt += C2.w * (__expf(An[11] * S0) * h[11]);
      yt += C3.x * (__expf(An[12] * S0) * h[12]);
      yt += C3.y * (__expf(An[13] * S0) * h[13]);
      yt += C3.z * (__expf(An[14] * S0) * h[14]);
      yt += C3.w * (__expf(An[15] * S0) * h[15]);
      const int tg = t0 + t;
      const int l = k ? (L_SEQ - 1 - tg) : tg;
      yptr[(size_t)l * D_INNER + d] += yt;
    }
    __syncthreads();
  }
}

// ---------------------------------------------------------------------------
// y_gated = (y0 + y1) * z  -> bf16
// ---------------------------------------------------------------------------
__global__ __launch_bounds__(256) void gate_kernel(
    const float* __restrict__ y, const float* __restrict__ xz,
    ushort* __restrict__ yg) {
  const size_t total = (size_t)B_SZ * L_SEQ * D_INNER;
  size_t idx = ((size_t)blockIdx.x * 256 + threadIdx.x) * 4;
  if (idx >= total) return;
  const size_t m = idx / D_INNER;
  const size_t dd = idx % D_INNER;
  const float4 y0 = *(const float4*)(y + idx);
  const float4 y1 = *(const float4*)(y + total + idx);
  const float4 zv = *(const float4*)(xz + m * 3072 + 1536 + dd);
  ushort4 o;
  o.x = f2bf((y0.x + y1.x) * zv.x);
  o.y = f2bf((y0.y + y1.y) * zv.y);
  o.z = f2bf((y0.z + y1.z) * zv.z);
  o.w = f2bf((y0.w + y1.w) * zv.w);
  *(ushort4*)(yg + idx) = o;
}

// ---------------------------------------------------------------------------
extern "C" void kernel_launch(void* const* d_in, const int* in_sizes, int n_in,
                              void* d_out, int out_size, void* d_ws,
                              size_t ws_size, hipStream_t stream) {
  const float* x          = (const float*)d_in[0];
  const float* in_proj_w  = (const float*)d_in[1];
  const float* conv_w     = (const float*)d_in[2];
  const float* conv_b     = (const float*)d_in[3];
  const float* x_proj_w   = (const float*)d_in[4];
  const float* dt_proj_w  = (const float*)d_in[5];
  const float* dt_proj_b  = (const float*)d_in[6];
  const float* A_logs     = (const float*)d_in[7];
  const float* Ds         = (const float*)d_in[8];
  const float* out_proj_w = (const float*)d_in[9];
  float* out = (float*)d_out;

  const int M = B_SZ * L_SEQ;  // 4096

  float* ws    = (float*)d_ws;
  float* xz    = ws;                                  // [M,3072]
  float* u     = xz + (size_t)M * 3072;               // [M,1536]
  float* xdbl  = u + (size_t)M * 1536;                // [M,160]
  float* delta = xdbl + (size_t)M * 160;              // [2,M,1536]
  float* y     = delta + (size_t)2 * M * 1536;        // [2,M,1536]
  float* hfin  = y + (size_t)2 * M * 1536;            // 1,572,864
  float* hin   = hfin + (size_t)2 * B_SZ * NCH * NDG * 1024;
  float* Tsum  = hin + (size_t)2 * B_SZ * NCH * NDG * 1024;  // 98,304
  ushort* w_out_bf = (ushort*)(Tsum + (size_t)2 * B_SZ * NCH * NDG * 64);

  // bf16 scratch overlaid on y (dead before scan_local writes y)
  ushort* x_bf    = (ushort*)y;
  ushort* w_in_bf = x_bf + (size_t)M * 768;
  ushort* w_xp_bf = w_in_bf + (size_t)3072 * 768;
  ushort* w_dt_bf = w_xp_bf + (size_t)256 * 1536;
  ushort* u_bf    = w_dt_bf + (size_t)2 * 1536 * 64;
  ushort* dtin    = u_bf + (size_t)M * 1536;
  ushort* yg_bf   = (ushort*)delta;  // dead after fixup

  dim3 blk(256);

  // 0. conversions
  cvt_bf16_kernel<<<dim3(M * 768 / 4 / 256), blk, 0, stream>>>(x, x_bf, M * 768);
  cvt_bf16_kernel<<<dim3(3072 * 768 / 4 / 256), blk, 0, stream>>>(
      in_proj_w, w_in_bf, 3072 * 768);
  cvt_bf16_kernel<<<dim3(768 * 1536 / 4 / 256), blk, 0, stream>>>(
      out_proj_w, w_out_bf, 768 * 1536);
  cvt_xprojw_kernel<<<dim3(256 * 1536 / 4 / 256), blk, 0, stream>>>(x_proj_w,
                                                                    w_xp_bf);
  cvt_dtw_kernel<<<dim3(2 * 1536 * 64 / 4 / 256), blk, 0, stream>>>(dt_proj_w,
                                                                    w_dt_bf);

  // 1. xz = x @ in_proj_w^T
  gemm_bf16<128, 128, 0><<<dim3(3072 / 128, M / 128), blk, 0, stream>>>(
      x_bf, 768, w_in_bf, 768, nullptr, xz, 3072, 3072, 768);

  // 2. u = silu(conv(x_conv)+bias)
  conv_silu_kernel<<<dim3((M * (D_INNER / 4) + 255) / 256), blk, 0, stream>>>(
      xz, conv_w, conv_b, u, u_bf);

  // 3. xdbl = u @ x_proj_w^T
  gemm_bf16<64, 64, 0><<<dim3(256 / 64, M / 64), blk, 0, stream>>>(
      u_bf, 1536, w_xp_bf, 1536, nullptr, xdbl, 160, 160, 1536);

  // 4. dtin
  cvt_dtin_kernel<<<dim3(2 * M * 64 / 4 / 256), blk, 0, stream>>>(xdbl, dtin);

  // 5. delta_k
  for (int k = 0; k < 2; ++k) {
    gemm_bf16<128, 128, 1><<<dim3(1536 / 128, M / 128), blk, 0, stream>>>(
        dtin + (size_t)k * M * 64, 64, w_dt_bf + (size_t)k * 1536 * 64, 64,
        dt_proj_b + k * 1536, delta + (size_t)k * M * 1536, 1536, 1536, 64);
  }

  // 6. scan
  scan_local_kernel<<<dim3(2 * B_SZ * NDG * NCH), blk, 0, stream>>>(
      u, xdbl, delta, A_logs, Ds, y, hfin, Tsum);
  scan_stitch_kernel<<<dim3(2 * B_SZ * NDG), blk, 0, stream>>>(hfin, Tsum,
                                                               A_logs, hin);
  scan_fixup_kernel<<<dim3(2 * B_SZ * NDG * NCH), blk, 0, stream>>>(
      xdbl, delta, A_logs, hin, y);

  // 7. gate
  gate_kernel<<<dim3((M * D_INNER / 4 + 255) / 256), blk, 0, stream>>>(y, xz,
                                                                       yg_bf);

  // 8. out = yg @ out_proj_w^T
  gemm_bf16<128, 128, 0><<<dim3(768 / 128, M / 128), blk, 0, stream>>>(
      yg_bf, 1536, w_out_bf, 1536, nullptr, out, 768, 768, 1536);
}

// Round 5
// 309.573 us; speedup vs baseline: 3.4800x; 1.0464x over previous
//
#include <hip/hip_runtime.h>
#include <math.h>

#define D_MODEL 768
#define D_STATE 16
#define D_INNER 1536
#define DT_RANK 48
#define B_SZ    2
#define L_SEQ   2048
#define CH      64             // scan chunk length
#define NCH     (L_SEQ / CH)   // 32 chunks
#define NDG     24             // d-groups of 64 channels

typedef __bf16 bf16x8 __attribute__((ext_vector_type(8)));
typedef float f32x4 __attribute__((ext_vector_type(4)));
typedef ushort ushort8_t __attribute__((ext_vector_type(8)));

__device__ __forceinline__ ushort f2bf(float f) {
  unsigned int u = __float_as_uint(f);
  unsigned int r = (u + 0x7fff + ((u >> 16) & 1)) >> 16;
  return (ushort)r;
}
__device__ __forceinline__ float bf2f(ushort u) {
  return __uint_as_float(((unsigned int)u) << 16);
}

__device__ __forceinline__ void gload_lds16(const ushort* g, ushort* l) {
  __builtin_amdgcn_global_load_lds(
      (__attribute__((address_space(1))) void*)(void*)(g),
      (__attribute__((address_space(3))) void*)(void*)(l), 16, 0, 0);
}

// ---------------------------------------------------------------------------
// bf16 MFMA GEMM: C[M,N] = A[M,K](bf16) * B[N,K](bf16)^T (+bias, +softplus)
// OBF: 1 -> bf16 output, 0 -> fp32 output.
// ---------------------------------------------------------------------------
template <int BM, int BN, int ACT, int OBF>
__global__ __launch_bounds__(256) void gemm_bf16(
    const ushort* __restrict__ A, int lda,
    const ushort* __restrict__ B, int ldb,
    const float* __restrict__ bias,
    void* __restrict__ Cp, int ldc, int Nreal, int K) {
  __shared__ ushort As[BM][32];
  __shared__ ushort Bs[BN][32];
  constexpr int WM = BM / 2, WN = BN / 2;
  constexpr int FM = WM / 16, FN = WN / 16;
  const int tid = threadIdx.x;
  const int lane = tid & 63;
  const int w = tid >> 6;
  const int wr = w >> 1, wc = w & 1;
  const int bm = blockIdx.y * BM, bn = blockIdx.x * BN;

  const int lrow = lane >> 2;
  const int lchunk = lane & 3;

  f32x4 acc[FM][FN] = {};

  const int fr = lane & 15;
  const int k8 = (lane >> 4) * 8;

  for (int k0 = 0; k0 < K; k0 += 32) {
#pragma unroll
    for (int g = 0; g < BM / 64; ++g) {
      const int rb = w * (BM / 4) + g * 16;
      const ushort* gp = A + (size_t)(bm + rb + lrow) * lda + k0 + lchunk * 8;
      gload_lds16(gp, &As[rb][0]);
    }
#pragma unroll
    for (int g = 0; g < BN / 64; ++g) {
      const int rb = w * (BN / 4) + g * 16;
      const ushort* gp = B + (size_t)(bn + rb + lrow) * ldb + k0 + lchunk * 8;
      gload_lds16(gp, &Bs[rb][0]);
    }
    __syncthreads();
    bf16x8 af[FM], bfr[FN];
#pragma unroll
    for (int m = 0; m < FM; ++m)
      af[m] = *reinterpret_cast<const bf16x8*>(&As[wr * WM + m * 16 + fr][k8]);
#pragma unroll
    for (int n = 0; n < FN; ++n)
      bfr[n] = *reinterpret_cast<const bf16x8*>(&Bs[wc * WN + n * 16 + fr][k8]);
#pragma unroll
    for (int m = 0; m < FM; ++m)
#pragma unroll
      for (int n = 0; n < FN; ++n)
        acc[m][n] = __builtin_amdgcn_mfma_f32_16x16x32_bf16(af[m], bfr[n],
                                                            acc[m][n], 0, 0, 0);
    __syncthreads();
  }

  const int row4 = (lane >> 4) * 4;
#pragma unroll
  for (int m = 0; m < FM; ++m) {
#pragma unroll
    for (int n = 0; n < FN; ++n) {
      const int gn = bn + wc * WN + n * 16 + fr;
      if (gn >= Nreal) continue;
      const int gm0 = bm + wr * WM + m * 16 + row4;
      const float bv = bias ? bias[gn] : 0.f;
#pragma unroll
      for (int j = 0; j < 4; ++j) {
        float v = acc[m][n][j] + bv;
        if (ACT == 1) v = (v > 20.f) ? v : log1pf(__expf(v));
        if (OBF)
          ((ushort*)Cp)[(size_t)(gm0 + j) * ldc + gn] = f2bf(v);
        else
          ((float*)Cp)[(size_t)(gm0 + j) * ldc + gn] = v;
      }
    }
  }
}

// ---------------------------------------------------------------------------
// One-shot fp32->bf16 conversion of x + all weights (with padding).
// Region order: x | in_proj_w | out_proj_w | x_proj_w(pad rows 160->256) |
//               dt_proj_w(pad cols 48->64)
// ---------------------------------------------------------------------------
__global__ __launch_bounds__(256) void cvt_all_kernel(
    const float* __restrict__ x, const float* __restrict__ w_in,
    const float* __restrict__ w_out, const float* __restrict__ w_xp,
    const float* __restrict__ w_dt, ushort* __restrict__ x_bf,
    ushort* __restrict__ w_in_bf, ushort* __restrict__ w_out_bf,
    ushort* __restrict__ w_xp_bf, ushort* __restrict__ w_dt_bf) {
  const long N0 = 3145728, N1 = 2359296, N2 = 1179648, N3 = 393216, N4 = 196608;
  long i = ((long)blockIdx.x * 256 + threadIdx.x) * 4;
  if (i < N0) {
    const float4 v = *(const float4*)(x + i);
    ushort4 o = {f2bf(v.x), f2bf(v.y), f2bf(v.z), f2bf(v.w)};
    *(ushort4*)(x_bf + i) = o;
    return;
  }
  i -= N0;
  if (i < N1) {
    const float4 v = *(const float4*)(w_in + i);
    ushort4 o = {f2bf(v.x), f2bf(v.y), f2bf(v.z), f2bf(v.w)};
    *(ushort4*)(w_in_bf + i) = o;
    return;
  }
  i -= N1;
  if (i < N2) {
    const float4 v = *(const float4*)(w_out + i);
    ushort4 o = {f2bf(v.x), f2bf(v.y), f2bf(v.z), f2bf(v.w)};
    *(ushort4*)(w_out_bf + i) = o;
    return;
  }
  i -= N2;
  if (i < N3) {
    const long row = i / 1536;
    ushort4 o = {0, 0, 0, 0};
    if (row < 160) {
      const float4 v = *(const float4*)(w_xp + i);
      o.x = f2bf(v.x); o.y = f2bf(v.y); o.z = f2bf(v.z); o.w = f2bf(v.w);
    }
    *(ushort4*)(w_xp_bf + i) = o;
    return;
  }
  i -= N3;
  if (i < N4) {
    const int col = (int)(i & 63);
    const long row = i >> 6;
    ushort4 o = {0, 0, 0, 0};
    if (col < 48) {
      const float4 v = *(const float4*)(w_dt + row * 48 + col);
      o.x = f2bf(v.x); o.y = f2bf(v.y); o.z = f2bf(v.z); o.w = f2bf(v.w);
    }
    *(ushort4*)(w_dt_bf + i) = o;
  }
}

// ---------------------------------------------------------------------------
// Depthwise conv (k=3, pad=1) + bias + SiLU, bf16 in/out. 8 ch per thread.
// ---------------------------------------------------------------------------
__global__ __launch_bounds__(256) void conv_silu_kernel(
    const ushort* __restrict__ xz, const float* __restrict__ cw,
    const float* __restrict__ cb, ushort* __restrict__ u_bf) {
  const int nd8 = D_INNER / 8;  // 192
  int idx = blockIdx.x * 256 + threadIdx.x;
  if (idx >= B_SZ * L_SEQ * nd8) return;
  const int d = (idx % nd8) * 8;
  const int l = (idx / nd8) % L_SEQ;
  const int b = idx / (nd8 * L_SEQ);
  float a[8];
#pragma unroll
  for (int j8 = 0; j8 < 8; ++j8) a[j8] = cb[d + j8];
#pragma unroll
  for (int j = 0; j < 3; ++j) {
    const int ll = l + j - 1;
    if (ll < 0 || ll >= L_SEQ) continue;
    const ushort8_t xv =
        *(const ushort8_t*)(xz + ((size_t)b * L_SEQ + ll) * 3072 + d);
#pragma unroll
    for (int j8 = 0; j8 < 8; ++j8)
      a[j8] += bf2f(xv[j8]) * cw[(d + j8) * 3 + j];
  }
  ushort8_t o;
#pragma unroll
  for (int j8 = 0; j8 < 8; ++j8) {
    const float s = a[j8] / (1.f + __expf(-a[j8]));
    o[j8] = f2bf(s);
  }
  *(ushort8_t*)(u_bf + ((size_t)b * L_SEQ + l) * D_INNER + d) = o;
}

// ---------------------------------------------------------------------------
// xdbl [M,160] f32 -> dtin [2,M,64] bf16 (cols 0..47 from k*80.., rest zero)
// ---------------------------------------------------------------------------
__global__ __launch_bounds__(256) void cvt_dtin_kernel(
    const float* __restrict__ xdbl, ushort* __restrict__ d) {
  const int M = B_SZ * L_SEQ;
  int i = (blockIdx.x * 256 + threadIdx.x) * 4;
  if (i >= 2 * M * 64) return;
  const int col = i & 63;
  const int m = (i >> 6) % M;
  const int k = i / (M * 64);
  ushort4 o = {0, 0, 0, 0};
  if (col < 48) {
    const float4 v = *(const float4*)(xdbl + (size_t)m * 160 + k * 80 + col);
    o.x = f2bf(v.x); o.y = f2bf(v.y); o.z = f2bf(v.z); o.w = f2bf(v.w);
  }
  *(ushort4*)(d + i) = o;
}

// ---------------------------------------------------------------------------
// K1: local scan. Block = (k,b,dgB of 64 ch, chunk of 64 l). Wave = 16d x 4nq.
// Lane holds h[4]; 2 shuffles/step. delta/u read as bf16.
// ---------------------------------------------------------------------------
__global__ __launch_bounds__(256) void scan_local_kernel(
    const ushort* __restrict__ u_bf, const float* __restrict__ xdbl,
    const ushort* __restrict__ delta_bf, const float* __restrict__ A_logs,
    const float* __restrict__ Ds, float* __restrict__ y,
    float* __restrict__ hfin, float* __restrict__ Tsum) {
  __shared__ float sd[32][64], su[32][64], sB[32][16], sC[32][16];
  const int tid = threadIdx.x;
  const int lane = tid & 63;
  const int w = tid >> 6;
  const int c = lane & 15;
  const int nq = lane >> 4;
  const int bid = blockIdx.x;
  const int ch = bid & (NCH - 1);
  const int rest = bid >> 5;
  const int dgB = rest % NDG;
  const int kb = rest / NDG;
  const int b = kb & 1;
  const int k = kb >> 1;
  const int d0 = dgB * 64;
  const int dl = w * 16 + c;
  const int d = d0 + dl;
  const int row = k * D_INNER + d;

  const float4 alv = *(const float4*)(A_logs + (size_t)row * D_STATE + nq * 4);
  const float An0 = -__expf(alv.x), An1 = -__expf(alv.y);
  const float An2 = -__expf(alv.z), An3 = -__expf(alv.w);
  const float Dk = Ds[row];

  const ushort* uptr = u_bf + ((size_t)b * L_SEQ) * D_INNER;
  const ushort* dptr = delta_bf + ((size_t)(k * B_SZ + b) * L_SEQ) * D_INNER;
  const float* xptr = xdbl + ((size_t)b * L_SEQ) * 160 + k * 80;
  float* yptr = y + ((size_t)(k * B_SZ + b) * L_SEQ) * D_INNER;

  float h0 = 0.f, h1 = 0.f, h2 = 0.f, h3 = 0.f, S = 0.f;

  for (int sub = 0; sub < CH / 32; ++sub) {
    const int t0 = ch * CH + sub * 32;
    const int lbase = k ? (L_SEQ - 32 - t0) : t0;
    // stage delta/u tiles [32][64] from bf16
    {
      const int r = tid >> 3, seg = tid & 7;
      const int ridx = k ? (31 - r) : r;
      const size_t off = (size_t)(lbase + r) * D_INNER + d0 + seg * 8;
      const ushort8_t dv = *(const ushort8_t*)(dptr + off);
      const ushort8_t uv = *(const ushort8_t*)(uptr + off);
#pragma unroll
      for (int j = 0; j < 8; ++j) {
        sd[ridx][seg * 8 + j] = bf2f(dv[j]);
        su[ridx][seg * 8 + j] = bf2f(uv[j]);
      }
    }
    // stage B/C [32][16] from fp32 xdbl
    {
      const int t2 = tid & 127;
      const int r = t2 >> 2;
      const int ridx = k ? (31 - r) : r;
      const int c4 = (t2 & 3) * 4;
      const size_t rowL = (size_t)(lbase + r);
      if (tid < 128)
        *(float4*)&sB[ridx][c4] = *(const float4*)(xptr + rowL * 160 + DT_RANK + c4);
      else
        *(float4*)&sC[ridx][c4] = *(const float4*)(xptr + rowL * 160 + DT_RANK + D_STATE + c4);
    }
    __syncthreads();
    for (int s = 0; s < 32; ++s) {
      const float dlt = sd[s][dl];
      const float uu = su[s][dl];
      S += dlt;
      const float4 Bv = *(const float4*)&sB[s][nq * 4];
      const float4 Cv = *(const float4*)&sC[s][nq * 4];
      const float du = dlt * uu;
      h0 = h0 * __expf(dlt * An0) + du * Bv.x;
      h1 = h1 * __expf(dlt * An1) + du * Bv.y;
      h2 = h2 * __expf(dlt * An2) + du * Bv.z;
      h3 = h3 * __expf(dlt * An3) + du * Bv.w;
      float yt = h0 * Cv.x + h1 * Cv.y + h2 * Cv.z + h3 * Cv.w;
      yt += __shfl_xor(yt, 16);
      yt += __shfl_xor(yt, 32);
      if (nq == 0) {
        const int t = t0 + s;
        const int l = k ? (L_SEQ - 1 - t) : t;
        yptr[(size_t)l * D_INNER + d] = yt + uu * Dk;
      }
    }
    __syncthreads();
  }

  const size_t cidxB = ((size_t)(k * B_SZ + b) * NCH + ch) * NDG + dgB;
  *(float4*)(hfin + cidxB * 1024 + dl * 16 + nq * 4) =
      make_float4(h0, h1, h2, h3);
  if (nq == 0) Tsum[cidxB * 64 + dl] = S;
}

// ---------------------------------------------------------------------------
// K2: stitch. Block = (k,b,dgB). Thread = (dl = tid>>2, nq = tid&3).
// ---------------------------------------------------------------------------
__global__ __launch_bounds__(256) void scan_stitch_kernel(
    const float* __restrict__ hfin, const float* __restrict__ Tsum,
    const float* __restrict__ A_logs, float* __restrict__ hin) {
  const int tid = threadIdx.x;
  const int dl = tid >> 2;
  const int nq = tid & 3;
  const int bid = blockIdx.x;
  const int dgB = bid % NDG;
  const int b = (bid / NDG) & 1;
  const int k = bid / (NDG * 2);
  const int row = k * D_INNER + dgB * 64 + dl;
  const float4 alv = *(const float4*)(A_logs + (size_t)row * D_STATE + nq * 4);
  const float An0 = -__expf(alv.x), An1 = -__expf(alv.y);
  const float An2 = -__expf(alv.z), An3 = -__expf(alv.w);
  float c0 = 0.f, c1 = 0.f, c2 = 0.f, c3 = 0.f;
  for (int ch = 0; ch < NCH; ++ch) {
    const size_t cidxB = ((size_t)(k * B_SZ + b) * NCH + ch) * NDG + dgB;
    const size_t off = cidxB * 1024 + dl * 16 + nq * 4;
    *(float4*)(hin + off) = make_float4(c0, c1, c2, c3);
    const float T = Tsum[cidxB * 64 + dl];
    const float4 hf = *(const float4*)(hfin + off);
    c0 = c0 * __expf(An0 * T) + hf.x;
    c1 = c1 * __expf(An1 * T) + hf.y;
    c2 = c2 * __expf(An2 * T) + hf.z;
    c3 = c3 * __expf(An3 * T) + hf.w;
  }
}

// ---------------------------------------------------------------------------
// K3: fused fixup (both directions) + gate. Block = (b, dgB, l-chunk of 64).
// Thread = (tq = tid>>6 owns 16 l's, dl = tid&63). Writes final yg bf16.
// Forward: chunk ch, prefix-cumsum of delta0. Backward: chunk chb = NCH-1-ch,
// suffix-cumsum of delta1 (scan order = descending l).
// ---------------------------------------------------------------------------
__global__ __launch_bounds__(256) void fixup_gate_kernel(
    const float* __restrict__ xdbl, const ushort* __restrict__ delta_bf,
    const float* __restrict__ A_logs, const float* __restrict__ hin,
    const float* __restrict__ y, const ushort* __restrict__ xz_bf,
    ushort* __restrict__ yg) {
  __shared__ float sd0[64][64], sd1[64][64];
  __shared__ float sC0[64][16], sC1[64][16];
  __shared__ float sQF[64][4], sQB[64][4];
  const int tid = threadIdx.x;
  const int tq = tid >> 6;
  const int dl = tid & 63;
  const int bid = blockIdx.x;
  const int ch = bid & (NCH - 1);
  const int rest = bid >> 5;
  const int dgB = rest % NDG;
  const int b = rest / NDG;
  const int d0 = dgB * 64;
  const int d = d0 + dl;
  const int lbase = ch * CH;
  const int chb = NCH - 1 - ch;

  float AnF[16], AnB[16], hF[16], hB[16];
#pragma unroll
  for (int q = 0; q < 4; ++q) {
    const float4 af = *(const float4*)(A_logs + (size_t)d * D_STATE + q * 4);
    AnF[q * 4 + 0] = -__expf(af.x); AnF[q * 4 + 1] = -__expf(af.y);
    AnF[q * 4 + 2] = -__expf(af.z); AnF[q * 4 + 3] = -__expf(af.w);
    const float4 ab =
        *(const float4*)(A_logs + (size_t)(D_INNER + d) * D_STATE + q * 4);
    AnB[q * 4 + 0] = -__expf(ab.x); AnB[q * 4 + 1] = -__expf(ab.y);
    AnB[q * 4 + 2] = -__expf(ab.z); AnB[q * 4 + 3] = -__expf(ab.w);
  }
  const size_t cF = ((size_t)(0 * B_SZ + b) * NCH + ch) * NDG + dgB;
  const size_t cB = ((size_t)(1 * B_SZ + b) * NCH + chb) * NDG + dgB;
#pragma unroll
  for (int q = 0; q < 4; ++q) {
    const float4 hv = *(const float4*)(hin + cF * 1024 + dl * 16 + q * 4);
    hF[q * 4 + 0] = hv.x; hF[q * 4 + 1] = hv.y;
    hF[q * 4 + 2] = hv.z; hF[q * 4 + 3] = hv.w;
    const float4 hw = *(const float4*)(hin + cB * 1024 + dl * 16 + q * 4);
    hB[q * 4 + 0] = hw.x; hB[q * 4 + 1] = hw.y;
    hB[q * 4 + 2] = hw.z; hB[q * 4 + 3] = hw.w;
  }

  const ushort* d0p =
      delta_bf + ((size_t)(0 * B_SZ + b) * L_SEQ + lbase) * D_INNER + d0;
  const ushort* d1p =
      delta_bf + ((size_t)(1 * B_SZ + b) * L_SEQ + lbase) * D_INNER + d0;
  // stage delta tiles [64][64]
#pragma unroll
  for (int i = 0; i < 2; ++i) {
    const int unit = tid + i * 256;
    const int r = unit >> 3, seg = unit & 7;
    const ushort8_t v0 = *(const ushort8_t*)(d0p + (size_t)r * D_INNER + seg * 8);
    const ushort8_t v1 = *(const ushort8_t*)(d1p + (size_t)r * D_INNER + seg * 8);
#pragma unroll
    for (int j = 0; j < 8; ++j) {
      sd0[r][seg * 8 + j] = bf2f(v0[j]);
      sd1[r][seg * 8 + j] = bf2f(v1[j]);
    }
  }
  // stage C tiles [64][16] (fp32 xdbl): k=0 cols [64,80), k=1 cols [144,160)
  {
    const int r = tid >> 2;
    const int c4 = (tid & 3) * 4;
    const float* xrow = xdbl + ((size_t)b * L_SEQ + lbase + r) * 160;
    *(float4*)&sC0[r][c4] = *(const float4*)(xrow + DT_RANK + D_STATE + c4);
    *(float4*)&sC1[r][c4] = *(const float4*)(xrow + 80 + DT_RANK + D_STATE + c4);
  }
  __syncthreads();
  // quarter sums
  float qf = 0.f, qb = 0.f;
#pragma unroll
  for (int i = 0; i < 16; ++i) {
    qf += sd0[tq * 16 + i][dl];
    qb += sd1[tq * 16 + i][dl];
  }
  sQF[dl][tq] = qf;
  sQB[dl][tq] = qb;
  __syncthreads();
  float SF = 0.f, SB = 0.f;
#pragma unroll
  for (int j = 0; j < 4; ++j) {
    if (j < tq) SF += sQF[dl][j];
    if (j > tq) SB += sQB[dl][j];
  }

  const float* y0p = y + ((size_t)(0 * B_SZ + b) * L_SEQ) * D_INNER;
  const float* y1p = y + ((size_t)(1 * B_SZ + b) * L_SEQ) * D_INNER;
  float yacc[16];
#pragma unroll
  for (int i = 0; i < 16; ++i) {
    const int t = tq * 16 + i;
    SF += sd0[t][dl];
    float wf = 0.f;
#pragma unroll
    for (int n = 0; n < 16; ++n)
      wf += sC0[t][n] * (__expf(AnF[n] * SF) * hF[n]);
    yacc[i] = y0p[(size_t)(lbase + t) * D_INNER + d] + wf;
  }
#pragma unroll
  for (int i = 15; i >= 0; --i) {
    const int t = tq * 16 + i;
    SB += sd1[t][dl];
    float wb = 0.f;
#pragma unroll
    for (int n = 0; n < 16; ++n)
      wb += sC1[t][n] * (__expf(AnB[n] * SB) * hB[n]);
    yacc[i] += y1p[(size_t)(lbase + t) * D_INNER + d] + wb;
  }
#pragma unroll
  for (int i = 0; i < 16; ++i) {
    const int l = lbase + tq * 16 + i;
    const float z = bf2f(xz_bf[((size_t)b * L_SEQ + l) * 3072 + 1536 + d]);
    yg[((size_t)b * L_SEQ + l) * D_INNER + d] = f2bf(yacc[i] * z);
  }
}

// ---------------------------------------------------------------------------
extern "C" void kernel_launch(void* const* d_in, const int* in_sizes, int n_in,
                              void* d_out, int out_size, void* d_ws,
                              size_t ws_size, hipStream_t stream) {
  const float* x          = (const float*)d_in[0];
  const float* in_proj_w  = (const float*)d_in[1];
  const float* conv_w     = (const float*)d_in[2];
  const float* conv_b     = (const float*)d_in[3];
  const float* x_proj_w   = (const float*)d_in[4];
  const float* dt_proj_w  = (const float*)d_in[5];
  const float* dt_proj_b  = (const float*)d_in[6];
  const float* A_logs     = (const float*)d_in[7];
  const float* Ds         = (const float*)d_in[8];
  const float* out_proj_w = (const float*)d_in[9];
  float* out = (float*)d_out;

  const int M = B_SZ * L_SEQ;  // 4096
  const size_t NST = (size_t)2 * B_SZ * NCH * NDG;  // state groups

  float* ws    = (float*)d_ws;
  float* xdbl  = ws;                         // M*160
  float* y     = xdbl + (size_t)M * 160;     // 2*M*1536
  float* hfin  = y + (size_t)2 * M * 1536;   // NST*1024
  float* hin   = hfin + NST * 1024;          // NST*1024
  float* Tsum  = hin + NST * 1024;           // NST*64
  ushort* x_bf     = (ushort*)(Tsum + NST * 64);
  ushort* w_in_bf  = x_bf + (size_t)M * 768;
  ushort* w_out_bf = w_in_bf + (size_t)3072 * 768;
  ushort* w_xp_bf  = w_out_bf + (size_t)768 * 1536;
  ushort* w_dt_bf  = w_xp_bf + (size_t)256 * 1536;
  ushort* xz_bf    = w_dt_bf + (size_t)2 * 1536 * 64;
  ushort* u_bf     = xz_bf + (size_t)M * 3072;
  ushort* delta_bf = u_bf + (size_t)M * 1536;
  ushort* dtin     = delta_bf + (size_t)2 * M * 1536;
  ushort* yg_bf    = dtin + (size_t)2 * M * 64;

  dim3 blk(256);

  // 0. conversions (one kernel)
  {
    const long TOT = 3145728L + 2359296 + 1179648 + 393216 + 196608;
    cvt_all_kernel<<<dim3((TOT / 4 + 255) / 256), blk, 0, stream>>>(
        x, in_proj_w, out_proj_w, x_proj_w, dt_proj_w, x_bf, w_in_bf, w_out_bf,
        w_xp_bf, w_dt_bf);
  }

  // 1. xz = x @ in_proj_w^T  -> bf16
  gemm_bf16<128, 128, 0, 1><<<dim3(3072 / 128, M / 128), blk, 0, stream>>>(
      x_bf, 768, w_in_bf, 768, nullptr, xz_bf, 3072, 3072, 768);

  // 2. u = silu(conv(x_conv)+bias) -> bf16
  conv_silu_kernel<<<dim3(M * (D_INNER / 8) / 256), blk, 0, stream>>>(
      xz_bf, conv_w, conv_b, u_bf);

  // 3. xdbl = u @ x_proj_w^T -> fp32 (N=160 real, 256 padded)
  gemm_bf16<64, 64, 0, 0><<<dim3(256 / 64, M / 64), blk, 0, stream>>>(
      u_bf, 1536, w_xp_bf, 1536, nullptr, xdbl, 160, 160, 1536);

  // 4. dtin (pad dt cols -> 64, bf16)
  cvt_dtin_kernel<<<dim3(2 * M * 64 / 4 / 256), blk, 0, stream>>>(xdbl, dtin);

  // 5. delta_k = softplus(dtin_k @ dtw_k^T + dtb_k) -> bf16
  for (int k = 0; k < 2; ++k) {
    gemm_bf16<128, 128, 1, 1><<<dim3(1536 / 128, M / 128), blk, 0, stream>>>(
        dtin + (size_t)k * M * 64, 64, w_dt_bf + (size_t)k * 1536 * 64, 64,
        dt_proj_b + k * 1536, delta_bf + (size_t)k * M * 1536, 1536, 1536, 64);
  }

  // 6. scan
  scan_local_kernel<<<dim3(2 * B_SZ * NDG * NCH), blk, 0, stream>>>(
      u_bf, xdbl, delta_bf, A_logs, Ds, y, hfin, Tsum);
  scan_stitch_kernel<<<dim3(2 * B_SZ * NDG), blk, 0, stream>>>(hfin, Tsum,
                                                               A_logs, hin);
  // 7. fused fixup(both dirs) + gate -> yg bf16
  fixup_gate_kernel<<<dim3(B_SZ * NDG * NCH), blk, 0, stream>>>(
      xdbl, delta_bf, A_logs, hin, y, xz_bf, yg_bf);

  // 8. out = yg @ out_proj_w^T -> fp32
  gemm_bf16<128, 128, 0, 0><<<dim3(768 / 128, M / 128), blk, 0, stream>>>(
      yg_bf, 1536, w_out_bf, 1536, nullptr, out, 768, 768, 1536);
}

// Round 7
// 289.317 us; speedup vs baseline: 3.7236x; 1.0700x over previous
//
#include <hip/hip_runtime.h>
#include <math.h>

#define D_MODEL 768
#define D_STATE 16
#define D_INNER 1536
#define DT_RANK 48
#define B_SZ    2
#define L_SEQ   2048
#define CH      64             // scan chunk length
#define NCH     (L_SEQ / CH)   // 32 chunks
#define NDG     24             // d-groups of 64 channels
#define MTOT    (B_SZ * L_SEQ) // 4096
#define LOG2E   1.4426950408889634f

typedef __bf16 bf16x8 __attribute__((ext_vector_type(8)));
typedef float f32x4 __attribute__((ext_vector_type(4)));
typedef ushort ushort8_t __attribute__((ext_vector_type(8)));

__device__ __forceinline__ float ex2(float x) {
  return __builtin_amdgcn_exp2f(x);  // v_exp_f32: D = 2^S0
}

__device__ __forceinline__ ushort f2bf(float f) {
  unsigned int u = __float_as_uint(f);
  unsigned int r = (u + 0x7fff + ((u >> 16) & 1)) >> 16;
  return (ushort)r;
}
__device__ __forceinline__ float bf2f(ushort u) {
  return __uint_as_float(((unsigned int)u) << 16);
}

__device__ __forceinline__ void gload_lds16(const ushort* g, ushort* l) {
  __builtin_amdgcn_global_load_lds(
      (__attribute__((address_space(1))) void*)(void*)(g),
      (__attribute__((address_space(3))) void*)(void*)(l), 16, 0, 0);
}

// ---------------------------------------------------------------------------
// bf16 MFMA GEMM body, double-buffered 2-phase K-loop.
// C[M,N] = A[M,K] * B[N,K]^T (+bias, +softplus). OBF: bf16 C. DTOUT: also
// emit dtin bf16 (cols 0..47 -> k0, 80..127 -> k1, pad to 64 with zeros).
// ---------------------------------------------------------------------------
template <int BM, int BN, int ACT, int OBF, int DTOUT>
__device__ __forceinline__ void gemm_body(
    const ushort* __restrict__ A, int lda, const ushort* __restrict__ B,
    int ldb, const float* __restrict__ bias, void* __restrict__ Cp, int ldc,
    int Nreal, int K, int bxi, int byi, ushort* __restrict__ dtin) {
  __shared__ ushort As[2][BM][32];
  __shared__ ushort Bs[2][BN][32];
  constexpr int WM = BM / 2, WN = BN / 2;
  constexpr int FM = WM / 16, FN = WN / 16;
  const int tid = threadIdx.x;
  const int lane = tid & 63;
  const int w = tid >> 6;
  const int wr = w >> 1, wc = w & 1;
  const int bm = byi * BM, bn = bxi * BN;
  const int lrow = lane >> 2;
  const int lchunk = lane & 3;
  const int fr = lane & 15;
  const int k8 = (lane >> 4) * 8;

  f32x4 acc[FM][FN] = {};

  auto stage = [&](int buf, int k0) {
#pragma unroll
    for (int g = 0; g < BM / 64; ++g) {
      const int rb = w * (BM / 4) + g * 16;
      gload_lds16(A + (size_t)(bm + rb + lrow) * lda + k0 + lchunk * 8,
                  &As[buf][rb][0]);
    }
#pragma unroll
    for (int g = 0; g < BN / 64; ++g) {
      const int rb = w * (BN / 4) + g * 16;
      gload_lds16(B + (size_t)(bn + rb + lrow) * ldb + k0 + lchunk * 8,
                  &Bs[buf][rb][0]);
    }
  };

  stage(0, 0);
  __syncthreads();
  int cur = 0;
  for (int k0 = 0; k0 < K; k0 += 32) {
    if (k0 + 32 < K) stage(cur ^ 1, k0 + 32);
    bf16x8 af[FM], bfr[FN];
#pragma unroll
    for (int m = 0; m < FM; ++m)
      af[m] =
          *reinterpret_cast<const bf16x8*>(&As[cur][wr * WM + m * 16 + fr][k8]);
#pragma unroll
    for (int n = 0; n < FN; ++n)
      bfr[n] =
          *reinterpret_cast<const bf16x8*>(&Bs[cur][wc * WN + n * 16 + fr][k8]);
#pragma unroll
    for (int m = 0; m < FM; ++m)
#pragma unroll
      for (int n = 0; n < FN; ++n)
        acc[m][n] = __builtin_amdgcn_mfma_f32_16x16x32_bf16(af[m], bfr[n],
                                                            acc[m][n], 0, 0, 0);
    __syncthreads();
    cur ^= 1;
  }

  const int row4 = (lane >> 4) * 4;
#pragma unroll
  for (int m = 0; m < FM; ++m) {
#pragma unroll
    for (int n = 0; n < FN; ++n) {
      const int gn = bn + wc * WN + n * 16 + fr;
      const int gm0 = bm + wr * WM + m * 16 + row4;
#pragma unroll
      for (int j = 0; j < 4; ++j) {
        const float v = acc[m][n][j];
        const int gm = gm0 + j;
        if (DTOUT) {
          if (gn < 64)
            dtin[(size_t)gm * 64 + gn] = (gn < 48) ? f2bf(v) : (ushort)0;
          else if (gn >= 80 && gn < 144)
            dtin[(size_t)MTOT * 64 + (size_t)gm * 64 + (gn - 80)] =
                (gn < 128) ? f2bf(v) : (ushort)0;
        }
        if (gn < Nreal) {
          float vv = v + (bias ? bias[gn] : 0.f);
          if (ACT == 1) vv = (vv > 20.f) ? vv : log1pf(__expf(vv));
          if (OBF)
            ((ushort*)Cp)[(size_t)gm * ldc + gn] = f2bf(vv);
          else
            ((float*)Cp)[(size_t)gm * ldc + gn] = vv;
        }
      }
    }
  }
}

template <int BM, int BN, int ACT, int OBF, int DTOUT>
__global__ __launch_bounds__(256) void gemm_k(
    const ushort* __restrict__ A, int lda, const ushort* __restrict__ B,
    int ldb, const float* __restrict__ bias, void* __restrict__ Cp, int ldc,
    int Nreal, int K, ushort* __restrict__ dtin) {
  gemm_body<BM, BN, ACT, OBF, DTOUT>(A, lda, B, ldb, bias, Cp, ldc, Nreal, K,
                                     blockIdx.x, blockIdx.y, dtin);
}

// dt_proj both directions in one dispatch (blockIdx.z = k)
__global__ __launch_bounds__(256) void gemm_dt_k(
    const ushort* __restrict__ dtin, const ushort* __restrict__ w_dt,
    const float* __restrict__ dtb, ushort* __restrict__ delta) {
  const int k = blockIdx.z;
  gemm_body<128, 128, 1, 1, 0>(
      dtin + (size_t)k * MTOT * 64, 64, w_dt + (size_t)k * D_INNER * 64, 64,
      dtb + k * D_INNER, delta + (size_t)k * MTOT * D_INNER, D_INNER, D_INNER,
      64, blockIdx.x, blockIdx.y, nullptr);
}

// ---------------------------------------------------------------------------
// One-shot fp32->bf16 conversion of x + all weights (with padding).
// ---------------------------------------------------------------------------
__global__ __launch_bounds__(256) void cvt_all_kernel(
    const float* __restrict__ x, const float* __restrict__ w_in,
    const float* __restrict__ w_out, const float* __restrict__ w_xp,
    const float* __restrict__ w_dt, ushort* __restrict__ x_bf,
    ushort* __restrict__ w_in_bf, ushort* __restrict__ w_out_bf,
    ushort* __restrict__ w_xp_bf, ushort* __restrict__ w_dt_bf) {
  const long N0 = 3145728, N1 = 2359296, N2 = 1179648, N3 = 393216, N4 = 196608;
  long i = ((long)blockIdx.x * 256 + threadIdx.x) * 4;
  if (i < N0) {
    const float4 v = *(const float4*)(x + i);
    ushort4 o = {f2bf(v.x), f2bf(v.y), f2bf(v.z), f2bf(v.w)};
    *(ushort4*)(x_bf + i) = o;
    return;
  }
  i -= N0;
  if (i < N1) {
    const float4 v = *(const float4*)(w_in + i);
    ushort4 o = {f2bf(v.x), f2bf(v.y), f2bf(v.z), f2bf(v.w)};
    *(ushort4*)(w_in_bf + i) = o;
    return;
  }
  i -= N1;
  if (i < N2) {
    const float4 v = *(const float4*)(w_out + i);
    ushort4 o = {f2bf(v.x), f2bf(v.y), f2bf(v.z), f2bf(v.w)};
    *(ushort4*)(w_out_bf + i) = o;
    return;
  }
  i -= N2;
  if (i < N3) {
    const long row = i / 1536;
    ushort4 o = {0, 0, 0, 0};
    if (row < 160) {
      const float4 v = *(const float4*)(w_xp + i);
      o.x = f2bf(v.x); o.y = f2bf(v.y); o.z = f2bf(v.z); o.w = f2bf(v.w);
    }
    *(ushort4*)(w_xp_bf + i) = o;
    return;
  }
  i -= N3;
  if (i < N4) {
    const int col = (int)(i & 63);
    const long row = i >> 6;
    ushort4 o = {0, 0, 0, 0};
    if (col < 48) {
      const float4 v = *(const float4*)(w_dt + row * 48 + col);
      o.x = f2bf(v.x); o.y = f2bf(v.y); o.z = f2bf(v.z); o.w = f2bf(v.w);
    }
    *(ushort4*)(w_dt_bf + i) = o;
  }
}

// ---------------------------------------------------------------------------
// Depthwise conv (k=3, pad=1) + bias + SiLU, bf16 in/out.
// ---------------------------------------------------------------------------
__global__ __launch_bounds__(256) void conv_silu_kernel(
    const ushort* __restrict__ xz, const float* __restrict__ cw,
    const float* __restrict__ cb, ushort* __restrict__ u_bf) {
  const int nd8 = D_INNER / 8;  // 192
  int idx = blockIdx.x * 256 + threadIdx.x;
  if (idx >= B_SZ * L_SEQ * nd8) return;
  const int d = (idx % nd8) * 8;
  const int l = (idx / nd8) % L_SEQ;
  const int b = idx / (nd8 * L_SEQ);
  float a[8];
#pragma unroll
  for (int j8 = 0; j8 < 8; ++j8) a[j8] = cb[d + j8];
#pragma unroll
  for (int j = 0; j < 3; ++j) {
    const int ll = l + j - 1;
    if (ll < 0 || ll >= L_SEQ) continue;
    const ushort8_t xv =
        *(const ushort8_t*)(xz + ((size_t)b * L_SEQ + ll) * 3072 + d);
#pragma unroll
    for (int j8 = 0; j8 < 8; ++j8)
      a[j8] += bf2f(xv[j8]) * cw[(d + j8) * 3 + j];
  }
  ushort8_t o;
#pragma unroll
  for (int j8 = 0; j8 < 8; ++j8) {
    const float s = a[j8] / (1.f + __expf(-a[j8]));
    o[j8] = f2bf(s);
  }
  *(ushort8_t*)(u_bf + ((size_t)b * L_SEQ + l) * D_INNER + d) = o;
}

// ---------------------------------------------------------------------------
// K1: local scan. Block = (k,b,dgB of 64 ch, chunk of 64 l). Wave = 16d x 4nq.
// Lane holds h[4]; 2 shuffles/step. y out bf16. exp2 with folded log2e.
// ---------------------------------------------------------------------------
__global__ __launch_bounds__(256) void scan_local_kernel(
    const ushort* __restrict__ u_bf, const float* __restrict__ xdbl,
    const ushort* __restrict__ delta_bf, const float* __restrict__ A_logs,
    const float* __restrict__ Ds, ushort* __restrict__ y,
    float* __restrict__ hfin, float* __restrict__ Tsum) {
  __shared__ float sd[32][64], su[32][64], sB[32][16], sC[32][16];
  const int tid = threadIdx.x;
  const int lane = tid & 63;
  const int w = tid >> 6;
  const int c = lane & 15;
  const int nq = lane >> 4;
  const int bid = blockIdx.x;
  const int ch = bid & (NCH - 1);
  const int rest = bid >> 5;
  const int dgB = rest % NDG;
  const int kb = rest / NDG;
  const int b = kb & 1;
  const int k = kb >> 1;
  const int d0 = dgB * 64;
  const int dl = w * 16 + c;
  const int d = d0 + dl;
  const int row = k * D_INNER + d;

  const float4 alv = *(const float4*)(A_logs + (size_t)row * D_STATE + nq * 4);
  const float An0 = -__expf(alv.x) * LOG2E, An1 = -__expf(alv.y) * LOG2E;
  const float An2 = -__expf(alv.z) * LOG2E, An3 = -__expf(alv.w) * LOG2E;
  const float Dk = Ds[row];

  const ushort* uptr = u_bf + ((size_t)b * L_SEQ) * D_INNER;
  const ushort* dptr = delta_bf + ((size_t)(k * B_SZ + b) * L_SEQ) * D_INNER;
  const float* xptr = xdbl + ((size_t)b * L_SEQ) * 160 + k * 80;
  ushort* yptr = y + ((size_t)(k * B_SZ + b) * L_SEQ) * D_INNER;

  float h0 = 0.f, h1 = 0.f, h2 = 0.f, h3 = 0.f, S = 0.f;

  for (int sub = 0; sub < CH / 32; ++sub) {
    const int t0 = ch * CH + sub * 32;
    const int lbase = k ? (L_SEQ - 32 - t0) : t0;
    // stage delta/u tiles [32][64] from bf16, float4 LDS stores
    {
      const int r = tid >> 3, seg = tid & 7;
      const int ridx = k ? (31 - r) : r;
      const size_t off = (size_t)(lbase + r) * D_INNER + d0 + seg * 8;
      const ushort8_t dv = *(const ushort8_t*)(dptr + off);
      const ushort8_t uv = *(const ushort8_t*)(uptr + off);
      *(float4*)&sd[ridx][seg * 8] =
          make_float4(bf2f(dv[0]), bf2f(dv[1]), bf2f(dv[2]), bf2f(dv[3]));
      *(float4*)&sd[ridx][seg * 8 + 4] =
          make_float4(bf2f(dv[4]), bf2f(dv[5]), bf2f(dv[6]), bf2f(dv[7]));
      *(float4*)&su[ridx][seg * 8] =
          make_float4(bf2f(uv[0]), bf2f(uv[1]), bf2f(uv[2]), bf2f(uv[3]));
      *(float4*)&su[ridx][seg * 8 + 4] =
          make_float4(bf2f(uv[4]), bf2f(uv[5]), bf2f(uv[6]), bf2f(uv[7]));
    }
    // stage B/C [32][16] from fp32 xdbl
    {
      const int t2 = tid & 127;
      const int r = t2 >> 2;
      const int ridx = k ? (31 - r) : r;
      const int c4 = (t2 & 3) * 4;
      const size_t rowL = (size_t)(lbase + r);
      if (tid < 128)
        *(float4*)&sB[ridx][c4] =
            *(const float4*)(xptr + rowL * 160 + DT_RANK + c4);
      else
        *(float4*)&sC[ridx][c4] =
            *(const float4*)(xptr + rowL * 160 + DT_RANK + D_STATE + c4);
    }
    __syncthreads();
    for (int s = 0; s < 32; ++s) {
      const float dlt = sd[s][dl];
      const float uu = su[s][dl];
      S += dlt;
      const float4 Bv = *(const float4*)&sB[s][nq * 4];
      const float4 Cv = *(const float4*)&sC[s][nq * 4];
      const float du = dlt * uu;
      h0 = h0 * ex2(dlt * An0) + du * Bv.x;
      h1 = h1 * ex2(dlt * An1) + du * Bv.y;
      h2 = h2 * ex2(dlt * An2) + du * Bv.z;
      h3 = h3 * ex2(dlt * An3) + du * Bv.w;
      float yt = h0 * Cv.x + h1 * Cv.y + h2 * Cv.z + h3 * Cv.w;
      yt += __shfl_xor(yt, 16);
      yt += __shfl_xor(yt, 32);
      if (nq == 0) {
        const int t = t0 + s;
        const int l = k ? (L_SEQ - 1 - t) : t;
        yptr[(size_t)l * D_INNER + d] = f2bf(yt + uu * Dk);
      }
    }
    __syncthreads();
  }

  const size_t cidxB = ((size_t)(k * B_SZ + b) * NCH + ch) * NDG + dgB;
  *(float4*)(hfin + cidxB * 1024 + dl * 16 + nq * 4) =
      make_float4(h0, h1, h2, h3);
  if (nq == 0) Tsum[cidxB * 64 + dl] = S;
}

// ---------------------------------------------------------------------------
// K2: stitch. Block = (k,b,dgB). Thread = (dl = tid>>2, nq = tid&3).
// ---------------------------------------------------------------------------
__global__ __launch_bounds__(256) void scan_stitch_kernel(
    const float* __restrict__ hfin, const float* __restrict__ Tsum,
    const float* __restrict__ A_logs, float* __restrict__ hin) {
  const int tid = threadIdx.x;
  const int dl = tid >> 2;
  const int nq = tid & 3;
  const int bid = blockIdx.x;
  const int dgB = bid % NDG;
  const int b = (bid / NDG) & 1;
  const int k = bid / (NDG * 2);
  const int row = k * D_INNER + dgB * 64 + dl;
  const float4 alv = *(const float4*)(A_logs + (size_t)row * D_STATE + nq * 4);
  const float An0 = -__expf(alv.x) * LOG2E, An1 = -__expf(alv.y) * LOG2E;
  const float An2 = -__expf(alv.z) * LOG2E, An3 = -__expf(alv.w) * LOG2E;
  float c0 = 0.f, c1 = 0.f, c2 = 0.f, c3 = 0.f;
  for (int ch = 0; ch < NCH; ++ch) {
    const size_t cidxB = ((size_t)(k * B_SZ + b) * NCH + ch) * NDG + dgB;
    const size_t off = cidxB * 1024 + dl * 16 + nq * 4;
    *(float4*)(hin + off) = make_float4(c0, c1, c2, c3);
    const float T = Tsum[cidxB * 64 + dl];
    const float4 hf = *(const float4*)(hfin + off);
    c0 = c0 * ex2(An0 * T) + hf.x;
    c1 = c1 * ex2(An1 * T) + hf.y;
    c2 = c2 * ex2(An2 * T) + hf.z;
    c3 = c3 * ex2(An3 * T) + hf.w;
  }
}

// ---------------------------------------------------------------------------
// K3: fused fixup (both directions) + gate -> yg bf16.
// ---------------------------------------------------------------------------
__global__ __launch_bounds__(256) void fixup_gate_kernel(
    const float* __restrict__ xdbl, const ushort* __restrict__ delta_bf,
    const float* __restrict__ A_logs, const float* __restrict__ hin,
    const ushort* __restrict__ y, const ushort* __restrict__ xz_bf,
    ushort* __restrict__ yg) {
  __shared__ float sd0[64][64], sd1[64][64];
  __shared__ float sC0[64][16], sC1[64][16];
  __shared__ float sQF[64][4], sQB[64][4];
  const int tid = threadIdx.x;
  const int tq = tid >> 6;
  const int dl = tid & 63;
  const int bid = blockIdx.x;
  const int ch = bid & (NCH - 1);
  const int rest = bid >> 5;
  const int dgB = rest % NDG;
  const int b = rest / NDG;
  const int d0 = dgB * 64;
  const int d = d0 + dl;
  const int lbase = ch * CH;
  const int chb = NCH - 1 - ch;

  float AnF[16], AnB[16], hF[16], hB[16];
#pragma unroll
  for (int q = 0; q < 4; ++q) {
    const float4 af = *(const float4*)(A_logs + (size_t)d * D_STATE + q * 4);
    AnF[q * 4 + 0] = -__expf(af.x) * LOG2E;
    AnF[q * 4 + 1] = -__expf(af.y) * LOG2E;
    AnF[q * 4 + 2] = -__expf(af.z) * LOG2E;
    AnF[q * 4 + 3] = -__expf(af.w) * LOG2E;
    const float4 ab =
        *(const float4*)(A_logs + (size_t)(D_INNER + d) * D_STATE + q * 4);
    AnB[q * 4 + 0] = -__expf(ab.x) * LOG2E;
    AnB[q * 4 + 1] = -__expf(ab.y) * LOG2E;
    AnB[q * 4 + 2] = -__expf(ab.z) * LOG2E;
    AnB[q * 4 + 3] = -__expf(ab.w) * LOG2E;
  }
  const size_t cF = ((size_t)(0 * B_SZ + b) * NCH + ch) * NDG + dgB;
  const size_t cB = ((size_t)(1 * B_SZ + b) * NCH + chb) * NDG + dgB;
#pragma unroll
  for (int q = 0; q < 4; ++q) {
    const float4 hv = *(const float4*)(hin + cF * 1024 + dl * 16 + q * 4);
    hF[q * 4 + 0] = hv.x; hF[q * 4 + 1] = hv.y;
    hF[q * 4 + 2] = hv.z; hF[q * 4 + 3] = hv.w;
    const float4 hw = *(const float4*)(hin + cB * 1024 + dl * 16 + q * 4);
    hB[q * 4 + 0] = hw.x; hB[q * 4 + 1] = hw.y;
    hB[q * 4 + 2] = hw.z; hB[q * 4 + 3] = hw.w;
  }

  const ushort* d0p =
      delta_bf + ((size_t)(0 * B_SZ + b) * L_SEQ + lbase) * D_INNER + d0;
  const ushort* d1p =
      delta_bf + ((size_t)(1 * B_SZ + b) * L_SEQ + lbase) * D_INNER + d0;
#pragma unroll
  for (int i = 0; i < 2; ++i) {
    const int unit = tid + i * 256;
    const int r = unit >> 3, seg = unit & 7;
    const ushort8_t v0 =
        *(const ushort8_t*)(d0p + (size_t)r * D_INNER + seg * 8);
    const ushort8_t v1 =
        *(const ushort8_t*)(d1p + (size_t)r * D_INNER + seg * 8);
    *(float4*)&sd0[r][seg * 8] =
        make_float4(bf2f(v0[0]), bf2f(v0[1]), bf2f(v0[2]), bf2f(v0[3]));
    *(float4*)&sd0[r][seg * 8 + 4] =
        make_float4(bf2f(v0[4]), bf2f(v0[5]), bf2f(v0[6]), bf2f(v0[7]));
    *(float4*)&sd1[r][seg * 8] =
        make_float4(bf2f(v1[0]), bf2f(v1[1]), bf2f(v1[2]), bf2f(v1[3]));
    *(float4*)&sd1[r][seg * 8 + 4] =
        make_float4(bf2f(v1[4]), bf2f(v1[5]), bf2f(v1[6]), bf2f(v1[7]));
  }
  {
    const int r = tid >> 2;
    const int c4 = (tid & 3) * 4;
    const float* xrow = xdbl + ((size_t)b * L_SEQ + lbase + r) * 160;
    *(float4*)&sC0[r][c4] = *(const float4*)(xrow + DT_RANK + D_STATE + c4);
    *(float4*)&sC1[r][c4] =
        *(const float4*)(xrow + 80 + DT_RANK + D_STATE + c4);
  }
  __syncthreads();
  float qf = 0.f, qb = 0.f;
#pragma unroll
  for (int i = 0; i < 16; ++i) {
    qf += sd0[tq * 16 + i][dl];
    qb += sd1[tq * 16 + i][dl];
  }
  sQF[dl][tq] = qf;
  sQB[dl][tq] = qb;
  __syncthreads();
  float SF = 0.f, SB = 0.f;
#pragma unroll
  for (int j = 0; j < 4; ++j) {
    if (j < tq) SF += sQF[dl][j];
    if (j > tq) SB += sQB[dl][j];
  }

  const ushort* y0p = y + ((size_t)(0 * B_SZ + b) * L_SEQ) * D_INNER;
  const ushort* y1p = y + ((size_t)(1 * B_SZ + b) * L_SEQ) * D_INNER;
  float yacc[16];
#pragma unroll
  for (int i = 0; i < 16; ++i) {
    const int t = tq * 16 + i;
    SF += sd0[t][dl];
    float wf = 0.f;
#pragma unroll
    for (int n = 0; n < 16; ++n)
      wf += sC0[t][n] * (ex2(AnF[n] * SF) * hF[n]);
    yacc[i] = bf2f(y0p[(size_t)(lbase + t) * D_INNER + d]) + wf;
  }
#pragma unroll
  for (int i = 15; i >= 0; --i) {
    const int t = tq * 16 + i;
    SB += sd1[t][dl];
    float wb = 0.f;
#pragma unroll
    for (int n = 0; n < 16; ++n)
      wb += sC1[t][n] * (ex2(AnB[n] * SB) * hB[n]);
    yacc[i] += bf2f(y1p[(size_t)(lbase + t) * D_INNER + d]) + wb;
  }
#pragma unroll
  for (int i = 0; i < 16; ++i) {
    const int l = lbase + tq * 16 + i;
    const float z = bf2f(xz_bf[((size_t)b * L_SEQ + l) * 3072 + 1536 + d]);
    yg[((size_t)b * L_SEQ + l) * D_INNER + d] = f2bf(yacc[i] * z);
  }
}

// ---------------------------------------------------------------------------
extern "C" void kernel_launch(void* const* d_in, const int* in_sizes, int n_in,
                              void* d_out, int out_size, void* d_ws,
                              size_t ws_size, hipStream_t stream) {
  const float* x          = (const float*)d_in[0];
  const float* in_proj_w  = (const float*)d_in[1];
  const float* conv_w     = (const float*)d_in[2];
  const float* conv_b     = (const float*)d_in[3];
  const float* x_proj_w   = (const float*)d_in[4];
  const float* dt_proj_w  = (const float*)d_in[5];
  const float* dt_proj_b  = (const float*)d_in[6];
  const float* A_logs     = (const float*)d_in[7];
  const float* Ds         = (const float*)d_in[8];
  const float* out_proj_w = (const float*)d_in[9];
  float* out = (float*)d_out;

  const int M = MTOT;
  const size_t NST = (size_t)2 * B_SZ * NCH * NDG;  // 3072

  float* ws    = (float*)d_ws;
  float* xdbl  = ws;                          // M*160
  float* hfin  = xdbl + (size_t)M * 160;      // NST*1024
  float* hin   = hfin + NST * 1024;           // NST*1024
  float* Tsum  = hin + NST * 1024;            // NST*64
  ushort* x_bf     = (ushort*)(Tsum + NST * 64);
  ushort* w_in_bf  = x_bf + (size_t)M * 768;
  ushort* w_out_bf = w_in_bf + (size_t)3072 * 768;
  ushort* w_xp_bf  = w_out_bf + (size_t)768 * 1536;
  ushort* w_dt_bf  = w_xp_bf + (size_t)256 * 1536;
  ushort* xz_bf    = w_dt_bf + (size_t)2 * 1536 * 64;
  ushort* u_bf     = xz_bf + (size_t)M * 3072;
  ushort* delta_bf = u_bf + (size_t)M * 1536;
  ushort* dtin     = delta_bf + (size_t)2 * M * 1536;
  ushort* y_bf     = dtin + (size_t)2 * M * 64;
  ushort* yg_bf    = y_bf + (size_t)2 * M * 1536;

  dim3 blk(256);

  // 0. conversions (one kernel)
  {
    const long TOT = 3145728L + 2359296 + 1179648 + 393216 + 196608;
    cvt_all_kernel<<<dim3((TOT / 4 + 255) / 256), blk, 0, stream>>>(
        x, in_proj_w, out_proj_w, x_proj_w, dt_proj_w, x_bf, w_in_bf, w_out_bf,
        w_xp_bf, w_dt_bf);
  }

  // 1. xz = x @ in_proj_w^T  -> bf16
  gemm_k<128, 128, 0, 1, 0><<<dim3(3072 / 128, M / 128), blk, 0, stream>>>(
      x_bf, 768, w_in_bf, 768, nullptr, xz_bf, 3072, 3072, 768, nullptr);

  // 2. u = silu(conv(x_conv)+bias) -> bf16
  conv_silu_kernel<<<dim3(M * (D_INNER / 8) / 256), blk, 0, stream>>>(
      xz_bf, conv_w, conv_b, u_bf);

  // 3. xdbl = u @ x_proj_w^T -> fp32 (+ dtin bf16 epilogue)
  gemm_k<64, 64, 0, 0, 1><<<dim3(256 / 64, M / 64), blk, 0, stream>>>(
      u_bf, 1536, w_xp_bf, 1536, nullptr, xdbl, 160, 160, 1536, dtin);

  // 4. delta = softplus(dtin @ dtw^T + dtb) -> bf16 (both k, one dispatch)
  gemm_dt_k<<<dim3(1536 / 128, M / 128, 2), blk, 0, stream>>>(
      dtin, w_dt_bf, dt_proj_b, delta_bf);

  // 5. scan
  scan_local_kernel<<<dim3(2 * B_SZ * NDG * NCH), blk, 0, stream>>>(
      u_bf, xdbl, delta_bf, A_logs, Ds, y_bf, hfin, Tsum);
  scan_stitch_kernel<<<dim3(2 * B_SZ * NDG), blk, 0, stream>>>(hfin, Tsum,
                                                               A_logs, hin);
  // 6. fused fixup(both dirs) + gate -> yg bf16
  fixup_gate_kernel<<<dim3(B_SZ * NDG * NCH), blk, 0, stream>>>(
      xdbl, delta_bf, A_logs, hin, y_bf, xz_bf, yg_bf);

  // 7. out = yg @ out_proj_w^T -> fp32
  gemm_k<128, 128, 0, 0, 0><<<dim3(768 / 128, M / 128), blk, 0, stream>>>(
      yg_bf, 1536, w_out_bf, 1536, nullptr, out, 768, 768, 1536, nullptr);
}

// Round 8
// 250.364 us; speedup vs baseline: 4.3030x; 1.1556x over previous
//
#include <hip/hip_runtime.h>
#include <math.h>

#define D_MODEL 768
#define D_STATE 16
#define D_INNER 1536
#define DT_RANK 48
#define B_SZ    2
#define L_SEQ   2048
#define CH      64             // scan chunk length
#define NCH     (L_SEQ / CH)   // 32 chunks
#define NDG     24             // d-groups of 64 channels
#define MTOT    (B_SZ * L_SEQ) // 4096
#define LOG2E   1.4426950408889634f
#define LN2     0.6931471805599453f

typedef __bf16 bf16x8 __attribute__((ext_vector_type(8)));
typedef float f32x4 __attribute__((ext_vector_type(4)));
typedef ushort ushort8_t __attribute__((ext_vector_type(8)));

__device__ __forceinline__ float ex2(float x) {
  return __builtin_amdgcn_exp2f(x);  // v_exp_f32: D = 2^S0
}

__device__ __forceinline__ ushort f2bf(float f) {
  unsigned int u = __float_as_uint(f);
  unsigned int r = (u + 0x7fff + ((u >> 16) & 1)) >> 16;
  return (ushort)r;
}
__device__ __forceinline__ float bf2f(ushort u) {
  return __uint_as_float(((unsigned int)u) << 16);
}

__device__ __forceinline__ void gload_lds16(const ushort* g, ushort* l) {
  __builtin_amdgcn_global_load_lds(
      (__attribute__((address_space(1))) void*)(void*)(g),
      (__attribute__((address_space(3))) void*)(void*)(l), 16, 0, 0);
}

// fast softplus: ln(1+e^x) = ln2 * log2(1 + 2^(x*log2e)); guard large x
__device__ __forceinline__ float softplus_fast(float x) {
  return (x > 20.f) ? x : LN2 * __log2f(1.f + ex2(x * LOG2E));
}

// ---------------------------------------------------------------------------
// bf16 MFMA GEMM body, double-buffered 2-phase K-loop.
// C[M,N] = A[M,K] * B[N,K]^T (+bias, +softplus). OBF: bf16 C. DTOUT: also
// emit dtin bf16 (cols 0..47 -> k0, 80..127 -> k1, pad to 64 with zeros).
// ---------------------------------------------------------------------------
template <int BM, int BN, int ACT, int OBF, int DTOUT>
__device__ __forceinline__ void gemm_body(
    const ushort* __restrict__ A, int lda, const ushort* __restrict__ B,
    int ldb, const float* __restrict__ bias, void* __restrict__ Cp, int ldc,
    int Nreal, int K, int bxi, int byi, ushort* __restrict__ dtin) {
  __shared__ ushort As[2][BM][32];
  __shared__ ushort Bs[2][BN][32];
  constexpr int WM = BM / 2, WN = BN / 2;
  constexpr int FM = WM / 16, FN = WN / 16;
  const int tid = threadIdx.x;
  const int lane = tid & 63;
  const int w = tid >> 6;
  const int wr = w >> 1, wc = w & 1;
  const int bm = byi * BM, bn = bxi * BN;
  const int lrow = lane >> 2;
  const int lchunk = lane & 3;
  const int fr = lane & 15;
  const int k8 = (lane >> 4) * 8;

  f32x4 acc[FM][FN] = {};

  auto stage = [&](int buf, int k0) {
#pragma unroll
    for (int g = 0; g < BM / 64; ++g) {
      const int rb = w * (BM / 4) + g * 16;
      gload_lds16(A + (size_t)(bm + rb + lrow) * lda + k0 + lchunk * 8,
                  &As[buf][rb][0]);
    }
#pragma unroll
    for (int g = 0; g < BN / 64; ++g) {
      const int rb = w * (BN / 4) + g * 16;
      gload_lds16(B + (size_t)(bn + rb + lrow) * ldb + k0 + lchunk * 8,
                  &Bs[buf][rb][0]);
    }
  };

  stage(0, 0);
  __syncthreads();
  int cur = 0;
  for (int k0 = 0; k0 < K; k0 += 32) {
    if (k0 + 32 < K) stage(cur ^ 1, k0 + 32);
    bf16x8 af[FM], bfr[FN];
#pragma unroll
    for (int m = 0; m < FM; ++m)
      af[m] =
          *reinterpret_cast<const bf16x8*>(&As[cur][wr * WM + m * 16 + fr][k8]);
#pragma unroll
    for (int n = 0; n < FN; ++n)
      bfr[n] =
          *reinterpret_cast<const bf16x8*>(&Bs[cur][wc * WN + n * 16 + fr][k8]);
#pragma unroll
    for (int m = 0; m < FM; ++m)
#pragma unroll
      for (int n = 0; n < FN; ++n)
        acc[m][n] = __builtin_amdgcn_mfma_f32_16x16x32_bf16(af[m], bfr[n],
                                                            acc[m][n], 0, 0, 0);
    __syncthreads();
    cur ^= 1;
  }

  const int row4 = (lane >> 4) * 4;
#pragma unroll
  for (int m = 0; m < FM; ++m) {
#pragma unroll
    for (int n = 0; n < FN; ++n) {
      const int gn = bn + wc * WN + n * 16 + fr;
      const int gm0 = bm + wr * WM + m * 16 + row4;
#pragma unroll
      for (int j = 0; j < 4; ++j) {
        const float v = acc[m][n][j];
        const int gm = gm0 + j;
        if (DTOUT) {
          if (gn < 64)
            dtin[(size_t)gm * 64 + gn] = (gn < 48) ? f2bf(v) : (ushort)0;
          else if (gn >= 80 && gn < 144)
            dtin[(size_t)MTOT * 64 + (size_t)gm * 64 + (gn - 80)] =
                (gn < 128) ? f2bf(v) : (ushort)0;
        }
        if (gn < Nreal) {
          float vv = v + (bias ? bias[gn] : 0.f);
          if (ACT == 1) vv = softplus_fast(vv);
          if (OBF)
            ((ushort*)Cp)[(size_t)gm * ldc + gn] = f2bf(vv);
          else
            ((float*)Cp)[(size_t)gm * ldc + gn] = vv;
        }
      }
    }
  }
}

template <int BM, int BN, int ACT, int OBF, int DTOUT>
__global__ __launch_bounds__(256) void gemm_k(
    const ushort* __restrict__ A, int lda, const ushort* __restrict__ B,
    int ldb, const float* __restrict__ bias, void* __restrict__ Cp, int ldc,
    int Nreal, int K, ushort* __restrict__ dtin) {
  gemm_body<BM, BN, ACT, OBF, DTOUT>(A, lda, B, ldb, bias, Cp, ldc, Nreal, K,
                                     blockIdx.x, blockIdx.y, dtin);
}

// dt_proj both directions in one dispatch (blockIdx.z = k); 64x128 tile
__global__ __launch_bounds__(256) void gemm_dt_k(
    const ushort* __restrict__ dtin, const ushort* __restrict__ w_dt,
    const float* __restrict__ dtb, ushort* __restrict__ delta) {
  const int k = blockIdx.z;
  gemm_body<64, 128, 1, 1, 0>(
      dtin + (size_t)k * MTOT * 64, 64, w_dt + (size_t)k * D_INNER * 64, 64,
      dtb + k * D_INNER, delta + (size_t)k * MTOT * D_INNER, D_INNER, D_INNER,
      64, blockIdx.x, blockIdx.y, nullptr);
}

// ---------------------------------------------------------------------------
// One-shot fp32->bf16 conversion of x + all weights (with padding).
// ---------------------------------------------------------------------------
__global__ __launch_bounds__(256) void cvt_all_kernel(
    const float* __restrict__ x, const float* __restrict__ w_in,
    const float* __restrict__ w_out, const float* __restrict__ w_xp,
    const float* __restrict__ w_dt, ushort* __restrict__ x_bf,
    ushort* __restrict__ w_in_bf, ushort* __restrict__ w_out_bf,
    ushort* __restrict__ w_xp_bf, ushort* __restrict__ w_dt_bf) {
  const long N0 = 3145728, N1 = 2359296, N2 = 1179648, N3 = 393216, N4 = 196608;
  long i = ((long)blockIdx.x * 256 + threadIdx.x) * 4;
  if (i < N0) {
    const float4 v = *(const float4*)(x + i);
    ushort4 o = {f2bf(v.x), f2bf(v.y), f2bf(v.z), f2bf(v.w)};
    *(ushort4*)(x_bf + i) = o;
    return;
  }
  i -= N0;
  if (i < N1) {
    const float4 v = *(const float4*)(w_in + i);
    ushort4 o = {f2bf(v.x), f2bf(v.y), f2bf(v.z), f2bf(v.w)};
    *(ushort4*)(w_in_bf + i) = o;
    return;
  }
  i -= N1;
  if (i < N2) {
    const float4 v = *(const float4*)(w_out + i);
    ushort4 o = {f2bf(v.x), f2bf(v.y), f2bf(v.z), f2bf(v.w)};
    *(ushort4*)(w_out_bf + i) = o;
    return;
  }
  i -= N2;
  if (i < N3) {
    const long row = i / 1536;
    ushort4 o = {0, 0, 0, 0};
    if (row < 160) {
      const float4 v = *(const float4*)(w_xp + i);
      o.x = f2bf(v.x); o.y = f2bf(v.y); o.z = f2bf(v.z); o.w = f2bf(v.w);
    }
    *(ushort4*)(w_xp_bf + i) = o;
    return;
  }
  i -= N3;
  if (i < N4) {
    const int col = (int)(i & 63);
    const long row = i >> 6;
    ushort4 o = {0, 0, 0, 0};
    if (col < 48) {
      const float4 v = *(const float4*)(w_dt + row * 48 + col);
      o.x = f2bf(v.x); o.y = f2bf(v.y); o.z = f2bf(v.z); o.w = f2bf(v.w);
    }
    *(ushort4*)(w_dt_bf + i) = o;
  }
}

// ---------------------------------------------------------------------------
// Depthwise conv (k=3, pad=1) + bias + SiLU, bf16 in/out.
// ---------------------------------------------------------------------------
__global__ __launch_bounds__(256) void conv_silu_kernel(
    const ushort* __restrict__ xz, const float* __restrict__ cw,
    const float* __restrict__ cb, ushort* __restrict__ u_bf) {
  const int nd8 = D_INNER / 8;  // 192
  int idx = blockIdx.x * 256 + threadIdx.x;
  if (idx >= B_SZ * L_SEQ * nd8) return;
  const int d = (idx % nd8) * 8;
  const int l = (idx / nd8) % L_SEQ;
  const int b = idx / (nd8 * L_SEQ);
  float a[8];
#pragma unroll
  for (int j8 = 0; j8 < 8; ++j8) a[j8] = cb[d + j8];
#pragma unroll
  for (int j = 0; j < 3; ++j) {
    const int ll = l + j - 1;
    if (ll < 0 || ll >= L_SEQ) continue;
    const ushort8_t xv =
        *(const ushort8_t*)(xz + ((size_t)b * L_SEQ + ll) * 3072 + d);
#pragma unroll
    for (int j8 = 0; j8 < 8; ++j8)
      a[j8] += bf2f(xv[j8]) * cw[(d + j8) * 3 + j];
  }
  ushort8_t o;
#pragma unroll
  for (int j8 = 0; j8 < 8; ++j8) {
    const float s = a[j8] / (1.f + __expf(-a[j8]));
    o[j8] = f2bf(s);
  }
  *(ushort8_t*)(u_bf + ((size_t)b * L_SEQ + l) * D_INNER + d) = o;
}

// ---------------------------------------------------------------------------
// K1: local scan. Block = (k,b,dgB of 64 ch, chunk of 64 l). Wave = 16d x 4nq.
// Lane holds h[4]; 2 shuffles/step. y out bf16. exp2 with folded log2e.
// ---------------------------------------------------------------------------
__global__ __launch_bounds__(256) void scan_local_kernel(
    const ushort* __restrict__ u_bf, const float* __restrict__ xdbl,
    const ushort* __restrict__ delta_bf, const float* __restrict__ A_logs,
    const float* __restrict__ Ds, ushort* __restrict__ y,
    float* __restrict__ hfin, float* __restrict__ Tsum) {
  __shared__ float sd[32][64], su[32][64], sB[32][16], sC[32][16];
  const int tid = threadIdx.x;
  const int lane = tid & 63;
  const int w = tid >> 6;
  const int c = lane & 15;
  const int nq = lane >> 4;
  const int bid = blockIdx.x;
  const int ch = bid & (NCH - 1);
  const int rest = bid >> 5;
  const int dgB = rest % NDG;
  const int kb = rest / NDG;
  const int b = kb & 1;
  const int k = kb >> 1;
  const int d0 = dgB * 64;
  const int dl = w * 16 + c;
  const int d = d0 + dl;
  const int row = k * D_INNER + d;

  const float4 alv = *(const float4*)(A_logs + (size_t)row * D_STATE + nq * 4);
  const float An0 = -__expf(alv.x) * LOG2E, An1 = -__expf(alv.y) * LOG2E;
  const float An2 = -__expf(alv.z) * LOG2E, An3 = -__expf(alv.w) * LOG2E;
  const float Dk = Ds[row];

  const ushort* uptr = u_bf + ((size_t)b * L_SEQ) * D_INNER;
  const ushort* dptr = delta_bf + ((size_t)(k * B_SZ + b) * L_SEQ) * D_INNER;
  const float* xptr = xdbl + ((size_t)b * L_SEQ) * 160 + k * 80;
  ushort* yptr = y + ((size_t)(k * B_SZ + b) * L_SEQ) * D_INNER;

  float h0 = 0.f, h1 = 0.f, h2 = 0.f, h3 = 0.f, S = 0.f;

  for (int sub = 0; sub < CH / 32; ++sub) {
    const int t0 = ch * CH + sub * 32;
    const int lbase = k ? (L_SEQ - 32 - t0) : t0;
    // stage delta/u tiles [32][64] from bf16, float4 LDS stores
    {
      const int r = tid >> 3, seg = tid & 7;
      const int ridx = k ? (31 - r) : r;
      const size_t off = (size_t)(lbase + r) * D_INNER + d0 + seg * 8;
      const ushort8_t dv = *(const ushort8_t*)(dptr + off);
      const ushort8_t uv = *(const ushort8_t*)(uptr + off);
      *(float4*)&sd[ridx][seg * 8] =
          make_float4(bf2f(dv[0]), bf2f(dv[1]), bf2f(dv[2]), bf2f(dv[3]));
      *(float4*)&sd[ridx][seg * 8 + 4] =
          make_float4(bf2f(dv[4]), bf2f(dv[5]), bf2f(dv[6]), bf2f(dv[7]));
      *(float4*)&su[ridx][seg * 8] =
          make_float4(bf2f(uv[0]), bf2f(uv[1]), bf2f(uv[2]), bf2f(uv[3]));
      *(float4*)&su[ridx][seg * 8 + 4] =
          make_float4(bf2f(uv[4]), bf2f(uv[5]), bf2f(uv[6]), bf2f(uv[7]));
    }
    // stage B/C [32][16] from fp32 xdbl
    {
      const int t2 = tid & 127;
      const int r = t2 >> 2;
      const int ridx = k ? (31 - r) : r;
      const int c4 = (t2 & 3) * 4;
      const size_t rowL = (size_t)(lbase + r);
      if (tid < 128)
        *(float4*)&sB[ridx][c4] =
            *(const float4*)(xptr + rowL * 160 + DT_RANK + c4);
      else
        *(float4*)&sC[ridx][c4] =
            *(const float4*)(xptr + rowL * 160 + DT_RANK + D_STATE + c4);
    }
    __syncthreads();
    for (int s = 0; s < 32; ++s) {
      const float dlt = sd[s][dl];
      const float uu = su[s][dl];
      S += dlt;
      const float4 Bv = *(const float4*)&sB[s][nq * 4];
      const float4 Cv = *(const float4*)&sC[s][nq * 4];
      const float du = dlt * uu;
      h0 = h0 * ex2(dlt * An0) + du * Bv.x;
      h1 = h1 * ex2(dlt * An1) + du * Bv.y;
      h2 = h2 * ex2(dlt * An2) + du * Bv.z;
      h3 = h3 * ex2(dlt * An3) + du * Bv.w;
      float yt = h0 * Cv.x + h1 * Cv.y + h2 * Cv.z + h3 * Cv.w;
      yt += __shfl_xor(yt, 16);
      yt += __shfl_xor(yt, 32);
      if (nq == 0) {
        const int t = t0 + s;
        const int l = k ? (L_SEQ - 1 - t) : t;
        yptr[(size_t)l * D_INNER + d] = f2bf(yt + uu * Dk);
      }
    }
    __syncthreads();
  }

  const size_t cidxB = ((size_t)(k * B_SZ + b) * NCH + ch) * NDG + dgB;
  *(float4*)(hfin + cidxB * 1024 + dl * 16 + nq * 4) =
      make_float4(h0, h1, h2, h3);
  if (nq == 0) Tsum[cidxB * 64 + dl] = S;
}

// ---------------------------------------------------------------------------
// K2: stitch. Block = (k,b,dgB). Thread = (dl = tid>>2, nq = tid&3).
// ---------------------------------------------------------------------------
__global__ __launch_bounds__(256) void scan_stitch_kernel(
    const float* __restrict__ hfin, const float* __restrict__ Tsum,
    const float* __restrict__ A_logs, float* __restrict__ hin) {
  const int tid = threadIdx.x;
  const int dl = tid >> 2;
  const int nq = tid & 3;
  const int bid = blockIdx.x;
  const int dgB = bid % NDG;
  const int b = (bid / NDG) & 1;
  const int k = bid / (NDG * 2);
  const int row = k * D_INNER + dgB * 64 + dl;
  const float4 alv = *(const float4*)(A_logs + (size_t)row * D_STATE + nq * 4);
  const float An0 = -__expf(alv.x) * LOG2E, An1 = -__expf(alv.y) * LOG2E;
  const float An2 = -__expf(alv.z) * LOG2E, An3 = -__expf(alv.w) * LOG2E;
  float c0 = 0.f, c1 = 0.f, c2 = 0.f, c3 = 0.f;
  for (int ch = 0; ch < NCH; ++ch) {
    const size_t cidxB = ((size_t)(k * B_SZ + b) * NCH + ch) * NDG + dgB;
    const size_t off = cidxB * 1024 + dl * 16 + nq * 4;
    *(float4*)(hin + off) = make_float4(c0, c1, c2, c3);
    const float T = Tsum[cidxB * 64 + dl];
    const float4 hf = *(const float4*)(hfin + off);
    c0 = c0 * ex2(An0 * T) + hf.x;
    c1 = c1 * ex2(An1 * T) + hf.y;
    c2 = c2 * ex2(An2 * T) + hf.z;
    c3 = c3 * ex2(An3 * T) + hf.w;
  }
}

// ---------------------------------------------------------------------------
// K3: fused fixup (both directions) + gate -> yg bf16.
// ---------------------------------------------------------------------------
__global__ __launch_bounds__(256) void fixup_gate_kernel(
    const float* __restrict__ xdbl, const ushort* __restrict__ delta_bf,
    const float* __restrict__ A_logs, const float* __restrict__ hin,
    const ushort* __restrict__ y, const ushort* __restrict__ xz_bf,
    ushort* __restrict__ yg) {
  __shared__ float sd0[64][64], sd1[64][64];
  __shared__ float sC0[64][16], sC1[64][16];
  __shared__ float sQF[64][4], sQB[64][4];
  const int tid = threadIdx.x;
  const int tq = tid >> 6;
  const int dl = tid & 63;
  const int bid = blockIdx.x;
  const int ch = bid & (NCH - 1);
  const int rest = bid >> 5;
  const int dgB = rest % NDG;
  const int b = rest / NDG;
  const int d0 = dgB * 64;
  const int d = d0 + dl;
  const int lbase = ch * CH;
  const int chb = NCH - 1 - ch;

  float AnF[16], AnB[16], hF[16], hB[16];
#pragma unroll
  for (int q = 0; q < 4; ++q) {
    const float4 af = *(const float4*)(A_logs + (size_t)d * D_STATE + q * 4);
    AnF[q * 4 + 0] = -__expf(af.x) * LOG2E;
    AnF[q * 4 + 1] = -__expf(af.y) * LOG2E;
    AnF[q * 4 + 2] = -__expf(af.z) * LOG2E;
    AnF[q * 4 + 3] = -__expf(af.w) * LOG2E;
    const float4 ab =
        *(const float4*)(A_logs + (size_t)(D_INNER + d) * D_STATE + q * 4);
    AnB[q * 4 + 0] = -__expf(ab.x) * LOG2E;
    AnB[q * 4 + 1] = -__expf(ab.y) * LOG2E;
    AnB[q * 4 + 2] = -__expf(ab.z) * LOG2E;
    AnB[q * 4 + 3] = -__expf(ab.w) * LOG2E;
  }
  const size_t cF = ((size_t)(0 * B_SZ + b) * NCH + ch) * NDG + dgB;
  const size_t cB = ((size_t)(1 * B_SZ + b) * NCH + chb) * NDG + dgB;
#pragma unroll
  for (int q = 0; q < 4; ++q) {
    const float4 hv = *(const float4*)(hin + cF * 1024 + dl * 16 + q * 4);
    hF[q * 4 + 0] = hv.x; hF[q * 4 + 1] = hv.y;
    hF[q * 4 + 2] = hv.z; hF[q * 4 + 3] = hv.w;
    const float4 hw = *(const float4*)(hin + cB * 1024 + dl * 16 + q * 4);
    hB[q * 4 + 0] = hw.x; hB[q * 4 + 1] = hw.y;
    hB[q * 4 + 2] = hw.z; hB[q * 4 + 3] = hw.w;
  }

  const ushort* d0p =
      delta_bf + ((size_t)(0 * B_SZ + b) * L_SEQ + lbase) * D_INNER + d0;
  const ushort* d1p =
      delta_bf + ((size_t)(1 * B_SZ + b) * L_SEQ + lbase) * D_INNER + d0;
#pragma unroll
  for (int i = 0; i < 2; ++i) {
    const int unit = tid + i * 256;
    const int r = unit >> 3, seg = unit & 7;
    const ushort8_t v0 =
        *(const ushort8_t*)(d0p + (size_t)r * D_INNER + seg * 8);
    const ushort8_t v1 =
        *(const ushort8_t*)(d1p + (size_t)r * D_INNER + seg * 8);
    *(float4*)&sd0[r][seg * 8] =
        make_float4(bf2f(v0[0]), bf2f(v0[1]), bf2f(v0[2]), bf2f(v0[3]));
    *(float4*)&sd0[r][seg * 8 + 4] =
        make_float4(bf2f(v0[4]), bf2f(v0[5]), bf2f(v0[6]), bf2f(v0[7]));
    *(float4*)&sd1[r][seg * 8] =
        make_float4(bf2f(v1[0]), bf2f(v1[1]), bf2f(v1[2]), bf2f(v1[3]));
    *(float4*)&sd1[r][seg * 8 + 4] =
        make_float4(bf2f(v1[4]), bf2f(v1[5]), bf2f(v1[6]), bf2f(v1[7]));
  }
  {
    const int r = tid >> 2;
    const int c4 = (tid & 3) * 4;
    const float* xrow = xdbl + ((size_t)b * L_SEQ + lbase + r) * 160;
    *(float4*)&sC0[r][c4] = *(const float4*)(xrow + DT_RANK + D_STATE + c4);
    *(float4*)&sC1[r][c4] =
        *(const float4*)(xrow + 80 + DT_RANK + D_STATE + c4);
  }
  __syncthreads();
  float qf = 0.f, qb = 0.f;
#pragma unroll
  for (int i = 0; i < 16; ++i) {
    qf += sd0[tq * 16 + i][dl];
    qb += sd1[tq * 16 + i][dl];
  }
  sQF[dl][tq] = qf;
  sQB[dl][tq] = qb;
  __syncthreads();
  float SF = 0.f, SB = 0.f;
#pragma unroll
  for (int j = 0; j < 4; ++j) {
    if (j < tq) SF += sQF[dl][j];
    if (j > tq) SB += sQB[dl][j];
  }

  const ushort* y0p = y + ((size_t)(0 * B_SZ + b) * L_SEQ) * D_INNER;
  const ushort* y1p = y + ((size_t)(1 * B_SZ + b) * L_SEQ) * D_INNER;
  float yacc[16];
#pragma unroll
  for (int i = 0; i < 16; ++i) {
    const int t = tq * 16 + i;
    SF += sd0[t][dl];
    float wf = 0.f;
#pragma unroll
    for (int n = 0; n < 16; ++n)
      wf += sC0[t][n] * (ex2(AnF[n] * SF) * hF[n]);
    yacc[i] = bf2f(y0p[(size_t)(lbase + t) * D_INNER + d]) + wf;
  }
#pragma unroll
  for (int i = 15; i >= 0; --i) {
    const int t = tq * 16 + i;
    SB += sd1[t][dl];
    float wb = 0.f;
#pragma unroll
    for (int n = 0; n < 16; ++n)
      wb += sC1[t][n] * (ex2(AnB[n] * SB) * hB[n]);
    yacc[i] += bf2f(y1p[(size_t)(lbase + t) * D_INNER + d]) + wb;
  }
#pragma unroll
  for (int i = 0; i < 16; ++i) {
    const int l = lbase + tq * 16 + i;
    const float z = bf2f(xz_bf[((size_t)b * L_SEQ + l) * 3072 + 1536 + d]);
    yg[((size_t)b * L_SEQ + l) * D_INNER + d] = f2bf(yacc[i] * z);
  }
}

// ---------------------------------------------------------------------------
extern "C" void kernel_launch(void* const* d_in, const int* in_sizes, int n_in,
                              void* d_out, int out_size, void* d_ws,
                              size_t ws_size, hipStream_t stream) {
  const float* x          = (const float*)d_in[0];
  const float* in_proj_w  = (const float*)d_in[1];
  const float* conv_w     = (const float*)d_in[2];
  const float* conv_b     = (const float*)d_in[3];
  const float* x_proj_w   = (const float*)d_in[4];
  const float* dt_proj_w  = (const float*)d_in[5];
  const float* dt_proj_b  = (const float*)d_in[6];
  const float* A_logs     = (const float*)d_in[7];
  const float* Ds         = (const float*)d_in[8];
  const float* out_proj_w = (const float*)d_in[9];
  float* out = (float*)d_out;

  const int M = MTOT;
  const size_t NST = (size_t)2 * B_SZ * NCH * NDG;  // 3072

  float* ws    = (float*)d_ws;
  float* xdbl  = ws;                          // M*160
  float* hfin  = xdbl + (size_t)M * 160;      // NST*1024
  float* hin   = hfin + NST * 1024;           // NST*1024
  float* Tsum  = hin + NST * 1024;            // NST*64
  ushort* x_bf     = (ushort*)(Tsum + NST * 64);
  ushort* w_in_bf  = x_bf + (size_t)M * 768;
  ushort* w_out_bf = w_in_bf + (size_t)3072 * 768;
  ushort* w_xp_bf  = w_out_bf + (size_t)768 * 1536;
  ushort* w_dt_bf  = w_xp_bf + (size_t)256 * 1536;
  ushort* xz_bf    = w_dt_bf + (size_t)2 * 1536 * 64;
  ushort* u_bf     = xz_bf + (size_t)M * 3072;
  ushort* delta_bf = u_bf + (size_t)M * 1536;
  ushort* dtin     = delta_bf + (size_t)2 * M * 1536;
  ushort* y_bf     = dtin + (size_t)2 * M * 64;
  ushort* yg_bf    = y_bf + (size_t)2 * M * 1536;

  dim3 blk(256);

  // 0. conversions (one kernel)
  {
    const long TOT = 3145728L + 2359296 + 1179648 + 393216 + 196608;
    cvt_all_kernel<<<dim3((TOT / 4 + 255) / 256), blk, 0, stream>>>(
        x, in_proj_w, out_proj_w, x_proj_w, dt_proj_w, x_bf, w_in_bf, w_out_bf,
        w_xp_bf, w_dt_bf);
  }

  // 1. xz = x @ in_proj_w^T  -> bf16
  gemm_k<128, 128, 0, 1, 0><<<dim3(3072 / 128, M / 128), blk, 0, stream>>>(
      x_bf, 768, w_in_bf, 768, nullptr, xz_bf, 3072, 3072, 768, nullptr);

  // 2. u = silu(conv(x_conv)+bias) -> bf16
  conv_silu_kernel<<<dim3(M * (D_INNER / 8) / 256), blk, 0, stream>>>(
      xz_bf, conv_w, conv_b, u_bf);

  // 3. xdbl = u @ x_proj_w^T -> fp32 (+ dtin bf16 epilogue)
  gemm_k<64, 64, 0, 0, 1><<<dim3(256 / 64, M / 64), blk, 0, stream>>>(
      u_bf, 1536, w_xp_bf, 1536, nullptr, xdbl, 160, 160, 1536, dtin);

  // 4. delta = softplus(dtin @ dtw^T + dtb) -> bf16 (both k, one dispatch)
  gemm_dt_k<<<dim3(1536 / 128, M / 64, 2), blk, 0, stream>>>(
      dtin, w_dt_bf, dt_proj_b, delta_bf);

  // 5. scan
  scan_local_kernel<<<dim3(2 * B_SZ * NDG * NCH), blk, 0, stream>>>(
      u_bf, xdbl, delta_bf, A_logs, Ds, y_bf, hfin, Tsum);
  scan_stitch_kernel<<<dim3(2 * B_SZ * NDG), blk, 0, stream>>>(hfin, Tsum,
                                                               A_logs, hin);
  // 6. fused fixup(both dirs) + gate -> yg bf16
  fixup_gate_kernel<<<dim3(B_SZ * NDG * NCH), blk, 0, stream>>>(
      xdbl, delta_bf, A_logs, hin, y_bf, xz_bf, yg_bf);

  // 7. out = yg @ out_proj_w^T -> fp32
  gemm_k<128, 128, 0, 0, 0><<<dim3(768 / 128, M / 128), blk, 0, stream>>>(
      yg_bf, 1536, w_out_bf, 1536, nullptr, out, 768, 768, 1536, nullptr);
}

// Round 9
// 228.652 us; speedup vs baseline: 4.7116x; 1.0950x over previous
//
#include <hip/hip_runtime.h>
#include <math.h>

#define D_MODEL 768
#define D_STATE 16
#define D_INNER 1536
#define DT_RANK 48
#define B_SZ    2
#define L_SEQ   2048
#define CH      64             // scan chunk length
#define NCH     (L_SEQ / CH)   // 32 chunks
#define NDG     24             // d-groups of 64 channels
#define MTOT    (B_SZ * L_SEQ) // 4096
#define LOG2E   1.4426950408889634f
#define LN2     0.6931471805599453f

typedef __bf16 bf16x8 __attribute__((ext_vector_type(8)));
typedef float f32x4 __attribute__((ext_vector_type(4)));
typedef ushort ushort8_t __attribute__((ext_vector_type(8)));

__device__ __forceinline__ float ex2(float x) {
  return __builtin_amdgcn_exp2f(x);  // v_exp_f32: D = 2^S0
}

__device__ __forceinline__ ushort f2bf(float f) {
  unsigned int u = __float_as_uint(f);
  unsigned int r = (u + 0x7fff + ((u >> 16) & 1)) >> 16;
  return (ushort)r;
}
__device__ __forceinline__ float bf2f(ushort u) {
  return __uint_as_float(((unsigned int)u) << 16);
}

__device__ __forceinline__ void gload_lds16(const ushort* g, ushort* l) {
  __builtin_amdgcn_global_load_lds(
      (__attribute__((address_space(1))) void*)(void*)(g),
      (__attribute__((address_space(3))) void*)(void*)(l), 16, 0, 0);
}

// fast softplus: ln(1+e^x) = ln2 * log2(1 + 2^(x*log2e)); guard large x
__device__ __forceinline__ float softplus_fast(float x) {
  return (x > 20.f) ? x : LN2 * __log2f(1.f + ex2(x * LOG2E));
}

// ---------------------------------------------------------------------------
// bf16 MFMA GEMM body, double-buffered 2-phase K-loop.
// C[M,N] = A[M,K] * B[N,K]^T (+bias, +softplus). OBF: bf16 C. DTOUT: also
// emit dtin bf16 (cols 0..47 -> k0, 80..127 -> k1, pad to 64 with zeros).
// ---------------------------------------------------------------------------
template <int BM, int BN, int ACT, int OBF, int DTOUT>
__device__ __forceinline__ void gemm_body(
    const ushort* __restrict__ A, int lda, const ushort* __restrict__ B,
    int ldb, const float* __restrict__ bias, void* __restrict__ Cp, int ldc,
    int Nreal, int K, int bxi, int byi, ushort* __restrict__ dtin) {
  __shared__ ushort As[2][BM][32];
  __shared__ ushort Bs[2][BN][32];
  constexpr int WM = BM / 2, WN = BN / 2;
  constexpr int FM = WM / 16, FN = WN / 16;
  const int tid = threadIdx.x;
  const int lane = tid & 63;
  const int w = tid >> 6;
  const int wr = w >> 1, wc = w & 1;
  const int bm = byi * BM, bn = bxi * BN;
  const int lrow = lane >> 2;
  const int lchunk = lane & 3;
  const int fr = lane & 15;
  const int k8 = (lane >> 4) * 8;

  f32x4 acc[FM][FN] = {};

  auto stage = [&](int buf, int k0) {
#pragma unroll
    for (int g = 0; g < BM / 64; ++g) {
      const int rb = w * (BM / 4) + g * 16;
      gload_lds16(A + (size_t)(bm + rb + lrow) * lda + k0 + lchunk * 8,
                  &As[buf][rb][0]);
    }
#pragma unroll
    for (int g = 0; g < BN / 64; ++g) {
      const int rb = w * (BN / 4) + g * 16;
      gload_lds16(B + (size_t)(bn + rb + lrow) * ldb + k0 + lchunk * 8,
                  &Bs[buf][rb][0]);
    }
  };

  stage(0, 0);
  __syncthreads();
  int cur = 0;
  for (int k0 = 0; k0 < K; k0 += 32) {
    if (k0 + 32 < K) stage(cur ^ 1, k0 + 32);
    bf16x8 af[FM], bfr[FN];
#pragma unroll
    for (int m = 0; m < FM; ++m)
      af[m] =
          *reinterpret_cast<const bf16x8*>(&As[cur][wr * WM + m * 16 + fr][k8]);
#pragma unroll
    for (int n = 0; n < FN; ++n)
      bfr[n] =
          *reinterpret_cast<const bf16x8*>(&Bs[cur][wc * WN + n * 16 + fr][k8]);
#pragma unroll
    for (int m = 0; m < FM; ++m)
#pragma unroll
      for (int n = 0; n < FN; ++n)
        acc[m][n] = __builtin_amdgcn_mfma_f32_16x16x32_bf16(af[m], bfr[n],
                                                            acc[m][n], 0, 0, 0);
    __syncthreads();
    cur ^= 1;
  }

  const int row4 = (lane >> 4) * 4;
#pragma unroll
  for (int m = 0; m < FM; ++m) {
#pragma unroll
    for (int n = 0; n < FN; ++n) {
      const int gn = bn + wc * WN + n * 16 + fr;
      const int gm0 = bm + wr * WM + m * 16 + row4;
#pragma unroll
      for (int j = 0; j < 4; ++j) {
        const float v = acc[m][n][j];
        const int gm = gm0 + j;
        if (DTOUT) {
          if (gn < 64)
            dtin[(size_t)gm * 64 + gn] = (gn < 48) ? f2bf(v) : (ushort)0;
          else if (gn >= 80 && gn < 144)
            dtin[(size_t)MTOT * 64 + (size_t)gm * 64 + (gn - 80)] =
                (gn < 128) ? f2bf(v) : (ushort)0;
        }
        if (gn < Nreal) {
          float vv = v + (bias ? bias[gn] : 0.f);
          if (ACT == 1) vv = softplus_fast(vv);
          if (OBF)
            ((ushort*)Cp)[(size_t)gm * ldc + gn] = f2bf(vv);
          else
            ((float*)Cp)[(size_t)gm * ldc + gn] = vv;
        }
      }
    }
  }
}

template <int BM, int BN, int ACT, int OBF, int DTOUT>
__global__ __launch_bounds__(256) void gemm_k(
    const ushort* __restrict__ A, int lda, const ushort* __restrict__ B,
    int ldb, const float* __restrict__ bias, void* __restrict__ Cp, int ldc,
    int Nreal, int K, ushort* __restrict__ dtin) {
  gemm_body<BM, BN, ACT, OBF, DTOUT>(A, lda, B, ldb, bias, Cp, ldc, Nreal, K,
                                     blockIdx.x, blockIdx.y, dtin);
}

// dt_proj both directions in one dispatch (blockIdx.z = k); 64x128 tile
__global__ __launch_bounds__(256) void gemm_dt_k(
    const ushort* __restrict__ dtin, const ushort* __restrict__ w_dt,
    const float* __restrict__ dtb, ushort* __restrict__ delta) {
  const int k = blockIdx.z;
  gemm_body<64, 128, 1, 1, 0>(
      dtin + (size_t)k * MTOT * 64, 64, w_dt + (size_t)k * D_INNER * 64, 64,
      dtb + k * D_INNER, delta + (size_t)k * MTOT * D_INNER, D_INNER, D_INNER,
      64, blockIdx.x, blockIdx.y, nullptr);
}

// ---------------------------------------------------------------------------
// One-shot fp32->bf16 conversion of x + all weights (with padding).
// ---------------------------------------------------------------------------
__global__ __launch_bounds__(256) void cvt_all_kernel(
    const float* __restrict__ x, const float* __restrict__ w_in,
    const float* __restrict__ w_out, const float* __restrict__ w_xp,
    const float* __restrict__ w_dt, ushort* __restrict__ x_bf,
    ushort* __restrict__ w_in_bf, ushort* __restrict__ w_out_bf,
    ushort* __restrict__ w_xp_bf, ushort* __restrict__ w_dt_bf) {
  const long N0 = 3145728, N1 = 2359296, N2 = 1179648, N3 = 393216, N4 = 196608;
  long i = ((long)blockIdx.x * 256 + threadIdx.x) * 4;
  if (i < N0) {
    const float4 v = *(const float4*)(x + i);
    ushort4 o = {f2bf(v.x), f2bf(v.y), f2bf(v.z), f2bf(v.w)};
    *(ushort4*)(x_bf + i) = o;
    return;
  }
  i -= N0;
  if (i < N1) {
    const float4 v = *(const float4*)(w_in + i);
    ushort4 o = {f2bf(v.x), f2bf(v.y), f2bf(v.z), f2bf(v.w)};
    *(ushort4*)(w_in_bf + i) = o;
    return;
  }
  i -= N1;
  if (i < N2) {
    const float4 v = *(const float4*)(w_out + i);
    ushort4 o = {f2bf(v.x), f2bf(v.y), f2bf(v.z), f2bf(v.w)};
    *(ushort4*)(w_out_bf + i) = o;
    return;
  }
  i -= N2;
  if (i < N3) {
    const long row = i / 1536;
    ushort4 o = {0, 0, 0, 0};
    if (row < 160) {
      const float4 v = *(const float4*)(w_xp + i);
      o.x = f2bf(v.x); o.y = f2bf(v.y); o.z = f2bf(v.z); o.w = f2bf(v.w);
    }
    *(ushort4*)(w_xp_bf + i) = o;
    return;
  }
  i -= N3;
  if (i < N4) {
    const int col = (int)(i & 63);
    const long row = i >> 6;
    ushort4 o = {0, 0, 0, 0};
    if (col < 48) {
      const float4 v = *(const float4*)(w_dt + row * 48 + col);
      o.x = f2bf(v.x); o.y = f2bf(v.y); o.z = f2bf(v.z); o.w = f2bf(v.w);
    }
    *(ushort4*)(w_dt_bf + i) = o;
  }
}

// ---------------------------------------------------------------------------
// Depthwise conv (k=3, pad=1) + bias + SiLU, bf16 in/out.
// Thread = 8 channels x 8 rows (rolling window): each row loaded once.
// ---------------------------------------------------------------------------
__global__ __launch_bounds__(256) void conv_silu_kernel(
    const ushort* __restrict__ xz, const float* __restrict__ cw,
    const float* __restrict__ cb, ushort* __restrict__ u_bf) {
  const int nd8 = D_INNER / 8;  // 192
  const int idx = blockIdx.x * 256 + threadIdx.x;
  const int d8 = idx % nd8;
  const int lg = (idx / nd8) % (L_SEQ / 8);
  const int b = idx / (nd8 * (L_SEQ / 8));
  const int d = d8 * 8;
  const int l0 = lg * 8;

  float w0[8], w1[8], w2[8], bs[8];
#pragma unroll
  for (int j = 0; j < 8; ++j) {
    w0[j] = cw[(d + j) * 3 + 0];
    w1[j] = cw[(d + j) * 3 + 1];
    w2[j] = cw[(d + j) * 3 + 2];
    bs[j] = cb[d + j];
  }
  const ushort* base = xz + ((size_t)b * L_SEQ) * 3072 + d;
  const ushort8_t zv = {0, 0, 0, 0, 0, 0, 0, 0};
  ushort8_t prev = (l0 > 0) ? *(const ushort8_t*)(base + (size_t)(l0 - 1) * 3072) : zv;
  ushort8_t curv = *(const ushort8_t*)(base + (size_t)l0 * 3072);
#pragma unroll
  for (int i = 0; i < 8; ++i) {
    const int l = l0 + i;
    const ushort8_t nxt =
        (l + 1 < L_SEQ) ? *(const ushort8_t*)(base + (size_t)(l + 1) * 3072) : zv;
    ushort8_t o;
#pragma unroll
    for (int j = 0; j < 8; ++j) {
      const float a = bs[j] + bf2f(prev[j]) * w0[j] + bf2f(curv[j]) * w1[j] +
                      bf2f(nxt[j]) * w2[j];
      o[j] = f2bf(a / (1.f + __expf(-a)));
    }
    *(ushort8_t*)(u_bf + ((size_t)b * L_SEQ + l) * D_INNER + d) = o;
    prev = curv;
    curv = nxt;
  }
}

// ---------------------------------------------------------------------------
// K1: local scan. Block = (k,b,dgB of 64 ch, chunk of 64 l). Wave = 16d x 4nq.
// Lane holds h[4]; 2 shuffles/step. y out bf16. Register-prefetch of next
// sub-tile's global loads overlaps the current sub-tile's compute (T14).
// ---------------------------------------------------------------------------
__global__ __launch_bounds__(256) void scan_local_kernel(
    const ushort* __restrict__ u_bf, const float* __restrict__ xdbl,
    const ushort* __restrict__ delta_bf, const float* __restrict__ A_logs,
    const float* __restrict__ Ds, ushort* __restrict__ y,
    float* __restrict__ hfin, float* __restrict__ Tsum) {
  __shared__ float sd[32][64], su[32][64], sB[32][16], sC[32][16];
  const int tid = threadIdx.x;
  const int lane = tid & 63;
  const int w = tid >> 6;
  const int c = lane & 15;
  const int nq = lane >> 4;
  const int bid = blockIdx.x;
  const int ch = bid & (NCH - 1);
  const int rest = bid >> 5;
  const int dgB = rest % NDG;
  const int kb = rest / NDG;
  const int b = kb & 1;
  const int k = kb >> 1;
  const int d0 = dgB * 64;
  const int dl = w * 16 + c;
  const int d = d0 + dl;
  const int row = k * D_INNER + d;

  const float4 alv = *(const float4*)(A_logs + (size_t)row * D_STATE + nq * 4);
  const float An0 = -__expf(alv.x) * LOG2E, An1 = -__expf(alv.y) * LOG2E;
  const float An2 = -__expf(alv.z) * LOG2E, An3 = -__expf(alv.w) * LOG2E;
  const float Dk = Ds[row];

  const ushort* uptr = u_bf + ((size_t)b * L_SEQ) * D_INNER;
  const ushort* dptr = delta_bf + ((size_t)(k * B_SZ + b) * L_SEQ) * D_INNER;
  const float* xptr = xdbl + ((size_t)b * L_SEQ) * 160 + k * 80;
  ushort* yptr = y + ((size_t)(k * B_SZ + b) * L_SEQ) * D_INNER;

  // staging geometry
  const int r_st = tid >> 3, seg = tid & 7;
  const int ridx_st = k ? (31 - r_st) : r_st;
  const int t2 = tid & 127;
  const int rBC = t2 >> 2;
  const int ridx_bc = k ? (31 - rBC) : rBC;
  const int c4 = (t2 & 3) * 4;
  const bool isB = tid < 128;

  ushort8_t dv, uv;
  float4 bc;
  auto gload = [&](int sub) {
    const int t0 = ch * CH + sub * 32;
    const int lbase = k ? (L_SEQ - 32 - t0) : t0;
    const size_t off = (size_t)(lbase + r_st) * D_INNER + d0 + seg * 8;
    dv = *(const ushort8_t*)(dptr + off);
    uv = *(const ushort8_t*)(uptr + off);
    const size_t rowL = (size_t)(lbase + rBC);
    bc = isB ? *(const float4*)(xptr + rowL * 160 + DT_RANK + c4)
             : *(const float4*)(xptr + rowL * 160 + DT_RANK + D_STATE + c4);
  };

  gload(0);

  float h0 = 0.f, h1 = 0.f, h2 = 0.f, h3 = 0.f, S = 0.f;

  for (int sub = 0; sub < CH / 32; ++sub) {
    // write staged registers to LDS (float4 stores)
    *(float4*)&sd[ridx_st][seg * 8] =
        make_float4(bf2f(dv[0]), bf2f(dv[1]), bf2f(dv[2]), bf2f(dv[3]));
    *(float4*)&sd[ridx_st][seg * 8 + 4] =
        make_float4(bf2f(dv[4]), bf2f(dv[5]), bf2f(dv[6]), bf2f(dv[7]));
    *(float4*)&su[ridx_st][seg * 8] =
        make_float4(bf2f(uv[0]), bf2f(uv[1]), bf2f(uv[2]), bf2f(uv[3]));
    *(float4*)&su[ridx_st][seg * 8 + 4] =
        make_float4(bf2f(uv[4]), bf2f(uv[5]), bf2f(uv[6]), bf2f(uv[7]));
    if (isB)
      *(float4*)&sB[ridx_bc][c4] = bc;
    else
      *(float4*)&sC[ridx_bc][c4] = bc;
    __syncthreads();
    // prefetch next sub-tile while computing this one
    if (sub + 1 < CH / 32) gload(sub + 1);
    const int t0 = ch * CH + sub * 32;
    for (int s = 0; s < 32; ++s) {
      const float dlt = sd[s][dl];
      const float uu = su[s][dl];
      S += dlt;
      const float4 Bv = *(const float4*)&sB[s][nq * 4];
      const float4 Cv = *(const float4*)&sC[s][nq * 4];
      const float du = dlt * uu;
      h0 = h0 * ex2(dlt * An0) + du * Bv.x;
      h1 = h1 * ex2(dlt * An1) + du * Bv.y;
      h2 = h2 * ex2(dlt * An2) + du * Bv.z;
      h3 = h3 * ex2(dlt * An3) + du * Bv.w;
      float yt = h0 * Cv.x + h1 * Cv.y + h2 * Cv.z + h3 * Cv.w;
      yt += __shfl_xor(yt, 16);
      yt += __shfl_xor(yt, 32);
      if (nq == 0) {
        const int t = t0 + s;
        const int l = k ? (L_SEQ - 1 - t) : t;
        yptr[(size_t)l * D_INNER + d] = f2bf(yt + uu * Dk);
      }
    }
    __syncthreads();
  }

  const size_t cidxB = ((size_t)(k * B_SZ + b) * NCH + ch) * NDG + dgB;
  *(float4*)(hfin + cidxB * 1024 + dl * 16 + nq * 4) =
      make_float4(h0, h1, h2, h3);
  if (nq == 0) Tsum[cidxB * 64 + dl] = S;
}

// ---------------------------------------------------------------------------
// K2: stitch. Block = (k,b,dgB). Thread = (dl = tid>>2, nq = tid&3).
// ---------------------------------------------------------------------------
__global__ __launch_bounds__(256) void scan_stitch_kernel(
    const float* __restrict__ hfin, const float* __restrict__ Tsum,
    const float* __restrict__ A_logs, float* __restrict__ hin) {
  const int tid = threadIdx.x;
  const int dl = tid >> 2;
  const int nq = tid & 3;
  const int bid = blockIdx.x;
  const int dgB = bid % NDG;
  const int b = (bid / NDG) & 1;
  const int k = bid / (NDG * 2);
  const int row = k * D_INNER + dgB * 64 + dl;
  const float4 alv = *(const float4*)(A_logs + (size_t)row * D_STATE + nq * 4);
  const float An0 = -__expf(alv.x) * LOG2E, An1 = -__expf(alv.y) * LOG2E;
  const float An2 = -__expf(alv.z) * LOG2E, An3 = -__expf(alv.w) * LOG2E;
  float c0 = 0.f, c1 = 0.f, c2 = 0.f, c3 = 0.f;
  for (int ch = 0; ch < NCH; ++ch) {
    const size_t cidxB = ((size_t)(k * B_SZ + b) * NCH + ch) * NDG + dgB;
    const size_t off = cidxB * 1024 + dl * 16 + nq * 4;
    *(float4*)(hin + off) = make_float4(c0, c1, c2, c3);
    const float T = Tsum[cidxB * 64 + dl];
    const float4 hf = *(const float4*)(hfin + off);
    c0 = c0 * ex2(An0 * T) + hf.x;
    c1 = c1 * ex2(An1 * T) + hf.y;
    c2 = c2 * ex2(An2 * T) + hf.z;
    c3 = c3 * ex2(An3 * T) + hf.w;
  }
}

// ---------------------------------------------------------------------------
// K3: fused fixup (both directions) + gate -> yg bf16.
// ---------------------------------------------------------------------------
__global__ __launch_bounds__(256) void fixup_gate_kernel(
    const float* __restrict__ xdbl, const ushort* __restrict__ delta_bf,
    const float* __restrict__ A_logs, const float* __restrict__ hin,
    const ushort* __restrict__ y, const ushort* __restrict__ xz_bf,
    ushort* __restrict__ yg) {
  __shared__ float sd0[64][64], sd1[64][64];
  __shared__ float sC0[64][16], sC1[64][16];
  __shared__ float sQF[64][4], sQB[64][4];
  const int tid = threadIdx.x;
  const int tq = tid >> 6;
  const int dl = tid & 63;
  const int bid = blockIdx.x;
  const int ch = bid & (NCH - 1);
  const int rest = bid >> 5;
  const int dgB = rest % NDG;
  const int b = rest / NDG;
  const int d0 = dgB * 64;
  const int d = d0 + dl;
  const int lbase = ch * CH;
  const int chb = NCH - 1 - ch;

  float AnF[16], AnB[16], hF[16], hB[16];
#pragma unroll
  for (int q = 0; q < 4; ++q) {
    const float4 af = *(const float4*)(A_logs + (size_t)d * D_STATE + q * 4);
    AnF[q * 4 + 0] = -__expf(af.x) * LOG2E;
    AnF[q * 4 + 1] = -__expf(af.y) * LOG2E;
    AnF[q * 4 + 2] = -__expf(af.z) * LOG2E;
    AnF[q * 4 + 3] = -__expf(af.w) * LOG2E;
    const float4 ab =
        *(const float4*)(A_logs + (size_t)(D_INNER + d) * D_STATE + q * 4);
    AnB[q * 4 + 0] = -__expf(ab.x) * LOG2E;
    AnB[q * 4 + 1] = -__expf(ab.y) * LOG2E;
    AnB[q * 4 + 2] = -__expf(ab.z) * LOG2E;
    AnB[q * 4 + 3] = -__expf(ab.w) * LOG2E;
  }
  const size_t cF = ((size_t)(0 * B_SZ + b) * NCH + ch) * NDG + dgB;
  const size_t cB = ((size_t)(1 * B_SZ + b) * NCH + chb) * NDG + dgB;
#pragma unroll
  for (int q = 0; q < 4; ++q) {
    const float4 hv = *(const float4*)(hin + cF * 1024 + dl * 16 + q * 4);
    hF[q * 4 + 0] = hv.x; hF[q * 4 + 1] = hv.y;
    hF[q * 4 + 2] = hv.z; hF[q * 4 + 3] = hv.w;
    const float4 hw = *(const float4*)(hin + cB * 1024 + dl * 16 + q * 4);
    hB[q * 4 + 0] = hw.x; hB[q * 4 + 1] = hw.y;
    hB[q * 4 + 2] = hw.z; hB[q * 4 + 3] = hw.w;
  }

  const ushort* d0p =
      delta_bf + ((size_t)(0 * B_SZ + b) * L_SEQ + lbase) * D_INNER + d0;
  const ushort* d1p =
      delta_bf + ((size_t)(1 * B_SZ + b) * L_SEQ + lbase) * D_INNER + d0;
#pragma unroll
  for (int i = 0; i < 2; ++i) {
    const int unit = tid + i * 256;
    const int r = unit >> 3, seg = unit & 7;
    const ushort8_t v0 =
        *(const ushort8_t*)(d0p + (size_t)r * D_INNER + seg * 8);
    const ushort8_t v1 =
        *(const ushort8_t*)(d1p + (size_t)r * D_INNER + seg * 8);
    *(float4*)&sd0[r][seg * 8] =
        make_float4(bf2f(v0[0]), bf2f(v0[1]), bf2f(v0[2]), bf2f(v0[3]));
    *(float4*)&sd0[r][seg * 8 + 4] =
        make_float4(bf2f(v0[4]), bf2f(v0[5]), bf2f(v0[6]), bf2f(v0[7]));
    *(float4*)&sd1[r][seg * 8] =
        make_float4(bf2f(v1[0]), bf2f(v1[1]), bf2f(v1[2]), bf2f(v1[3]));
    *(float4*)&sd1[r][seg * 8 + 4] =
        make_float4(bf2f(v1[4]), bf2f(v1[5]), bf2f(v1[6]), bf2f(v1[7]));
  }
  {
    const int r = tid >> 2;
    const int c4 = (tid & 3) * 4;
    const float* xrow = xdbl + ((size_t)b * L_SEQ + lbase + r) * 160;
    *(float4*)&sC0[r][c4] = *(const float4*)(xrow + DT_RANK + D_STATE + c4);
    *(float4*)&sC1[r][c4] =
        *(const float4*)(xrow + 80 + DT_RANK + D_STATE + c4);
  }
  __syncthreads();
  float qf = 0.f, qb = 0.f;
#pragma unroll
  for (int i = 0; i < 16; ++i) {
    qf += sd0[tq * 16 + i][dl];
    qb += sd1[tq * 16 + i][dl];
  }
  sQF[dl][tq] = qf;
  sQB[dl][tq] = qb;
  __syncthreads();
  float SF = 0.f, SB = 0.f;
#pragma unroll
  for (int j = 0; j < 4; ++j) {
    if (j < tq) SF += sQF[dl][j];
    if (j > tq) SB += sQB[dl][j];
  }

  const ushort* y0p = y + ((size_t)(0 * B_SZ + b) * L_SEQ) * D_INNER;
  const ushort* y1p = y + ((size_t)(1 * B_SZ + b) * L_SEQ) * D_INNER;
  float yacc[16];
#pragma unroll
  for (int i = 0; i < 16; ++i) {
    const int t = tq * 16 + i;
    SF += sd0[t][dl];
    float wf = 0.f;
#pragma unroll
    for (int n = 0; n < 16; ++n)
      wf += sC0[t][n] * (ex2(AnF[n] * SF) * hF[n]);
    yacc[i] = bf2f(y0p[(size_t)(lbase + t) * D_INNER + d]) + wf;
  }
#pragma unroll
  for (int i = 15; i >= 0; --i) {
    const int t = tq * 16 + i;
    SB += sd1[t][dl];
    float wb = 0.f;
#pragma unroll
    for (int n = 0; n < 16; ++n)
      wb += sC1[t][n] * (ex2(AnB[n] * SB) * hB[n]);
    yacc[i] += bf2f(y1p[(size_t)(lbase + t) * D_INNER + d]) + wb;
  }
#pragma unroll
  for (int i = 0; i < 16; ++i) {
    const int l = lbase + tq * 16 + i;
    const float z = bf2f(xz_bf[((size_t)b * L_SEQ + l) * 3072 + 1536 + d]);
    yg[((size_t)b * L_SEQ + l) * D_INNER + d] = f2bf(yacc[i] * z);
  }
}

// ---------------------------------------------------------------------------
extern "C" void kernel_launch(void* const* d_in, const int* in_sizes, int n_in,
                              void* d_out, int out_size, void* d_ws,
                              size_t ws_size, hipStream_t stream) {
  const float* x          = (const float*)d_in[0];
  const float* in_proj_w  = (const float*)d_in[1];
  const float* conv_w     = (const float*)d_in[2];
  const float* conv_b     = (const float*)d_in[3];
  const float* x_proj_w   = (const float*)d_in[4];
  const float* dt_proj_w  = (const float*)d_in[5];
  const float* dt_proj_b  = (const float*)d_in[6];
  const float* A_logs     = (const float*)d_in[7];
  const float* Ds         = (const float*)d_in[8];
  const float* out_proj_w = (const float*)d_in[9];
  float* out = (float*)d_out;

  const int M = MTOT;
  const size_t NST = (size_t)2 * B_SZ * NCH * NDG;  // 3072

  float* ws    = (float*)d_ws;
  float* xdbl  = ws;                          // M*160
  float* hfin  = xdbl + (size_t)M * 160;      // NST*1024
  float* hin   = hfin + NST * 1024;           // NST*1024
  float* Tsum  = hin + NST * 1024;            // NST*64
  ushort* x_bf     = (ushort*)(Tsum + NST * 64);
  ushort* w_in_bf  = x_bf + (size_t)M * 768;
  ushort* w_out_bf = w_in_bf + (size_t)3072 * 768;
  ushort* w_xp_bf  = w_out_bf + (size_t)768 * 1536;
  ushort* w_dt_bf  = w_xp_bf + (size_t)256 * 1536;
  ushort* xz_bf    = w_dt_bf + (size_t)2 * 1536 * 64;
  ushort* u_bf     = xz_bf + (size_t)M * 3072;
  ushort* delta_bf = u_bf + (size_t)M * 1536;
  ushort* dtin     = delta_bf + (size_t)2 * M * 1536;
  ushort* y_bf     = dtin + (size_t)2 * M * 64;
  ushort* yg_bf    = y_bf + (size_t)2 * M * 1536;

  dim3 blk(256);

  // 0. conversions (one kernel)
  {
    const long TOT = 3145728L + 2359296 + 1179648 + 393216 + 196608;
    cvt_all_kernel<<<dim3((TOT / 4 + 255) / 256), blk, 0, stream>>>(
        x, in_proj_w, out_proj_w, x_proj_w, dt_proj_w, x_bf, w_in_bf, w_out_bf,
        w_xp_bf, w_dt_bf);
  }

  // 1. xz = x @ in_proj_w^T  -> bf16
  gemm_k<128, 128, 0, 1, 0><<<dim3(3072 / 128, M / 128), blk, 0, stream>>>(
      x_bf, 768, w_in_bf, 768, nullptr, xz_bf, 3072, 3072, 768, nullptr);

  // 2. u = silu(conv(x_conv)+bias) -> bf16 (8 rows per thread)
  conv_silu_kernel<<<dim3(B_SZ * (L_SEQ / 8) * (D_INNER / 8) / 256), blk, 0,
                     stream>>>(xz_bf, conv_w, conv_b, u_bf);

  // 3. xdbl = u @ x_proj_w^T -> fp32 (+ dtin bf16 epilogue); 3 N-tiles
  gemm_k<64, 64, 0, 0, 1><<<dim3(3, M / 64), blk, 0, stream>>>(
      u_bf, 1536, w_xp_bf, 1536, nullptr, xdbl, 160, 160, 1536, dtin);

  // 4. delta = softplus(dtin @ dtw^T + dtb) -> bf16 (both k, one dispatch)
  gemm_dt_k<<<dim3(1536 / 128, M / 64, 2), blk, 0, stream>>>(
      dtin, w_dt_bf, dt_proj_b, delta_bf);

  // 5. scan
  scan_local_kernel<<<dim3(2 * B_SZ * NDG * NCH), blk, 0, stream>>>(
      u_bf, xdbl, delta_bf, A_logs, Ds, y_bf, hfin, Tsum);
  scan_stitch_kernel<<<dim3(2 * B_SZ * NDG), blk, 0, stream>>>(hfin, Tsum,
                                                               A_logs, hin);
  // 6. fused fixup(both dirs) + gate -> yg bf16
  fixup_gate_kernel<<<dim3(B_SZ * NDG * NCH), blk, 0, stream>>>(
      xdbl, delta_bf, A_logs, hin, y_bf, xz_bf, yg_bf);

  // 7. out = yg @ out_proj_w^T -> fp32
  gemm_k<128, 128, 0, 0, 0><<<dim3(768 / 128, M / 128), blk, 0, stream>>>(
      yg_bf, 1536, w_out_bf, 1536, nullptr, out, 768, 768, 1536, nullptr);
}

// Round 10
// 223.233 us; speedup vs baseline: 4.8259x; 1.0243x over previous
//
#include <hip/hip_runtime.h>
#include <math.h>

#define D_MODEL 768
#define D_STATE 16
#define D_INNER 1536
#define DT_RANK 48
#define B_SZ    2
#define L_SEQ   2048
#define CH      64             // scan chunk length
#define NCH     (L_SEQ / CH)   // 32 chunks
#define NDG     24             // d-groups of 64 channels
#define MTOT    (B_SZ * L_SEQ) // 4096
#define LOG2E   1.4426950408889634f
#define LN2     0.6931471805599453f

typedef __bf16 bf16x8 __attribute__((ext_vector_type(8)));
typedef float f32x4 __attribute__((ext_vector_type(4)));
typedef ushort ushort8_t __attribute__((ext_vector_type(8)));

__device__ __forceinline__ float ex2(float x) {
  return __builtin_amdgcn_exp2f(x);  // v_exp_f32: D = 2^S0
}

__device__ __forceinline__ ushort f2bf(float f) {
  unsigned int u = __float_as_uint(f);
  unsigned int r = (u + 0x7fff + ((u >> 16) & 1)) >> 16;
  return (ushort)r;
}
__device__ __forceinline__ float bf2f(ushort u) {
  return __uint_as_float(((unsigned int)u) << 16);
}

__device__ __forceinline__ void gload_lds16(const ushort* g, ushort* l) {
  __builtin_amdgcn_global_load_lds(
      (__attribute__((address_space(1))) void*)(void*)(g),
      (__attribute__((address_space(3))) void*)(void*)(l), 16, 0, 0);
}

// fast softplus: ln(1+e^x) = ln2 * log2(1 + 2^(x*log2e)); guard large x
__device__ __forceinline__ float softplus_fast(float x) {
  return (x > 20.f) ? x : LN2 * __log2f(1.f + ex2(x * LOG2E));
}

// ---------------------------------------------------------------------------
// bf16 MFMA GEMM body, double-buffered 2-phase K-loop.
// C[M,N] = A[M,K] * B[N,K]^T (+bias, +softplus). OBF: bf16 C. DTOUT: also
// emit dtin bf16 (cols 0..47 -> k0, 80..127 -> k1, pad to 64 with zeros).
// Supports BM in {32, 64, 128}.
// ---------------------------------------------------------------------------
template <int BM, int BN, int ACT, int OBF, int DTOUT>
__device__ __forceinline__ void gemm_body(
    const ushort* __restrict__ A, int lda, const ushort* __restrict__ B,
    int ldb, const float* __restrict__ bias, void* __restrict__ Cp, int ldc,
    int Nreal, int K, int bxi, int byi, ushort* __restrict__ dtin) {
  __shared__ ushort As[2][BM][32];
  __shared__ ushort Bs[2][BN][32];
  constexpr int WM = BM / 2, WN = BN / 2;
  constexpr int FM = WM / 16, FN = WN / 16;
  const int tid = threadIdx.x;
  const int lane = tid & 63;
  const int w = tid >> 6;
  const int wr = w >> 1, wc = w & 1;
  const int bm = byi * BM, bn = bxi * BN;
  const int lrow = lane >> 2;
  const int lchunk = lane & 3;
  const int fr = lane & 15;
  const int k8 = (lane >> 4) * 8;

  f32x4 acc[FM][FN] = {};

  auto stage = [&](int buf, int k0) {
    if constexpr (BM >= 64) {
#pragma unroll
      for (int g = 0; g < BM / 64; ++g) {
        const int rb = w * (BM / 4) + g * 16;
        gload_lds16(A + (size_t)(bm + rb + lrow) * lda + k0 + lchunk * 8,
                    &As[buf][rb][0]);
      }
    } else {  // BM == 32: waves 0,1 stage 16 rows each
      if (w < 2)
        gload_lds16(A + (size_t)(bm + w * 16 + lrow) * lda + k0 + lchunk * 8,
                    &As[buf][w * 16][0]);
    }
#pragma unroll
    for (int g = 0; g < BN / 64; ++g) {
      const int rb = w * (BN / 4) + g * 16;
      gload_lds16(B + (size_t)(bn + rb + lrow) * ldb + k0 + lchunk * 8,
                  &Bs[buf][rb][0]);
    }
  };

  stage(0, 0);
  __syncthreads();
  int cur = 0;
  for (int k0 = 0; k0 < K; k0 += 32) {
    if (k0 + 32 < K) stage(cur ^ 1, k0 + 32);
    bf16x8 af[FM], bfr[FN];
#pragma unroll
    for (int m = 0; m < FM; ++m)
      af[m] =
          *reinterpret_cast<const bf16x8*>(&As[cur][wr * WM + m * 16 + fr][k8]);
#pragma unroll
    for (int n = 0; n < FN; ++n)
      bfr[n] =
          *reinterpret_cast<const bf16x8*>(&Bs[cur][wc * WN + n * 16 + fr][k8]);
#pragma unroll
    for (int m = 0; m < FM; ++m)
#pragma unroll
      for (int n = 0; n < FN; ++n)
        acc[m][n] = __builtin_amdgcn_mfma_f32_16x16x32_bf16(af[m], bfr[n],
                                                            acc[m][n], 0, 0, 0);
    __syncthreads();
    cur ^= 1;
  }

  const int row4 = (lane >> 4) * 4;
#pragma unroll
  for (int m = 0; m < FM; ++m) {
#pragma unroll
    for (int n = 0; n < FN; ++n) {
      const int gn = bn + wc * WN + n * 16 + fr;
      const int gm0 = bm + wr * WM + m * 16 + row4;
#pragma unroll
      for (int j = 0; j < 4; ++j) {
        const float v = acc[m][n][j];
        const int gm = gm0 + j;
        if (DTOUT) {
          if (gn < 64)
            dtin[(size_t)gm * 64 + gn] = (gn < 48) ? f2bf(v) : (ushort)0;
          else if (gn >= 80 && gn < 144)
            dtin[(size_t)MTOT * 64 + (size_t)gm * 64 + (gn - 80)] =
                (gn < 128) ? f2bf(v) : (ushort)0;
        }
        if (gn < Nreal) {
          float vv = v + (bias ? bias[gn] : 0.f);
          if (ACT == 1) vv = softplus_fast(vv);
          if (OBF)
            ((ushort*)Cp)[(size_t)gm * ldc + gn] = f2bf(vv);
          else
            ((float*)Cp)[(size_t)gm * ldc + gn] = vv;
        }
      }
    }
  }
}

template <int BM, int BN, int ACT, int OBF, int DTOUT>
__global__ __launch_bounds__(256) void gemm_k(
    const ushort* __restrict__ A, int lda, const ushort* __restrict__ B,
    int ldb, const float* __restrict__ bias, void* __restrict__ Cp, int ldc,
    int Nreal, int K, ushort* __restrict__ dtin) {
  gemm_body<BM, BN, ACT, OBF, DTOUT>(A, lda, B, ldb, bias, Cp, ldc, Nreal, K,
                                     blockIdx.x, blockIdx.y, dtin);
}

// dt_proj both directions in one dispatch (blockIdx.z = k); 64x128 tile
__global__ __launch_bounds__(256) void gemm_dt_k(
    const ushort* __restrict__ dtin, const ushort* __restrict__ w_dt,
    const float* __restrict__ dtb, ushort* __restrict__ delta) {
  const int k = blockIdx.z;
  gemm_body<64, 128, 1, 1, 0>(
      dtin + (size_t)k * MTOT * 64, 64, w_dt + (size_t)k * D_INNER * 64, 64,
      dtb + k * D_INNER, delta + (size_t)k * MTOT * D_INNER, D_INNER, D_INNER,
      64, blockIdx.x, blockIdx.y, nullptr);
}

// ---------------------------------------------------------------------------
// One-shot fp32->bf16 conversion of x + all weights (with padding).
// ---------------------------------------------------------------------------
__global__ __launch_bounds__(256) void cvt_all_kernel(
    const float* __restrict__ x, const float* __restrict__ w_in,
    const float* __restrict__ w_out, const float* __restrict__ w_xp,
    const float* __restrict__ w_dt, ushort* __restrict__ x_bf,
    ushort* __restrict__ w_in_bf, ushort* __restrict__ w_out_bf,
    ushort* __restrict__ w_xp_bf, ushort* __restrict__ w_dt_bf) {
  const long N0 = 3145728, N1 = 2359296, N2 = 1179648, N3 = 393216, N4 = 196608;
  long i = ((long)blockIdx.x * 256 + threadIdx.x) * 4;
  if (i < N0) {
    const float4 v = *(const float4*)(x + i);
    ushort4 o = {f2bf(v.x), f2bf(v.y), f2bf(v.z), f2bf(v.w)};
    *(ushort4*)(x_bf + i) = o;
    return;
  }
  i -= N0;
  if (i < N1) {
    const float4 v = *(const float4*)(w_in + i);
    ushort4 o = {f2bf(v.x), f2bf(v.y), f2bf(v.z), f2bf(v.w)};
    *(ushort4*)(w_in_bf + i) = o;
    return;
  }
  i -= N1;
  if (i < N2) {
    const float4 v = *(const float4*)(w_out + i);
    ushort4 o = {f2bf(v.x), f2bf(v.y), f2bf(v.z), f2bf(v.w)};
    *(ushort4*)(w_out_bf + i) = o;
    return;
  }
  i -= N2;
  if (i < N3) {
    const long row = i / 1536;
    ushort4 o = {0, 0, 0, 0};
    if (row < 160) {
      const float4 v = *(const float4*)(w_xp + i);
      o.x = f2bf(v.x); o.y = f2bf(v.y); o.z = f2bf(v.z); o.w = f2bf(v.w);
    }
    *(ushort4*)(w_xp_bf + i) = o;
    return;
  }
  i -= N3;
  if (i < N4) {
    const int col = (int)(i & 63);
    const long row = i >> 6;
    ushort4 o = {0, 0, 0, 0};
    if (col < 48) {
      const float4 v = *(const float4*)(w_dt + row * 48 + col);
      o.x = f2bf(v.x); o.y = f2bf(v.y); o.z = f2bf(v.z); o.w = f2bf(v.w);
    }
    *(ushort4*)(w_dt_bf + i) = o;
  }
}

// ---------------------------------------------------------------------------
// Depthwise conv (k=3, pad=1) + bias + SiLU, bf16 in/out.
// Thread = 8 channels x 8 rows (rolling window): each row loaded once.
// ---------------------------------------------------------------------------
__global__ __launch_bounds__(256) void conv_silu_kernel(
    const ushort* __restrict__ xz, const float* __restrict__ cw,
    const float* __restrict__ cb, ushort* __restrict__ u_bf) {
  const int nd8 = D_INNER / 8;  // 192
  const int idx = blockIdx.x * 256 + threadIdx.x;
  const int d8 = idx % nd8;
  const int lg = (idx / nd8) % (L_SEQ / 8);
  const int b = idx / (nd8 * (L_SEQ / 8));
  const int d = d8 * 8;
  const int l0 = lg * 8;

  float w0[8], w1[8], w2[8], bs[8];
#pragma unroll
  for (int j = 0; j < 8; ++j) {
    w0[j] = cw[(d + j) * 3 + 0];
    w1[j] = cw[(d + j) * 3 + 1];
    w2[j] = cw[(d + j) * 3 + 2];
    bs[j] = cb[d + j];
  }
  const ushort* base = xz + ((size_t)b * L_SEQ) * 3072 + d;
  const ushort8_t zv = {0, 0, 0, 0, 0, 0, 0, 0};
  ushort8_t prev = (l0 > 0) ? *(const ushort8_t*)(base + (size_t)(l0 - 1) * 3072) : zv;
  ushort8_t curv = *(const ushort8_t*)(base + (size_t)l0 * 3072);
#pragma unroll
  for (int i = 0; i < 8; ++i) {
    const int l = l0 + i;
    const ushort8_t nxt =
        (l + 1 < L_SEQ) ? *(const ushort8_t*)(base + (size_t)(l + 1) * 3072) : zv;
    ushort8_t o;
#pragma unroll
    for (int j = 0; j < 8; ++j) {
      const float a = bs[j] + bf2f(prev[j]) * w0[j] + bf2f(curv[j]) * w1[j] +
                      bf2f(nxt[j]) * w2[j];
      o[j] = f2bf(a / (1.f + __expf(-a)));
    }
    *(ushort8_t*)(u_bf + ((size_t)b * L_SEQ + l) * D_INNER + d) = o;
    prev = curv;
    curv = nxt;
  }
}

// ---------------------------------------------------------------------------
// K1: local scan. Block = 128 threads (2 waves), covering (k,b,dgB,chunk).
// Wave = 32 channels x 2 half-lanes; lane holds h[8] (8 states).
// 1 shuffle/step. delta/u staged as raw bf16 via global_load_lds with
// k-reversed per-lane SOURCE rows (LDS stays linear). LDS = 12 KB.
// ---------------------------------------------------------------------------
__global__ __launch_bounds__(128) void scan_local_kernel(
    const ushort* __restrict__ u_bf, const float* __restrict__ xdbl,
    const ushort* __restrict__ delta_bf, const float* __restrict__ A_logs,
    const float* __restrict__ Ds, ushort* __restrict__ y,
    float* __restrict__ hfin, float* __restrict__ Tsum) {
  __shared__ ushort sdu[32][64];  // delta (bf16), scan-order rows
  __shared__ ushort suu[32][64];  // u (bf16)
  __shared__ float sB[32][16], sC[32][16];
  const int tid = threadIdx.x;
  const int lane = tid & 63;
  const int w = tid >> 6;       // 0,1
  const int chW = lane >> 1;    // 0..31
  const int half = lane & 1;    // state half: n = half*8 + j
  const int bid = blockIdx.x;
  const int ch = bid & (NCH - 1);
  const int rest = bid >> 5;
  const int dgB = rest % NDG;
  const int kb = rest / NDG;
  const int b = kb & 1;
  const int k = kb >> 1;
  const int d0 = dgB * 64;
  const int dl = w * 32 + chW;  // 0..63 channel within block
  const int d = d0 + dl;
  const int row = k * D_INNER + d;

  float An[8];
  {
    const float4 a0 =
        *(const float4*)(A_logs + (size_t)row * D_STATE + half * 8);
    const float4 a1 =
        *(const float4*)(A_logs + (size_t)row * D_STATE + half * 8 + 4);
    An[0] = -__expf(a0.x) * LOG2E; An[1] = -__expf(a0.y) * LOG2E;
    An[2] = -__expf(a0.z) * LOG2E; An[3] = -__expf(a0.w) * LOG2E;
    An[4] = -__expf(a1.x) * LOG2E; An[5] = -__expf(a1.y) * LOG2E;
    An[6] = -__expf(a1.z) * LOG2E; An[7] = -__expf(a1.w) * LOG2E;
  }
  const float Dk = Ds[row];

  const ushort* uptr = u_bf + ((size_t)b * L_SEQ) * D_INNER;
  const ushort* dptr = delta_bf + ((size_t)(k * B_SZ + b) * L_SEQ) * D_INNER;
  const float* xptr = xdbl + ((size_t)b * L_SEQ) * 160 + k * 80;
  ushort* yptr = y + ((size_t)(k * B_SZ + b) * L_SEQ) * D_INNER;

  float h[8] = {};
  float S = 0.f;

  for (int sub = 0; sub < CH / 32; ++sub) {
    const int t0 = ch * CH + sub * 32;
    const int lbase = k ? (L_SEQ - 32 - t0) : t0;
    // stage delta (wave0) / u (wave1) via global_load_lds, k-reversed source
    {
      const ushort* src = (w == 0) ? dptr : uptr;
      ushort* dst = (w == 0) ? &sdu[0][0] : &suu[0][0];
#pragma unroll
      for (int i = 0; i < 4; ++i) {
        const int rd = i * 8 + (lane >> 3);   // dest scan-order row
        const int gr = k ? (31 - rd) : rd;    // global row offset
        const int seg = lane & 7;
        gload_lds16(src + (size_t)(lbase + gr) * D_INNER + d0 + seg * 8,
                    dst + i * 512);
      }
    }
    // stage B (wave0) / C (wave1): [32][16] f32
    {
      const int r = lane >> 1;
      const int ridx = k ? (31 - r) : r;
      const int c8 = (lane & 1) * 8;
      const float* srcx =
          xptr + (size_t)(lbase + r) * 160 + DT_RANK + (w ? D_STATE : 0) + c8;
      float* dstx = (w == 0) ? &sB[ridx][c8] : &sC[ridx][c8];
      *(float4*)dstx = *(const float4*)srcx;
      *(float4*)(dstx + 4) = *(const float4*)(srcx + 4);
    }
    __syncthreads();
    for (int s = 0; s < 32; ++s) {
      const float dlt = bf2f(sdu[s][dl]);
      const float uu = bf2f(suu[s][dl]);
      S += dlt;
      const float du = dlt * uu;
      const float4 Bv0 = *(const float4*)&sB[s][half * 8];
      const float4 Bv1 = *(const float4*)&sB[s][half * 8 + 4];
      const float4 Cv0 = *(const float4*)&sC[s][half * 8];
      const float4 Cv1 = *(const float4*)&sC[s][half * 8 + 4];
      h[0] = h[0] * ex2(dlt * An[0]) + du * Bv0.x;
      h[1] = h[1] * ex2(dlt * An[1]) + du * Bv0.y;
      h[2] = h[2] * ex2(dlt * An[2]) + du * Bv0.z;
      h[3] = h[3] * ex2(dlt * An[3]) + du * Bv0.w;
      h[4] = h[4] * ex2(dlt * An[4]) + du * Bv1.x;
      h[5] = h[5] * ex2(dlt * An[5]) + du * Bv1.y;
      h[6] = h[6] * ex2(dlt * An[6]) + du * Bv1.z;
      h[7] = h[7] * ex2(dlt * An[7]) + du * Bv1.w;
      float yt = h[0] * Cv0.x + h[1] * Cv0.y + h[2] * Cv0.z + h[3] * Cv0.w +
                 h[4] * Cv1.x + h[5] * Cv1.y + h[6] * Cv1.z + h[7] * Cv1.w;
      yt += __shfl_xor(yt, 1);
      if (half == 0) {
        const int t = t0 + s;
        const int l = k ? (L_SEQ - 1 - t) : t;
        yptr[(size_t)l * D_INNER + d] = f2bf(yt + uu * Dk);
      }
    }
    __syncthreads();
  }

  const size_t cidxB = ((size_t)(k * B_SZ + b) * NCH + ch) * NDG + dgB;
  *(float4*)(hfin + cidxB * 1024 + dl * 16 + half * 8) =
      make_float4(h[0], h[1], h[2], h[3]);
  *(float4*)(hfin + cidxB * 1024 + dl * 16 + half * 8 + 4) =
      make_float4(h[4], h[5], h[6], h[7]);
  if (half == 0) Tsum[cidxB * 64 + dl] = S;
}

// ---------------------------------------------------------------------------
// K2: stitch. Block = (k,b,dgB). Thread = (dl = tid>>2, nq = tid&3).
// ---------------------------------------------------------------------------
__global__ __launch_bounds__(256) void scan_stitch_kernel(
    const float* __restrict__ hfin, const float* __restrict__ Tsum,
    const float* __restrict__ A_logs, float* __restrict__ hin) {
  const int tid = threadIdx.x;
  const int dl = tid >> 2;
  const int nq = tid & 3;
  const int bid = blockIdx.x;
  const int dgB = bid % NDG;
  const int b = (bid / NDG) & 1;
  const int k = bid / (NDG * 2);
  const int row = k * D_INNER + dgB * 64 + dl;
  const float4 alv = *(const float4*)(A_logs + (size_t)row * D_STATE + nq * 4);
  const float An0 = -__expf(alv.x) * LOG2E, An1 = -__expf(alv.y) * LOG2E;
  const float An2 = -__expf(alv.z) * LOG2E, An3 = -__expf(alv.w) * LOG2E;
  float c0 = 0.f, c1 = 0.f, c2 = 0.f, c3 = 0.f;
  for (int ch = 0; ch < NCH; ++ch) {
    const size_t cidxB = ((size_t)(k * B_SZ + b) * NCH + ch) * NDG + dgB;
    const size_t off = cidxB * 1024 + dl * 16 + nq * 4;
    *(float4*)(hin + off) = make_float4(c0, c1, c2, c3);
    const float T = Tsum[cidxB * 64 + dl];
    const float4 hf = *(const float4*)(hfin + off);
    c0 = c0 * ex2(An0 * T) + hf.x;
    c1 = c1 * ex2(An1 * T) + hf.y;
    c2 = c2 * ex2(An2 * T) + hf.z;
    c3 = c3 * ex2(An3 * T) + hf.w;
  }
}

// ---------------------------------------------------------------------------
// K3: fused fixup (both directions) + gate -> yg bf16.
// ---------------------------------------------------------------------------
__global__ __launch_bounds__(256) void fixup_gate_kernel(
    const float* __restrict__ xdbl, const ushort* __restrict__ delta_bf,
    const float* __restrict__ A_logs, const float* __restrict__ hin,
    const ushort* __restrict__ y, const ushort* __restrict__ xz_bf,
    ushort* __restrict__ yg) {
  __shared__ float sd0[64][64], sd1[64][64];
  __shared__ float sC0[64][16], sC1[64][16];
  __shared__ float sQF[64][4], sQB[64][4];
  const int tid = threadIdx.x;
  const int tq = tid >> 6;
  const int dl = tid & 63;
  const int bid = blockIdx.x;
  const int ch = bid & (NCH - 1);
  const int rest = bid >> 5;
  const int dgB = rest % NDG;
  const int b = rest / NDG;
  const int d0 = dgB * 64;
  const int d = d0 + dl;
  const int lbase = ch * CH;
  const int chb = NCH - 1 - ch;

  float AnF[16], AnB[16], hF[16], hB[16];
#pragma unroll
  for (int q = 0; q < 4; ++q) {
    const float4 af = *(const float4*)(A_logs + (size_t)d * D_STATE + q * 4);
    AnF[q * 4 + 0] = -__expf(af.x) * LOG2E;
    AnF[q * 4 + 1] = -__expf(af.y) * LOG2E;
    AnF[q * 4 + 2] = -__expf(af.z) * LOG2E;
    AnF[q * 4 + 3] = -__expf(af.w) * LOG2E;
    const float4 ab =
        *(const float4*)(A_logs + (size_t)(D_INNER + d) * D_STATE + q * 4);
    AnB[q * 4 + 0] = -__expf(ab.x) * LOG2E;
    AnB[q * 4 + 1] = -__expf(ab.y) * LOG2E;
    AnB[q * 4 + 2] = -__expf(ab.z) * LOG2E;
    AnB[q * 4 + 3] = -__expf(ab.w) * LOG2E;
  }
  const size_t cF = ((size_t)(0 * B_SZ + b) * NCH + ch) * NDG + dgB;
  const size_t cB = ((size_t)(1 * B_SZ + b) * NCH + chb) * NDG + dgB;
#pragma unroll
  for (int q = 0; q < 4; ++q) {
    const float4 hv = *(const float4*)(hin + cF * 1024 + dl * 16 + q * 4);
    hF[q * 4 + 0] = hv.x; hF[q * 4 + 1] = hv.y;
    hF[q * 4 + 2] = hv.z; hF[q * 4 + 3] = hv.w;
    const float4 hw = *(const float4*)(hin + cB * 1024 + dl * 16 + q * 4);
    hB[q * 4 + 0] = hw.x; hB[q * 4 + 1] = hw.y;
    hB[q * 4 + 2] = hw.z; hB[q * 4 + 3] = hw.w;
  }

  const ushort* d0p =
      delta_bf + ((size_t)(0 * B_SZ + b) * L_SEQ + lbase) * D_INNER + d0;
  const ushort* d1p =
      delta_bf + ((size_t)(1 * B_SZ + b) * L_SEQ + lbase) * D_INNER + d0;
#pragma unroll
  for (int i = 0; i < 2; ++i) {
    const int unit = tid + i * 256;
    const int r = unit >> 3, seg = unit & 7;
    const ushort8_t v0 =
        *(const ushort8_t*)(d0p + (size_t)r * D_INNER + seg * 8);
    const ushort8_t v1 =
        *(const ushort8_t*)(d1p + (size_t)r * D_INNER + seg * 8);
    *(float4*)&sd0[r][seg * 8] =
        make_float4(bf2f(v0[0]), bf2f(v0[1]), bf2f(v0[2]), bf2f(v0[3]));
    *(float4*)&sd0[r][seg * 8 + 4] =
        make_float4(bf2f(v0[4]), bf2f(v0[5]), bf2f(v0[6]), bf2f(v0[7]));
    *(float4*)&sd1[r][seg * 8] =
        make_float4(bf2f(v1[0]), bf2f(v1[1]), bf2f(v1[2]), bf2f(v1[3]));
    *(float4*)&sd1[r][seg * 8 + 4] =
        make_float4(bf2f(v1[4]), bf2f(v1[5]), bf2f(v1[6]), bf2f(v1[7]));
  }
  {
    const int r = tid >> 2;
    const int c4 = (tid & 3) * 4;
    const float* xrow = xdbl + ((size_t)b * L_SEQ + lbase + r) * 160;
    *(float4*)&sC0[r][c4] = *(const float4*)(xrow + DT_RANK + D_STATE + c4);
    *(float4*)&sC1[r][c4] =
        *(const float4*)(xrow + 80 + DT_RANK + D_STATE + c4);
  }
  __syncthreads();
  float qf = 0.f, qb = 0.f;
#pragma unroll
  for (int i = 0; i < 16; ++i) {
    qf += sd0[tq * 16 + i][dl];
    qb += sd1[tq * 16 + i][dl];
  }
  sQF[dl][tq] = qf;
  sQB[dl][tq] = qb;
  __syncthreads();
  float SF = 0.f, SB = 0.f;
#pragma unroll
  for (int j = 0; j < 4; ++j) {
    if (j < tq) SF += sQF[dl][j];
    if (j > tq) SB += sQB[dl][j];
  }

  const ushort* y0p = y + ((size_t)(0 * B_SZ + b) * L_SEQ) * D_INNER;
  const ushort* y1p = y + ((size_t)(1 * B_SZ + b) * L_SEQ) * D_INNER;
  float yacc[16];
#pragma unroll
  for (int i = 0; i < 16; ++i) {
    const int t = tq * 16 + i;
    SF += sd0[t][dl];
    float wf = 0.f;
#pragma unroll
    for (int n = 0; n < 16; ++n)
      wf += sC0[t][n] * (ex2(AnF[n] * SF) * hF[n]);
    yacc[i] = bf2f(y0p[(size_t)(lbase + t) * D_INNER + d]) + wf;
  }
#pragma unroll
  for (int i = 15; i >= 0; --i) {
    const int t = tq * 16 + i;
    SB += sd1[t][dl];
    float wb = 0.f;
#pragma unroll
    for (int n = 0; n < 16; ++n)
      wb += sC1[t][n] * (ex2(AnB[n] * SB) * hB[n]);
    yacc[i] += bf2f(y1p[(size_t)(lbase + t) * D_INNER + d]) + wb;
  }
#pragma unroll
  for (int i = 0; i < 16; ++i) {
    const int l = lbase + tq * 16 + i;
    const float z = bf2f(xz_bf[((size_t)b * L_SEQ + l) * 3072 + 1536 + d]);
    yg[((size_t)b * L_SEQ + l) * D_INNER + d] = f2bf(yacc[i] * z);
  }
}

// ---------------------------------------------------------------------------
extern "C" void kernel_launch(void* const* d_in, const int* in_sizes, int n_in,
                              void* d_out, int out_size, void* d_ws,
                              size_t ws_size, hipStream_t stream) {
  const float* x          = (const float*)d_in[0];
  const float* in_proj_w  = (const float*)d_in[1];
  const float* conv_w     = (const float*)d_in[2];
  const float* conv_b     = (const float*)d_in[3];
  const float* x_proj_w   = (const float*)d_in[4];
  const float* dt_proj_w  = (const float*)d_in[5];
  const float* dt_proj_b  = (const float*)d_in[6];
  const float* A_logs     = (const float*)d_in[7];
  const float* Ds         = (const float*)d_in[8];
  const float* out_proj_w = (const float*)d_in[9];
  float* out = (float*)d_out;

  const int M = MTOT;
  const size_t NST = (size_t)2 * B_SZ * NCH * NDG;  // 3072

  float* ws    = (float*)d_ws;
  float* xdbl  = ws;                          // M*160
  float* hfin  = xdbl + (size_t)M * 160;      // NST*1024
  float* hin   = hfin + NST * 1024;           // NST*1024
  float* Tsum  = hin + NST * 1024;            // NST*64
  ushort* x_bf     = (ushort*)(Tsum + NST * 64);
  ushort* w_in_bf  = x_bf + (size_t)M * 768;
  ushort* w_out_bf = w_in_bf + (size_t)3072 * 768;
  ushort* w_xp_bf  = w_out_bf + (size_t)768 * 1536;
  ushort* w_dt_bf  = w_xp_bf + (size_t)256 * 1536;
  ushort* xz_bf    = w_dt_bf + (size_t)2 * 1536 * 64;
  ushort* u_bf     = xz_bf + (size_t)M * 3072;
  ushort* delta_bf = u_bf + (size_t)M * 1536;
  ushort* dtin     = delta_bf + (size_t)2 * M * 1536;
  ushort* y_bf     = dtin + (size_t)2 * M * 64;
  ushort* yg_bf    = y_bf + (size_t)2 * M * 1536;

  dim3 blk(256);
  dim3 blk128(128);

  // 0. conversions (one kernel)
  {
    const long TOT = 3145728L + 2359296 + 1179648 + 393216 + 196608;
    cvt_all_kernel<<<dim3((TOT / 4 + 255) / 256), blk, 0, stream>>>(
        x, in_proj_w, out_proj_w, x_proj_w, dt_proj_w, x_bf, w_in_bf, w_out_bf,
        w_xp_bf, w_dt_bf);
  }

  // 1. xz = x @ in_proj_w^T  -> bf16
  gemm_k<128, 128, 0, 1, 0><<<dim3(3072 / 128, M / 128), blk, 0, stream>>>(
      x_bf, 768, w_in_bf, 768, nullptr, xz_bf, 3072, 3072, 768, nullptr);

  // 2. u = silu(conv(x_conv)+bias) -> bf16 (8 rows per thread)
  conv_silu_kernel<<<dim3(B_SZ * (L_SEQ / 8) * (D_INNER / 8) / 256), blk, 0,
                     stream>>>(xz_bf, conv_w, conv_b, u_bf);

  // 3. xdbl = u @ x_proj_w^T -> fp32 (+ dtin bf16 epilogue); BM=32, 3 N-tiles
  gemm_k<32, 64, 0, 0, 1><<<dim3(3, M / 32), blk, 0, stream>>>(
      u_bf, 1536, w_xp_bf, 1536, nullptr, xdbl, 160, 160, 1536, dtin);

  // 4. delta = softplus(dtin @ dtw^T + dtb) -> bf16 (both k, one dispatch)
  gemm_dt_k<<<dim3(1536 / 128, M / 64, 2), blk, 0, stream>>>(
      dtin, w_dt_bf, dt_proj_b, delta_bf);

  // 5. scan
  scan_local_kernel<<<dim3(2 * B_SZ * NDG * NCH), blk128, 0, stream>>>(
      u_bf, xdbl, delta_bf, A_logs, Ds, y_bf, hfin, Tsum);
  scan_stitch_kernel<<<dim3(2 * B_SZ * NDG), blk, 0, stream>>>(hfin, Tsum,
                                                               A_logs, hin);
  // 6. fused fixup(both dirs) + gate -> yg bf16
  fixup_gate_kernel<<<dim3(B_SZ * NDG * NCH), blk, 0, stream>>>(
      xdbl, delta_bf, A_logs, hin, y_bf, xz_bf, yg_bf);

  // 7. out = yg @ out_proj_w^T -> fp32
  gemm_k<128, 128, 0, 0, 0><<<dim3(768 / 128, M / 128), blk, 0, stream>>>(
      yg_bf, 1536, w_out_bf, 1536, nullptr, out, 768, 768, 1536, nullptr);
}